// Round 2
// baseline (18147.531 us; speedup 1.0000x reference)
//
#include <hip/hip_runtime.h>
#include <math.h>

// ---------------------------------------------------------------------------
// Model constants
// ---------------------------------------------------------------------------
#define Bn   64
#define Nn   256
#define Ln   2048
#define CMP  128
#define PROT 128
#define GF   64
#define NHEADS 4
#define LT   128
#define DOUT 386   // 3*LATENT + 2
#define CB   16    // batch chunk
#define NCH  (Bn / CB)

__device__ __forceinline__ float apply_act(float v, int act) {
  if (act == 1) return v > 0.f ? v : 0.2f * v;   // lrelu ALPHA
  if (act == 2) return v > 0.f ? v : 0.1f * v;   // lrelu 0.1 (fingerprint)
  if (act == 3) return tanhf(v);
  return v;
}

// ---------------------------------------------------------------------------
// Embedding gather: out[r,:] = E[idx[r],:]
// ---------------------------------------------------------------------------
__global__ void embed_kernel(const int* __restrict__ idx, const float* __restrict__ E,
                             float* __restrict__ out, long total, int C) {
  long i = (long)blockIdx.x * blockDim.x + threadIdx.x;
  if (i >= total) return;
  long r = i / C;
  int c = (int)(i - r * (long)C);
  out[i] = E[(long)idx[r] * C + c];
}

// ---------------------------------------------------------------------------
// Generic tiled matmul  C = act(A @ B + bias). A: MxK row-major, B: KxN.
// In-place (C==A) is safe: each block reads only its own 32 rows of A and
// writes only those rows after the k-loop completes.
// ---------------------------------------------------------------------------
__global__ __launch_bounds__(256) void mm_kernel(
    const float* __restrict__ A, const float* __restrict__ Bm,
    const float* __restrict__ bias, float* __restrict__ C,
    int M, int N, int K, int lda, int ldb, int ldc, int colOff, int act)
{
  __shared__ float As[32][33];
  __shared__ float Bs[32][33];
  int tx = threadIdx.x, ty = threadIdx.y;
  int tid = ty * 16 + tx;
  int m0 = blockIdx.y * 32;
  int n0 = blockIdx.x * 32;
  float acc00 = 0.f, acc01 = 0.f, acc10 = 0.f, acc11 = 0.f;
  for (int k0 = 0; k0 < K; k0 += 32) {
#pragma unroll
    for (int t = 0; t < 4; ++t) {
      int li = tid + t * 256;
      int r = li >> 5, c = li & 31;
      int mm = m0 + r, kk = k0 + c;
      As[r][c] = (mm < M && kk < K) ? A[(long)mm * lda + kk] : 0.f;
      int kk2 = k0 + r, nn = n0 + c;
      Bs[r][c] = (kk2 < K && nn < N) ? Bm[(long)kk2 * ldb + nn] : 0.f;
    }
    __syncthreads();
#pragma unroll
    for (int kk = 0; kk < 32; ++kk) {
      float a0 = As[ty][kk], a1 = As[ty + 16][kk];
      float b0 = Bs[kk][tx], b1 = Bs[kk][tx + 16];
      acc00 += a0 * b0; acc01 += a0 * b1;
      acc10 += a1 * b0; acc11 += a1 * b1;
    }
    __syncthreads();
  }
  float accs[2][2] = {{acc00, acc01}, {acc10, acc11}};
#pragma unroll
  for (int i = 0; i < 2; ++i) {
    int m = m0 + ty + i * 16;
    if (m >= M) continue;
#pragma unroll
    for (int j = 0; j < 2; ++j) {
      int n = n0 + tx + j * 16;
      if (n >= N) continue;
      float v = accs[i][j];
      if (bias) v += bias[n];
      C[(long)m * ldc + colOff + n] = apply_act(v, act);
    }
  }
}

static void mm(hipStream_t st, const float* A, const float* Bm, const float* bias,
               float* C, int M, int N, int K, int lda, int ldb, int ldc,
               int colOff, int act)
{
  dim3 grid((N + 31) / 32, (M + 31) / 32), block(16, 16);
  mm_kernel<<<grid, block, 0, st>>>(A, Bm, bias, C, M, N, K, lda, ldb, ldc, colOff, act);
}

// ---------------------------------------------------------------------------
// f1/f2 = Wh . a[:F], Wh . a[F:]
// ---------------------------------------------------------------------------
__global__ void fvec_kernel(const float* __restrict__ Wh, const float* __restrict__ a,
                            float* __restrict__ f1, float* __restrict__ f2,
                            long rows, int F) {
  long r = (long)blockIdx.x * blockDim.x + threadIdx.x;
  if (r >= rows) return;
  const float* w = Wh + r * F;
  float s1 = 0.f, s2 = 0.f;
  for (int d = 0; d < F; ++d) { s1 += w[d] * a[d]; s2 += w[d] * a[F + d]; }
  f1[r] = s1; f2[r] = s2;
}

// ---------------------------------------------------------------------------
// GAT attention row: e_j = lrelu(f1_i + f2_j), mask by adj, softmax, hp=att@Wh,
// elu.  One block per (i, local_batch), 256 threads (N=256). All pointers are
// chunk-local except adj which is pre-offset.
// ---------------------------------------------------------------------------
__global__ __launch_bounds__(256) void gat_att_kernel(
    const float* __restrict__ Wh, const float* __restrict__ f1, const float* __restrict__ f2,
    const int* __restrict__ adj, float* __restrict__ out,
    int F, int ldo, int colOff)
{
  int bg = blockIdx.y, i = blockIdx.x;
  int j = threadIdx.x;
  __shared__ float att[Nn];
  __shared__ float red[Nn];
  float e = f1[(long)bg * Nn + i] + f2[(long)bg * Nn + j];
  e = e > 0.f ? e : 0.2f * e;
  bool pos = adj[((long)bg * Nn + i) * Nn + j] > 0;
  float val = pos ? e : -9e15f;
  red[j] = val; __syncthreads();
  for (int s = 128; s > 0; s >>= 1) { if (j < s) red[j] = fmaxf(red[j], red[j + s]); __syncthreads(); }
  float m = red[0]; __syncthreads();
  float p = expf(val - m);
  att[j] = p;
  red[j] = p; __syncthreads();
  for (int s = 128; s > 0; s >>= 1) { if (j < s) red[j] += red[j + s]; __syncthreads(); }
  float inv = 1.f / red[0];
  __syncthreads();
  for (int d = j; d < F; d += 256) {
    const float* whb = Wh + (long)bg * Nn * F + d;
    float acc = 0.f;
    for (int t = 0; t < Nn; ++t) acc += att[t] * whb[(long)t * F];
    acc *= inv;
    out[((long)bg * Nn + i) * ldo + colOff + d] = acc > 0.f ? acc : expm1f(acc);
  }
}

// ---------------------------------------------------------------------------
// 11x11 same-padding conv over [L x 128] + bias + lrelu(0.2).
// ---------------------------------------------------------------------------
__global__ __launch_bounds__(256) void conv11_kernel(
    const float* __restrict__ in, const float* __restrict__ kw,
    const float* __restrict__ bias_p, float* __restrict__ out)
{
  __shared__ float s[26][140];
  __shared__ float kk[121];
  int b = blockIdx.y;
  int l0 = blockIdx.x * 16;
  int tid = threadIdx.x;
  if (tid < 121) kk[tid] = kw[tid];
  const float* inb = in + (long)b * Ln * PROT;
  for (int li = tid; li < 26 * 138; li += 256) {
    int r = li / 138, c = li - r * 138;
    int l = l0 - 5 + r, p = c - 5;
    float v = 0.f;
    if (l >= 0 && l < Ln && p >= 0 && p < PROT) v = inb[(long)l * PROT + p];
    s[r][c] = v;
  }
  __syncthreads();
  float bias = bias_p[0];
  float* outb = out + (long)b * Ln * PROT;
#pragma unroll
  for (int t = 0; t < 8; ++t) {
    int idx = tid + t * 256;
    int r = idx >> 7;
    int p = idx & 127;
    int l = l0 + r;
    float acc = 0.f;
#pragma unroll
    for (int u = 0; u < 11; ++u)
#pragma unroll
      for (int v = 0; v < 11; ++v)
        acc += s[r + u][p + v] * kk[u * 11 + v];
    acc += bias;
    outb[(long)l * PROT + p] = acc > 0.f ? acc : 0.2f * acc;
  }
}

// ---------------------------------------------------------------------------
// score part 1: SC[r] = sum_d tanh( (X@W)[r,d] + bvec[d] ) * aw[d] + ab[0]
// X: rows x 128, W: 128x128.  32 rows per block.
// ---------------------------------------------------------------------------
__global__ __launch_bounds__(256) void score1_kernel(
    const float* __restrict__ X, const float* __restrict__ W,
    const float* __restrict__ bvec, const float* __restrict__ aw,
    const float* __restrict__ ab, float* __restrict__ SC, long rows)
{
  __shared__ float sX[32][33];
  __shared__ float sW[32][132];
  __shared__ float red[32][17];
  long r0 = (long)blockIdx.x * 32;
  int tx = threadIdx.x, ty = threadIdx.y;
  int tid = ty * 16 + tx;
  float acc[2][8] = {};
  for (int k0 = 0; k0 < 128; k0 += 32) {
#pragma unroll
    for (int t = 0; t < 4; ++t) {
      int li = tid + t * 256;
      int rr = li >> 5, kkc = li & 31;
      long r = r0 + rr;
      sX[rr][kkc] = (r < rows) ? X[r * 128 + k0 + kkc] : 0.f;
    }
#pragma unroll
    for (int t = 0; t < 16; ++t) {
      int li = tid + t * 256;
      int kkc = li >> 7, cc = li & 127;
      sW[kkc][cc] = W[(long)(k0 + kkc) * 128 + cc];
    }
    __syncthreads();
#pragma unroll
    for (int kk = 0; kk < 32; ++kk) {
      float x0 = sX[ty][kk], x1 = sX[ty + 16][kk];
#pragma unroll
      for (int j = 0; j < 8; ++j) {
        float wv = sW[kk][tx + j * 16];
        acc[0][j] += x0 * wv;
        acc[1][j] += x1 * wv;
      }
    }
    __syncthreads();
  }
  float p0 = 0.f, p1 = 0.f;
#pragma unroll
  for (int j = 0; j < 8; ++j) {
    int c = tx + j * 16;
    float bb = bvec[c], ww = aw[c];
    p0 += tanhf(acc[0][j] + bb) * ww;
    p1 += tanhf(acc[1][j] + bb) * ww;
  }
  red[ty][tx] = p0; red[ty + 16][tx] = p1;
  __syncthreads();
  if (tid < 32) {
    float s = 0.f;
#pragma unroll
    for (int t = 0; t < 16; ++t) s += red[tid][t];
    long r = r0 + tid;
    if (r < rows) SC[r] = s + ab[0];
  }
}

// ---------------------------------------------------------------------------
// Fused BIDAT pass A (atoms side): for 32 n-rows, iterate over all L:
//   A[n,l] = tanh(dot(avU[n], pv[l])) * am[n]*pm[l]
//   atr[n,:] += A[n,l] * pvT[l,:]
// epilogue: SCA[n] += atr[n,:].w2
// ---------------------------------------------------------------------------
__global__ __launch_bounds__(256) void bidat_passA_kernel(
    const float* __restrict__ AVU, const float* __restrict__ PVb,
    const float* __restrict__ PVTT,   // chunk-local [CB, L, 128]
    const float* __restrict__ am, const float* __restrict__ pm,
    const float* __restrict__ w2, float* __restrict__ SCA, int b0)
{
  int bl = blockIdx.y;
  int b = b0 + bl;
  int n0 = blockIdx.x * 32;
  int tx = threadIdx.x, ty = threadIdx.y, tid = ty * 16 + tx;
  __shared__ float sU[32][132];
  __shared__ float sP[32][132];
  __shared__ float sA[32][33];
  __shared__ float am_s[32];
  __shared__ float red[32][17];
  const float* avu = AVU + ((long)b * Nn + n0) * 128;
#pragma unroll
  for (int t = 0; t < 16; ++t) {
    int li = tid + t * 256;
    int rr = li >> 7, cc = li & 127;
    sU[rr][cc] = avu[(long)rr * 128 + cc];
  }
  if (tid < 32) am_s[tid] = am[(long)b * Nn + n0 + tid];
  float atr[2][8] = {};
  const float* pv  = PVb  + (long)b * Ln * 128;
  const float* pvt = PVTT + (long)bl * Ln * 128;
  __syncthreads();
  for (int l0 = 0; l0 < Ln; l0 += 32) {
#pragma unroll
    for (int t = 0; t < 16; ++t) {
      int li = tid + t * 256;
      int rr = li >> 7, cc = li & 127;
      sP[rr][cc] = pv[(long)(l0 + rr) * 128 + cc];
    }
    __syncthreads();
    float d00 = 0, d01 = 0, d10 = 0, d11 = 0;
#pragma unroll 4
    for (int k = 0; k < 128; ++k) {
      float u0 = sU[ty][k], u1 = sU[ty + 16][k];
      float q0 = sP[tx][k], q1 = sP[tx + 16][k];
      d00 += u0 * q0; d01 += u0 * q1; d10 += u1 * q0; d11 += u1 * q1;
    }
    float pm0 = pm[(long)b * Ln + l0 + tx];
    float pm1 = pm[(long)b * Ln + l0 + tx + 16];
    sA[ty][tx]           = tanhf(d00) * am_s[ty] * pm0;
    sA[ty][tx + 16]      = tanhf(d01) * am_s[ty] * pm1;
    sA[ty + 16][tx]      = tanhf(d10) * am_s[ty + 16] * pm0;
    sA[ty + 16][tx + 16] = tanhf(d11) * am_s[ty + 16] * pm1;
    __syncthreads();
#pragma unroll
    for (int t = 0; t < 16; ++t) {
      int li = tid + t * 256;
      int rr = li >> 7, cc = li & 127;
      sP[rr][cc] = pvt[(long)(l0 + rr) * 128 + cc];
    }
    __syncthreads();
#pragma unroll 8
    for (int l = 0; l < 32; ++l) {
      float a0 = sA[ty][l], a1 = sA[ty + 16][l];
#pragma unroll
      for (int j = 0; j < 8; ++j) {
        float v = sP[l][tx + j * 16];
        atr[0][j] += a0 * v;
        atr[1][j] += a1 * v;
      }
    }
    __syncthreads();
  }
  float p0 = 0.f, p1 = 0.f;
#pragma unroll
  for (int j = 0; j < 8; ++j) {
    float ww = w2[tx + j * 16];
    p0 += atr[0][j] * ww;
    p1 += atr[1][j] * ww;
  }
  red[ty][tx] = p0; red[ty + 16][tx] = p1;
  __syncthreads();
  if (tid < 32) {
    float s = 0.f;
#pragma unroll
    for (int t = 0; t < 16; ++t) s += red[tid][t];
    long r = (long)b * Nn + n0 + tid;
    SCA[r] = SCA[r] + s;
  }
}

// ---------------------------------------------------------------------------
// Fused BIDAT pass B (amino side): for 32 l-rows, iterate over all N:
//   A[n,l] = tanh(dot(avU[n], pv[l])) * am[n]*pm[l]
//   amt[l,:] += A[n,l] * avT[n,:]
// epilogue: SCP[l] += amt[l,:].w2
// ---------------------------------------------------------------------------
__global__ __launch_bounds__(256) void bidat_passB_kernel(
    const float* __restrict__ AVU, const float* __restrict__ AVTT,
    const float* __restrict__ PVb,
    const float* __restrict__ am, const float* __restrict__ pm,
    const float* __restrict__ w2, float* __restrict__ SCP)
{
  int b = blockIdx.y;
  int l0 = blockIdx.x * 32;
  int tx = threadIdx.x, ty = threadIdx.y, tid = ty * 16 + tx;
  __shared__ float sPv[32][132];
  __shared__ float sX[32][132];
  __shared__ float sA[32][33];
  __shared__ float pm_s[32];
  __shared__ float red[32][17];
  const float* pv = PVb + ((long)b * Ln + l0) * 128;
#pragma unroll
  for (int t = 0; t < 16; ++t) {
    int li = tid + t * 256;
    int rr = li >> 7, cc = li & 127;
    sPv[rr][cc] = pv[(long)rr * 128 + cc];
  }
  if (tid < 32) pm_s[tid] = pm[(long)b * Ln + l0 + tid];
  float amt[2][8] = {};
  __syncthreads();
  for (int n0 = 0; n0 < Nn; n0 += 32) {
    const float* avu = AVU + ((long)b * Nn + n0) * 128;
#pragma unroll
    for (int t = 0; t < 16; ++t) {
      int li = tid + t * 256;
      int rr = li >> 7, cc = li & 127;
      sX[rr][cc] = avu[(long)rr * 128 + cc];
    }
    __syncthreads();
    float d00 = 0, d01 = 0, d10 = 0, d11 = 0;  // (l=ty/ty+16, n=tx/tx+16)
#pragma unroll 4
    for (int k = 0; k < 128; ++k) {
      float pv0 = sPv[ty][k], pv1 = sPv[ty + 16][k];
      float u0 = sX[tx][k], u1 = sX[tx + 16][k];
      d00 += pv0 * u0; d01 += pv0 * u1; d10 += pv1 * u0; d11 += pv1 * u1;
    }
    float am0 = am[(long)b * Nn + n0 + tx];
    float am1 = am[(long)b * Nn + n0 + tx + 16];
    sA[ty][tx]           = tanhf(d00) * am0 * pm_s[ty];
    sA[ty][tx + 16]      = tanhf(d01) * am1 * pm_s[ty];
    sA[ty + 16][tx]      = tanhf(d10) * am0 * pm_s[ty + 16];
    sA[ty + 16][tx + 16] = tanhf(d11) * am1 * pm_s[ty + 16];
    __syncthreads();
    const float* avt = AVTT + ((long)b * Nn + n0) * 128;
#pragma unroll
    for (int t = 0; t < 16; ++t) {
      int li = tid + t * 256;
      int rr = li >> 7, cc = li & 127;
      sX[rr][cc] = avt[(long)rr * 128 + cc];
    }
    __syncthreads();
#pragma unroll 8
    for (int n = 0; n < 32; ++n) {
      float a0 = sA[ty][n], a1 = sA[ty + 16][n];
#pragma unroll
      for (int j = 0; j < 8; ++j) {
        float v = sX[n][tx + j * 16];
        amt[0][j] += a0 * v;
        amt[1][j] += a1 * v;
      }
    }
    __syncthreads();
  }
  float p0 = 0.f, p1 = 0.f;
#pragma unroll
  for (int j = 0; j < 8; ++j) {
    float ww = w2[tx + j * 16];
    p0 += amt[0][j] * ww;
    p1 += amt[1][j] * ww;
  }
  red[ty][tx] = p0; red[ty + 16][tx] = p1;
  __syncthreads();
  if (tid < 32) {
    float s = 0.f;
#pragma unroll
    for (int t = 0; t < 16; ++t) s += red[tid][t];
    long r = (long)b * Ln + l0 + tid;
    SCP[r] = SCP[r] + s;
  }
}

// ---------------------------------------------------------------------------
// masked softmax: e = exp(a - max(a)) * mask; e/(sum+1e-6)
// ---------------------------------------------------------------------------
__global__ __launch_bounds__(256) void mask_softmax_kernel(
    const float* __restrict__ score, const float* __restrict__ mask,
    float* __restrict__ att, int n)
{
  int b = blockIdx.x;
  int tid = threadIdx.x;
  __shared__ float red[256];
  const float* s = score + (long)b * n;
  const float* mk = mask + (long)b * n;
  float mx = -3.4e38f;
  for (int i = tid; i < n; i += 256) mx = fmaxf(mx, s[i]);
  red[tid] = mx; __syncthreads();
  for (int st = 128; st > 0; st >>= 1) { if (tid < st) red[tid] = fmaxf(red[tid], red[tid + st]); __syncthreads(); }
  mx = red[0]; __syncthreads();
  float sum = 0.f;
  for (int i = tid; i < n; i += 256) sum += expf(s[i] - mx) * mk[i];
  red[tid] = sum; __syncthreads();
  for (int st = 128; st > 0; st >>= 1) { if (tid < st) red[tid] += red[tid + st]; __syncthreads(); }
  float denom = red[0] + 1e-6f;
  for (int i = tid; i < n; i += 256) att[(long)b * n + i] = expf(s[i] - mx) * mk[i] / denom;
}

// ---------------------------------------------------------------------------
// out[b, colOff + d] = sum_t x[b,t,d] * att[b,t]
// ---------------------------------------------------------------------------
__global__ __launch_bounds__(128) void wsum_kernel(
    const float* __restrict__ x, const float* __restrict__ att,
    float* __restrict__ out, int n, int colOff)
{
  int b = blockIdx.x;
  int d = threadIdx.x;
  float acc = 0.f;
  const float* xb = x + (long)b * n * LT + d;
  const float* ab = att + (long)b * n;
  for (int t = 0; t < n; ++t) acc += xb[(long)t * LT] * ab[t];
  out[(long)b * 512 + colOff + d] = acc;
}

// ---------------------------------------------------------------------------
// v[:,128:256]=sf, v[:,384]=invT, v[:,385]=Temp
// ---------------------------------------------------------------------------
__global__ __launch_bounds__(128) void assemble_v_kernel(
    const float* __restrict__ sf, const float* __restrict__ invT,
    const float* __restrict__ T, float* __restrict__ v)
{
  int b = blockIdx.x;
  int t = threadIdx.x;
  v[(long)b * DOUT + 128 + t] = sf[(long)b * LT + t];
  if (t == 0) { v[(long)b * DOUT + 384] = invT[b]; v[(long)b * DOUT + 385] = T[b]; }
}

// ---------------------------------------------------------------------------
extern "C" void kernel_launch(void* const* d_in, const int* in_sizes, int n_in,
                              void* d_out, int out_size, void* d_ws, size_t ws_size,
                              hipStream_t stream) {
  const long NB = (long)Bn * Nn;    // 16384
  const long LB = (long)Bn * Ln;    // 131072

  const int*   atoms      = (const int*)d_in[0];
  const float* atoms_mask = (const float*)d_in[1];
  const int*   adj        = (const int*)d_in[2];
  const int*   amino      = (const int*)d_in[3];
  const float* amino_mask = (const float*)d_in[4];
  const float* fps        = (const float*)d_in[5];
  const float* invT       = (const float*)d_in[6];
  const float* Temp       = (const float*)d_in[7];
  const float* E_atom     = (const float*)d_in[8];
  const float* E_amino    = (const float*)d_in[9];
  const float* gatW       = (const float*)d_in[10];
  const float* gatA       = (const float*)d_in[11];
  const float* goW        = (const float*)d_in[12];
  const float* goA        = (const float*)d_in[13];
  const float* Wc_w       = (const float*)d_in[14];
  const float* Wc_b       = (const float*)d_in[15];
  const float* conv_k     = (const float*)d_in[16];
  const float* conv_b     = (const float*)d_in[17];
  const float* Wp_w       = (const float*)d_in[18];
  const float* Wp_b       = (const float*)d_in[19];
  const float* fp0        = (const float*)d_in[20];
  const float* fp1        = (const float*)d_in[21];
  const float* U          = (const float*)d_in[22];
  const float* t_c2p_w    = (const float*)d_in[23];
  const float* t_c2p_b    = (const float*)d_in[24];
  const float* t_p2c_w    = (const float*)d_in[25];
  const float* t_p2c_b    = (const float*)d_in[26];
  const float* bh_c_w     = (const float*)d_in[27];
  const float* bh_c_b     = (const float*)d_in[28];
  const float* bh_p_w     = (const float*)d_in[29];
  const float* bh_p_b     = (const float*)d_in[30];
  const float* ba_c_w     = (const float*)d_in[31];
  const float* ba_c_b     = (const float*)d_in[32];
  const float* ba_p_w     = (const float*)d_in[33];
  const float* ba_p_b     = (const float*)d_in[34];
  const float* comb_c_w   = (const float*)d_in[35];
  const float* comb_c_b   = (const float*)d_in[36];
  const float* comb_p_w   = (const float*)d_in[37];
  const float* comb_p_b   = (const float*)d_in[38];
  const float* Wout_w     = (const float*)d_in[39];
  const float* Wout_b     = (const float*)d_in[40];
  const float* out_w      = (const float*)d_in[41];
  const float* out_b      = (const float*)d_in[42];
  float* out = (float*)d_out;

  // ---------------- workspace layout (total ~111 MB) ----------------
  float* ws = (float*)d_ws;
  long off = 0;
  float* AV   = ws + off; off += NB * LT;          // 2,097,152
  float* PV   = ws + off; off += LB * LT;          // 16,777,216
  float* SF   = ws + off; off += (long)Bn * LT;
  float* SFT  = ws + off; off += (long)Bn * LT;
  float* CF   = ws + off; off += (long)Bn * 512;
  float* PF   = ws + off; off += (long)Bn * 512;
  float* F1   = ws + off; off += (long)CB * Nn;
  float* F2   = ws + off; off += (long)CB * Nn;
  float* SCA  = ws + off; off += NB;
  float* ATTA = ws + off; off += NB;
  float* SCP  = ws + off; off += LB;
  float* ATTP = ws + off; off += LB;
  float* V0   = ws + off; off += (long)Bn * DOUT;
  float* V1   = ws + off; off += (long)Bn * DOUT;
  float* POOL = ws + off;
  // pool aliases (stages sequential); pool size = 8,388,608 floats
  // GAT chunk stage:
  float* AVE = POOL;                               // CB*N*128 = 524288
  float* MH  = AVE + (long)CB * Nn * CMP;          // CB*N*256 = 1048576
  float* WH  = MH  + (long)CB * Nn * 256;          // CB*N*64
  float* WH2 = WH  + (long)CB * Nn * GF;           // CB*N*128
  float* G2  = WH2 + (long)CB * Nn * CMP;          // CB*N*128
  // CNN chunk stage:
  float* PVA = POOL;                               // CB*L*128 = 4,194,304
  // BIDAT stage:
  float* AVU  = POOL;                              // 2,097,152
  float* AVTT = AVU + NB * LT;                     // 2,097,152
  float* PVTT = AVTT + NB * LT;                    // CB*L*128 = 4,194,304

  // ======================= comp GAT (chunked) =======================
  for (int c = 0; c < NCH; ++c) {
    long b0 = (long)c * CB;
    long rows = (long)CB * Nn;                     // 4096
    long tot = rows * CMP;
    embed_kernel<<<dim3((unsigned)((tot + 255) / 256)), 256, 0, stream>>>(
        atoms + b0 * Nn, E_atom, AVE, tot, CMP);
    const int* adj_c = adj + b0 * Nn * Nn;
    for (int h = 0; h < NHEADS; ++h) {
      mm(stream, AVE, gatW + (long)h * CMP * GF, nullptr, WH,
         (int)rows, GF, CMP, CMP, GF, GF, 0, 0);
      fvec_kernel<<<dim3((unsigned)((rows + 255) / 256)), 256, 0, stream>>>(
          WH, gatA + (long)h * 2 * GF, F1, F2, rows, GF);
      gat_att_kernel<<<dim3(Nn, CB), 256, 0, stream>>>(WH, F1, F2, adj_c, MH, GF, 256, h * GF);
    }
    mm(stream, MH, goW, nullptr, WH2, (int)rows, CMP, 256, 256, CMP, CMP, 0, 0);
    fvec_kernel<<<dim3((unsigned)((rows + 255) / 256)), 256, 0, stream>>>(
        WH2, goA, F1, F2, rows, CMP);
    gat_att_kernel<<<dim3(Nn, CB), 256, 0, stream>>>(WH2, F1, F2, adj_c, G2, CMP, CMP, 0);
    mm(stream, G2, Wc_w, Wc_b, AV + b0 * Nn * LT, (int)rows, LT, CMP, CMP, LT, LT, 0, 1);
  }

  // ======================= prot CNN (chunked) =======================
  for (int c = 0; c < NCH; ++c) {
    long b0 = (long)c * CB;
    float* PVc = PV + b0 * Ln * LT;
    long tot = (long)CB * Ln * PROT;
    embed_kernel<<<dim3((unsigned)((tot + 255) / 256)), 256, 0, stream>>>(
        amino + b0 * Ln, E_amino, PVA, tot, PROT);
    conv11_kernel<<<dim3(Ln / 16, CB), 256, 0, stream>>>(PVA, conv_k + 0 * 121, conv_b + 0, PVc);
    conv11_kernel<<<dim3(Ln / 16, CB), 256, 0, stream>>>(PVc, conv_k + 1 * 121, conv_b + 1, PVA);
    conv11_kernel<<<dim3(Ln / 16, CB), 256, 0, stream>>>(PVA, conv_k + 2 * 121, conv_b + 2, PVc);
    // in-place: PVc = lrelu(PVc @ Wp + b)   (row-partitioned, safe)
    mm(stream, PVc, Wp_w, Wp_b, PVc, (int)((long)CB * Ln), LT, PROT, PROT, LT, LT, 0, 1);
  }

  // ======================= fingerprint =======================
  mm(stream, fps, fp0, nullptr, SFT, Bn, LT, 1024, 1024, LT, LT, 0, 2);
  mm(stream, SFT, fp1, nullptr, SF, Bn, LT, LT, LT, LT, LT, 0, 2);

  // ======================= bidirectional attention =======================
  for (int i = 0; i < 4; ++i) {
    mm(stream, AV, U + (long)i * LT * LT, nullptr, AVU, (int)NB, LT, LT, LT, LT, LT, 0, 0);
    mm(stream, AV, t_c2p_w + (long)i * LT * LT, t_c2p_b + (long)i * LT, AVTT,
       (int)NB, LT, LT, LT, LT, LT, 0, 3);
    // score part 1 (tanh(x@bh_w+b) . w1 + bias)
    score1_kernel<<<dim3((unsigned)(NB / 32)), dim3(16, 16), 0, stream>>>(
        AV, bh_c_w + (long)i * LT * LT, bh_c_b + (long)i * LT,
        ba_c_w + (long)i * 2 * LT, ba_c_b + i, SCA, NB);
    score1_kernel<<<dim3((unsigned)(LB / 32)), dim3(16, 16), 0, stream>>>(
        PV, bh_p_w + (long)i * LT * LT, bh_p_b + (long)i * LT,
        ba_p_w + (long)i * 2 * LT, ba_p_b + i, SCP, LB);
    // pass A per batch chunk (needs PVTT chunk)
    for (int c = 0; c < NCH; ++c) {
      long b0 = (long)c * CB;
      mm(stream, PV + b0 * Ln * LT, t_p2c_w + (long)i * LT * LT, t_p2c_b + (long)i * LT,
         PVTT, (int)((long)CB * Ln), LT, LT, LT, LT, LT, 0, 3);
      bidat_passA_kernel<<<dim3(Nn / 32, CB), dim3(16, 16), 0, stream>>>(
          AVU, PV, PVTT, atoms_mask, amino_mask,
          ba_c_w + (long)i * 2 * LT + LT, SCA, (int)b0);
    }
    // pass B full batch
    bidat_passB_kernel<<<dim3(Ln / 32, Bn), dim3(16, 16), 0, stream>>>(
        AVU, AVTT, PV, atoms_mask, amino_mask,
        ba_p_w + (long)i * 2 * LT + LT, SCP);
    mask_softmax_kernel<<<Bn, 256, 0, stream>>>(SCA, atoms_mask, ATTA, Nn);
    mask_softmax_kernel<<<Bn, 256, 0, stream>>>(SCP, amino_mask, ATTP, Ln);
    wsum_kernel<<<Bn, 128, 0, stream>>>(AV, ATTA, CF, Nn, i * LT);
    wsum_kernel<<<Bn, 128, 0, stream>>>(PV, ATTP, PF, Ln, i * LT);
  }

  // ======================= head =======================
  mm(stream, CF, comb_c_w, comb_c_b, V0, Bn, LT, 512, 512, LT, DOUT, 0, 0);
  mm(stream, PF, comb_p_w, comb_p_b, V0, Bn, LT, 512, 512, LT, DOUT, 256, 0);
  assemble_v_kernel<<<Bn, 128, 0, stream>>>(SF, invT, Temp, V0);
  mm(stream, V0, Wout_w,                     Wout_b,            V1, Bn, DOUT, DOUT, DOUT, DOUT, DOUT, 0, 1);
  mm(stream, V1, Wout_w + (long)DOUT * DOUT, Wout_b + DOUT,     V0, Bn, DOUT, DOUT, DOUT, DOUT, DOUT, 0, 1);
  mm(stream, V0, Wout_w + 2L * DOUT * DOUT,  Wout_b + 2 * DOUT, V1, Bn, DOUT, DOUT, DOUT, DOUT, DOUT, 0, 1);
  mm(stream, V1, out_w, out_b, out, Bn, 1, DOUT, DOUT, 1, 1, 0, 0);
}

// Round 3
// 7157.481 us; speedup vs baseline: 2.5355x; 2.5355x over previous
//
#include <hip/hip_runtime.h>
#include <math.h>

// ---------------------------------------------------------------------------
// Model constants
// ---------------------------------------------------------------------------
#define Bn   64
#define Nn   256
#define Ln   2048
#define CMP  128
#define PROT 128
#define GF   64
#define NHEADS 4
#define LT   128
#define DOUT 386   // 3*LATENT + 2
#define CB   16    // batch chunk (CNN / BIDAT passA staging)
#define NCH  (Bn / CB)

__device__ __forceinline__ float apply_act(float v, int act) {
  if (act == 1) return v > 0.f ? v : 0.2f * v;   // lrelu ALPHA
  if (act == 2) return v > 0.f ? v : 0.1f * v;   // lrelu 0.1 (fingerprint)
  if (act == 3) return tanhf(v);
  return v;
}

// ---------------------------------------------------------------------------
// Embedding gather: out[r,:] = E[idx[r],:]
// ---------------------------------------------------------------------------
__global__ void embed_kernel(const int* __restrict__ idx, const float* __restrict__ E,
                             float* __restrict__ out, long total, int C) {
  long i = (long)blockIdx.x * blockDim.x + threadIdx.x;
  if (i >= total) return;
  long r = i / C;
  int c = (int)(i - r * (long)C);
  out[i] = E[(long)idx[r] * C + c];
}

__global__ void zero_kernel(float* __restrict__ a, long n) {
  long i = (long)blockIdx.x * blockDim.x + threadIdx.x;
  if (i < n) a[i] = 0.f;
}

// ---------------------------------------------------------------------------
// Generic tiled matmul  C = act(A @ B + bias). A: MxK row-major, B: KxN.
// In-place (C==A) safe (blocks write only their own rows, after k-loop).
// ---------------------------------------------------------------------------
__global__ __launch_bounds__(256) void mm_kernel(
    const float* __restrict__ A, const float* __restrict__ Bm,
    const float* __restrict__ bias, float* __restrict__ C,
    int M, int N, int K, int lda, int ldb, int ldc, int colOff, int act)
{
  __shared__ float As[32][33];
  __shared__ float Bs[32][33];
  int tx = threadIdx.x, ty = threadIdx.y;
  int tid = ty * 16 + tx;
  int m0 = blockIdx.y * 32;
  int n0 = blockIdx.x * 32;
  float acc00 = 0.f, acc01 = 0.f, acc10 = 0.f, acc11 = 0.f;
  for (int k0 = 0; k0 < K; k0 += 32) {
#pragma unroll
    for (int t = 0; t < 4; ++t) {
      int li = tid + t * 256;
      int r = li >> 5, c = li & 31;
      int mm = m0 + r, kk = k0 + c;
      As[r][c] = (mm < M && kk < K) ? A[(long)mm * lda + kk] : 0.f;
      int kk2 = k0 + r, nn = n0 + c;
      Bs[r][c] = (kk2 < K && nn < N) ? Bm[(long)kk2 * ldb + nn] : 0.f;
    }
    __syncthreads();
#pragma unroll
    for (int kk = 0; kk < 32; ++kk) {
      float a0 = As[ty][kk], a1 = As[ty + 16][kk];
      float b0 = Bs[kk][tx], b1 = Bs[kk][tx + 16];
      acc00 += a0 * b0; acc01 += a0 * b1;
      acc10 += a1 * b0; acc11 += a1 * b1;
    }
    __syncthreads();
  }
  float accs[2][2] = {{acc00, acc01}, {acc10, acc11}};
#pragma unroll
  for (int i = 0; i < 2; ++i) {
    int m = m0 + ty + i * 16;
    if (m >= M) continue;
#pragma unroll
    for (int j = 0; j < 2; ++j) {
      int n = n0 + tx + j * 16;
      if (n >= N) continue;
      float v = accs[i][j];
      if (bias) v += bias[n];
      C[(long)m * ldc + colOff + n] = apply_act(v, act);
    }
  }
}

static void mm(hipStream_t st, const float* A, const float* Bm, const float* bias,
               float* C, int M, int N, int K, int lda, int ldb, int ldc,
               int colOff, int act)
{
  dim3 grid((N + 31) / 32, (M + 31) / 32), block(16, 16);
  mm_kernel<<<grid, block, 0, st>>>(A, Bm, bias, C, M, N, K, lda, ldb, ldc, colOff, act);
}

// ---------------------------------------------------------------------------
// f1/f2 = Wh . a[:F], Wh . a[F:]
// ---------------------------------------------------------------------------
__global__ void fvec_kernel(const float* __restrict__ Wh, const float* __restrict__ a,
                            float* __restrict__ f1, float* __restrict__ f2,
                            long rows, int F) {
  long r = (long)blockIdx.x * blockDim.x + threadIdx.x;
  if (r >= rows) return;
  const float* w = Wh + r * F;
  float s1 = 0.f, s2 = 0.f;
  for (int d = 0; d < F; ++d) { s1 += w[d] * a[d]; s2 += w[d] * a[F + d]; }
  f1[r] = s1; f2[r] = s2;
}

// ---------------------------------------------------------------------------
// Tiled GAT attention: one block handles 32 rows (i) for one b.
//   sE[r][j] = masked score; per-row softmax in LDS; out = (att @ Wh)*elu
// Block 256 threads (16x16). Full-batch grid: (Nn/32, Bn).
// ---------------------------------------------------------------------------
template<int F>
__global__ __launch_bounds__(256) void gat_att_tiled_kernel(
    const float* __restrict__ Wh, int ldW, int cW,
    const float* __restrict__ f1, const float* __restrict__ f2,
    const int* __restrict__ adj, float* __restrict__ out, int ldo, int cO)
{
  __shared__ float sE[32][257];
  __shared__ float sW[32][(F == 64) ? 68 : 132];
  __shared__ float f1s[32];
  __shared__ float mrow[32], srow[32];
  __shared__ float pred[32][9];
  int b = blockIdx.y;
  int i0 = blockIdx.x * 32;
  int tx = threadIdx.x, ty = threadIdx.y;
  int tid = ty * 16 + tx;
  const long rowb = (long)b * Nn;

  if (tid < 32) f1s[tid] = f1[rowb + i0 + tid];
  float f2v = f2[rowb + tid];
  __syncthreads();
  // scores (coalesced adj reads)
  for (int r = 0; r < 32; ++r) {
    float e = f1s[r] + f2v;
    e = e > 0.f ? e : 0.2f * e;
    int a = adj[(rowb + i0 + r) * Nn + tid];
    sE[r][tid] = (a > 0) ? e : -9e15f;
  }
  __syncthreads();
  // row max (8 lanes per row)
  {
    int r = tid >> 3, s = tid & 7;
    float m = -3.4e38f;
    for (int j = s; j < 256; j += 8) m = fmaxf(m, sE[r][j]);
    pred[r][s] = m;
  }
  __syncthreads();
  if (tid < 32) {
    float m = pred[tid][0];
#pragma unroll
    for (int s = 1; s < 8; ++s) m = fmaxf(m, pred[tid][s]);
    mrow[tid] = m;
  }
  __syncthreads();
  // exp + row sum
  {
    int r = tid >> 3, s = tid & 7;
    float m = mrow[r];
    float sum = 0.f;
    for (int j = s; j < 256; j += 8) {
      float v = expf(sE[r][j] - m);
      sE[r][j] = v;
      sum += v;
    }
    pred[r][s] = sum;
  }
  __syncthreads();
  if (tid < 32) {
    float s = 0.f;
#pragma unroll
    for (int t = 0; t < 8; ++t) s += pred[tid][t];
    srow[tid] = 1.f / s;
  }
  __syncthreads();
  // (32x256) @ (256xF), Wh staged through LDS in k-tiles of 32
  float acc[2][F / 16] = {};
  for (int k0 = 0; k0 < 256; k0 += 32) {
    for (int li = tid; li < 32 * F; li += 256) {
      int rr = li / F, cc = li % F;
      sW[rr][cc] = Wh[(rowb + k0 + rr) * (long)ldW + cW + cc];
    }
    __syncthreads();
#pragma unroll
    for (int kk = 0; kk < 32; ++kk) {
      float a0 = sE[ty][k0 + kk], a1 = sE[ty + 16][k0 + kk];
#pragma unroll
      for (int j = 0; j < F / 16; ++j) {
        float w = sW[kk][tx + j * 16];
        acc[0][j] += a0 * w;
        acc[1][j] += a1 * w;
      }
    }
    __syncthreads();
  }
#pragma unroll
  for (int ii = 0; ii < 2; ++ii) {
    int r = ty + ii * 16;
    float sc = srow[r];
#pragma unroll
    for (int j = 0; j < F / 16; ++j) {
      float v = acc[ii][j] * sc;
      v = v > 0.f ? v : expm1f(v);   // elu
      out[(rowb + i0 + r) * (long)ldo + cO + tx + j * 16] = v;
    }
  }
}

// ---------------------------------------------------------------------------
// 11x11 same-padding conv + bias + lrelu(0.2). 128 threads; each thread owns
// one p-column and 16 l-outputs; sliding register column (26 vals) per v.
// ---------------------------------------------------------------------------
__global__ __launch_bounds__(128) void conv11_kernel(
    const float* __restrict__ in, const float* __restrict__ kw,
    const float* __restrict__ bias_p, float* __restrict__ out)
{
  __shared__ float s[26][140];
  __shared__ float kk[121];
  int b = blockIdx.y;
  int l0 = blockIdx.x * 16;
  int tid = threadIdx.x;
  if (tid < 121) kk[tid] = kw[tid];
  const float* inb = in + (long)b * Ln * PROT;
  for (int r = 0; r < 26; ++r) {
    int l = l0 - 5 + r;
    for (int c = tid; c < 138; c += 128) {
      int p = c - 5;
      float v = 0.f;
      if (l >= 0 && l < Ln && p >= 0 && p < PROT) v = inb[(long)l * PROT + p];
      s[r][c] = v;
    }
  }
  __syncthreads();
  float bias = bias_p[0];
  float acc[16];
#pragma unroll
  for (int i = 0; i < 16; ++i) acc[i] = bias;
  int p = tid;
#pragma unroll
  for (int v = 0; v < 11; ++v) {
    float c[26];
#pragma unroll
    for (int u = 0; u < 26; ++u) c[u] = s[u][p + v];
#pragma unroll
    for (int u = 0; u < 11; ++u) {
      float w = kk[u * 11 + v];
#pragma unroll
      for (int i = 0; i < 16; ++i) acc[i] += c[i + u] * w;
    }
  }
  float* outb = out + (long)b * Ln * PROT;
#pragma unroll
  for (int i = 0; i < 16; ++i) {
    float vv = acc[i];
    outb[(long)(l0 + i) * PROT + p] = vv > 0.f ? vv : 0.2f * vv;
  }
}

// ---------------------------------------------------------------------------
// score part 1: SC[r] = sum_d tanh( (X@W)[r,d] + bvec[d] ) * aw[d] + ab[0]
// ---------------------------------------------------------------------------
__global__ __launch_bounds__(256) void score1_kernel(
    const float* __restrict__ X, const float* __restrict__ W,
    const float* __restrict__ bvec, const float* __restrict__ aw,
    const float* __restrict__ ab, float* __restrict__ SC, long rows)
{
  __shared__ float sX[32][33];
  __shared__ float sW[32][132];
  __shared__ float red[32][17];
  long r0 = (long)blockIdx.x * 32;
  int tx = threadIdx.x, ty = threadIdx.y;
  int tid = ty * 16 + tx;
  float acc[2][8] = {};
  for (int k0 = 0; k0 < 128; k0 += 32) {
#pragma unroll
    for (int t = 0; t < 4; ++t) {
      int li = tid + t * 256;
      int rr = li >> 5, kkc = li & 31;
      long r = r0 + rr;
      sX[rr][kkc] = (r < rows) ? X[r * 128 + k0 + kkc] : 0.f;
    }
#pragma unroll
    for (int t = 0; t < 16; ++t) {
      int li = tid + t * 256;
      int kkc = li >> 7, cc = li & 127;
      sW[kkc][cc] = W[(long)(k0 + kkc) * 128 + cc];
    }
    __syncthreads();
#pragma unroll
    for (int kk = 0; kk < 32; ++kk) {
      float x0 = sX[ty][kk], x1 = sX[ty + 16][kk];
#pragma unroll
      for (int j = 0; j < 8; ++j) {
        float wv = sW[kk][tx + j * 16];
        acc[0][j] += x0 * wv;
        acc[1][j] += x1 * wv;
      }
    }
    __syncthreads();
  }
  float p0 = 0.f, p1 = 0.f;
#pragma unroll
  for (int j = 0; j < 8; ++j) {
    int c = tx + j * 16;
    float bb = bvec[c], ww = aw[c];
    p0 += tanhf(acc[0][j] + bb) * ww;
    p1 += tanhf(acc[1][j] + bb) * ww;
  }
  red[ty][tx] = p0; red[ty + 16][tx] = p1;
  __syncthreads();
  if (tid < 32) {
    float s = 0.f;
#pragma unroll
    for (int t = 0; t < 16; ++t) s += red[tid][t];
    long r = r0 + tid;
    if (r < rows) SC[r] = s + ab[0];
  }
}

// ---------------------------------------------------------------------------
// Fused BIDAT pass A (atoms side), l-split over blockIdx.z (atomic score add)
// ---------------------------------------------------------------------------
#define LSPLIT 4
__global__ __launch_bounds__(256) void bidat_passA_kernel(
    const float* __restrict__ AVU, const float* __restrict__ PVb,
    const float* __restrict__ PVTT,   // chunk-local [CB, L, 128]
    const float* __restrict__ am, const float* __restrict__ pm,
    const float* __restrict__ w2, float* __restrict__ SCA, int b0)
{
  int bl = blockIdx.y;
  int b = b0 + bl;
  int n0 = blockIdx.x * 32;
  int lz = blockIdx.z;
  int tx = threadIdx.x, ty = threadIdx.y, tid = ty * 16 + tx;
  __shared__ float sU[32][132];
  __shared__ float sP[32][132];
  __shared__ float sA[32][33];
  __shared__ float am_s[32];
  __shared__ float red[32][17];
  const float* avu = AVU + ((long)b * Nn + n0) * 128;
#pragma unroll
  for (int t = 0; t < 16; ++t) {
    int li = tid + t * 256;
    int rr = li >> 7, cc = li & 127;
    sU[rr][cc] = avu[(long)rr * 128 + cc];
  }
  if (tid < 32) am_s[tid] = am[(long)b * Nn + n0 + tid];
  float atr[2][8] = {};
  const float* pv  = PVb  + (long)b * Ln * 128;
  const float* pvt = PVTT + (long)bl * Ln * 128;
  __syncthreads();
  int lbeg = lz * (Ln / LSPLIT), lend = lbeg + Ln / LSPLIT;
  for (int l0 = lbeg; l0 < lend; l0 += 32) {
#pragma unroll
    for (int t = 0; t < 16; ++t) {
      int li = tid + t * 256;
      int rr = li >> 7, cc = li & 127;
      sP[rr][cc] = pv[(long)(l0 + rr) * 128 + cc];
    }
    __syncthreads();
    float d00 = 0, d01 = 0, d10 = 0, d11 = 0;
#pragma unroll 4
    for (int k = 0; k < 128; ++k) {
      float u0 = sU[ty][k], u1 = sU[ty + 16][k];
      float q0 = sP[tx][k], q1 = sP[tx + 16][k];
      d00 += u0 * q0; d01 += u0 * q1; d10 += u1 * q0; d11 += u1 * q1;
    }
    float pm0 = pm[(long)b * Ln + l0 + tx];
    float pm1 = pm[(long)b * Ln + l0 + tx + 16];
    sA[ty][tx]           = tanhf(d00) * am_s[ty] * pm0;
    sA[ty][tx + 16]      = tanhf(d01) * am_s[ty] * pm1;
    sA[ty + 16][tx]      = tanhf(d10) * am_s[ty + 16] * pm0;
    sA[ty + 16][tx + 16] = tanhf(d11) * am_s[ty + 16] * pm1;
    __syncthreads();
#pragma unroll
    for (int t = 0; t < 16; ++t) {
      int li = tid + t * 256;
      int rr = li >> 7, cc = li & 127;
      sP[rr][cc] = pvt[(long)(l0 + rr) * 128 + cc];
    }
    __syncthreads();
#pragma unroll 8
    for (int l = 0; l < 32; ++l) {
      float a0 = sA[ty][l], a1 = sA[ty + 16][l];
#pragma unroll
      for (int j = 0; j < 8; ++j) {
        float v = sP[l][tx + j * 16];
        atr[0][j] += a0 * v;
        atr[1][j] += a1 * v;
      }
    }
    __syncthreads();
  }
  float p0 = 0.f, p1 = 0.f;
#pragma unroll
  for (int j = 0; j < 8; ++j) {
    float ww = w2[tx + j * 16];
    p0 += atr[0][j] * ww;
    p1 += atr[1][j] * ww;
  }
  red[ty][tx] = p0; red[ty + 16][tx] = p1;
  __syncthreads();
  if (tid < 32) {
    float s = 0.f;
#pragma unroll
    for (int t = 0; t < 16; ++t) s += red[tid][t];
    atomicAdd(&SCA[(long)b * Nn + n0 + tid], s);
  }
}

// ---------------------------------------------------------------------------
// Fused BIDAT pass B (amino side)
// ---------------------------------------------------------------------------
__global__ __launch_bounds__(256) void bidat_passB_kernel(
    const float* __restrict__ AVU, const float* __restrict__ AVTT,
    const float* __restrict__ PVb,
    const float* __restrict__ am, const float* __restrict__ pm,
    const float* __restrict__ w2, float* __restrict__ SCP)
{
  int b = blockIdx.y;
  int l0 = blockIdx.x * 32;
  int tx = threadIdx.x, ty = threadIdx.y, tid = ty * 16 + tx;
  __shared__ float sPv[32][132];
  __shared__ float sX[32][132];
  __shared__ float sA[32][33];
  __shared__ float pm_s[32];
  __shared__ float red[32][17];
  const float* pv = PVb + ((long)b * Ln + l0) * 128;
#pragma unroll
  for (int t = 0; t < 16; ++t) {
    int li = tid + t * 256;
    int rr = li >> 7, cc = li & 127;
    sPv[rr][cc] = pv[(long)rr * 128 + cc];
  }
  if (tid < 32) pm_s[tid] = pm[(long)b * Ln + l0 + tid];
  float amt[2][8] = {};
  __syncthreads();
  for (int n0 = 0; n0 < Nn; n0 += 32) {
    const float* avu = AVU + ((long)b * Nn + n0) * 128;
#pragma unroll
    for (int t = 0; t < 16; ++t) {
      int li = tid + t * 256;
      int rr = li >> 7, cc = li & 127;
      sX[rr][cc] = avu[(long)rr * 128 + cc];
    }
    __syncthreads();
    float d00 = 0, d01 = 0, d10 = 0, d11 = 0;  // (l=ty/ty+16, n=tx/tx+16)
#pragma unroll 4
    for (int k = 0; k < 128; ++k) {
      float pv0 = sPv[ty][k], pv1 = sPv[ty + 16][k];
      float u0 = sX[tx][k], u1 = sX[tx + 16][k];
      d00 += pv0 * u0; d01 += pv0 * u1; d10 += pv1 * u0; d11 += pv1 * u1;
    }
    float am0 = am[(long)b * Nn + n0 + tx];
    float am1 = am[(long)b * Nn + n0 + tx + 16];
    sA[ty][tx]           = tanhf(d00) * am0 * pm_s[ty];
    sA[ty][tx + 16]      = tanhf(d01) * am1 * pm_s[ty];
    sA[ty + 16][tx]      = tanhf(d10) * am0 * pm_s[ty + 16];
    sA[ty + 16][tx + 16] = tanhf(d11) * am1 * pm_s[ty + 16];
    __syncthreads();
    const float* avt = AVTT + ((long)b * Nn + n0) * 128;
#pragma unroll
    for (int t = 0; t < 16; ++t) {
      int li = tid + t * 256;
      int rr = li >> 7, cc = li & 127;
      sX[rr][cc] = avt[(long)rr * 128 + cc];
    }
    __syncthreads();
#pragma unroll 8
    for (int n = 0; n < 32; ++n) {
      float a0 = sA[ty][n], a1 = sA[ty + 16][n];
#pragma unroll
      for (int j = 0; j < 8; ++j) {
        float v = sX[n][tx + j * 16];
        amt[0][j] += a0 * v;
        amt[1][j] += a1 * v;
      }
    }
    __syncthreads();
  }
  float p0 = 0.f, p1 = 0.f;
#pragma unroll
  for (int j = 0; j < 8; ++j) {
    float ww = w2[tx + j * 16];
    p0 += amt[0][j] * ww;
    p1 += amt[1][j] * ww;
  }
  red[ty][tx] = p0; red[ty + 16][tx] = p1;
  __syncthreads();
  if (tid < 32) {
    float s = 0.f;
#pragma unroll
    for (int t = 0; t < 16; ++t) s += red[tid][t];
    long r = (long)b * Ln + l0 + tid;
    SCP[r] = SCP[r] + s;
  }
}

// ---------------------------------------------------------------------------
// masked softmax
// ---------------------------------------------------------------------------
__global__ __launch_bounds__(256) void mask_softmax_kernel(
    const float* __restrict__ score, const float* __restrict__ mask,
    float* __restrict__ att, int n)
{
  int b = blockIdx.x;
  int tid = threadIdx.x;
  __shared__ float red[256];
  const float* s = score + (long)b * n;
  const float* mk = mask + (long)b * n;
  float mx = -3.4e38f;
  for (int i = tid; i < n; i += 256) mx = fmaxf(mx, s[i]);
  red[tid] = mx; __syncthreads();
  for (int st = 128; st > 0; st >>= 1) { if (tid < st) red[tid] = fmaxf(red[tid], red[tid + st]); __syncthreads(); }
  mx = red[0]; __syncthreads();
  float sum = 0.f;
  for (int i = tid; i < n; i += 256) sum += expf(s[i] - mx) * mk[i];
  red[tid] = sum; __syncthreads();
  for (int st = 128; st > 0; st >>= 1) { if (tid < st) red[tid] += red[tid + st]; __syncthreads(); }
  float denom = red[0] + 1e-6f;
  for (int i = tid; i < n; i += 256) att[(long)b * n + i] = expf(s[i] - mx) * mk[i] / denom;
}

// ---------------------------------------------------------------------------
// weighted sum with t-split + atomicAdd (out must be pre-zeroed)
// ---------------------------------------------------------------------------
__global__ __launch_bounds__(128) void wsum_kernel(
    const float* __restrict__ x, const float* __restrict__ att,
    float* __restrict__ out, int n, int colOff, int nsplit)
{
  int b = blockIdx.x;
  int sp = blockIdx.y;
  int d = threadIdx.x;
  int chunk = n / nsplit;
  int t0 = sp * chunk, t1 = t0 + chunk;
  const float* xb = x + (long)b * n * LT + d;
  const float* ab = att + (long)b * n;
  float acc = 0.f;
  for (int t = t0; t < t1; ++t) acc += xb[(long)t * LT] * ab[t];
  atomicAdd(&out[(long)b * 512 + colOff + d], acc);
}

// ---------------------------------------------------------------------------
// v[:,128:256]=sf, v[:,384]=invT, v[:,385]=Temp
// ---------------------------------------------------------------------------
__global__ __launch_bounds__(128) void assemble_v_kernel(
    const float* __restrict__ sf, const float* __restrict__ invT,
    const float* __restrict__ T, float* __restrict__ v)
{
  int b = blockIdx.x;
  int t = threadIdx.x;
  v[(long)b * DOUT + 128 + t] = sf[(long)b * LT + t];
  if (t == 0) { v[(long)b * DOUT + 384] = invT[b]; v[(long)b * DOUT + 385] = T[b]; }
}

// ---------------------------------------------------------------------------
extern "C" void kernel_launch(void* const* d_in, const int* in_sizes, int n_in,
                              void* d_out, int out_size, void* d_ws, size_t ws_size,
                              hipStream_t stream) {
  const long NB = (long)Bn * Nn;    // 16384
  const long LB = (long)Bn * Ln;    // 131072
  const long M1 = 1024 * 1024;

  const int*   atoms      = (const int*)d_in[0];
  const float* atoms_mask = (const float*)d_in[1];
  const int*   adj        = (const int*)d_in[2];
  const int*   amino      = (const int*)d_in[3];
  const float* amino_mask = (const float*)d_in[4];
  const float* fps        = (const float*)d_in[5];
  const float* invT       = (const float*)d_in[6];
  const float* Temp       = (const float*)d_in[7];
  const float* E_atom     = (const float*)d_in[8];
  const float* E_amino    = (const float*)d_in[9];
  const float* gatW       = (const float*)d_in[10];
  const float* gatA       = (const float*)d_in[11];
  const float* goW        = (const float*)d_in[12];
  const float* goA        = (const float*)d_in[13];
  const float* Wc_w       = (const float*)d_in[14];
  const float* Wc_b       = (const float*)d_in[15];
  const float* conv_k     = (const float*)d_in[16];
  const float* conv_b     = (const float*)d_in[17];
  const float* Wp_w       = (const float*)d_in[18];
  const float* Wp_b       = (const float*)d_in[19];
  const float* fp0        = (const float*)d_in[20];
  const float* fp1        = (const float*)d_in[21];
  const float* U          = (const float*)d_in[22];
  const float* t_c2p_w    = (const float*)d_in[23];
  const float* t_c2p_b    = (const float*)d_in[24];
  const float* t_p2c_w    = (const float*)d_in[25];
  const float* t_p2c_b    = (const float*)d_in[26];
  const float* bh_c_w     = (const float*)d_in[27];
  const float* bh_c_b     = (const float*)d_in[28];
  const float* bh_p_w     = (const float*)d_in[29];
  const float* bh_p_b     = (const float*)d_in[30];
  const float* ba_c_w     = (const float*)d_in[31];
  const float* ba_c_b     = (const float*)d_in[32];
  const float* ba_p_w     = (const float*)d_in[33];
  const float* ba_p_b     = (const float*)d_in[34];
  const float* comb_c_w   = (const float*)d_in[35];
  const float* comb_c_b   = (const float*)d_in[36];
  const float* comb_p_w   = (const float*)d_in[37];
  const float* comb_p_b   = (const float*)d_in[38];
  const float* Wout_w     = (const float*)d_in[39];
  const float* Wout_b     = (const float*)d_in[40];
  const float* out_w      = (const float*)d_in[41];
  const float* out_b      = (const float*)d_in[42];
  float* out = (float*)d_out;

  // ---------------- workspace layout (~111 MB) ----------------
  float* ws = (float*)d_ws;
  long off = 0;
  float* AV   = ws + off; off += NB * LT;          // 2M
  float* PV   = ws + off; off += LB * LT;          // 16M
  float* SF   = ws + off; off += (long)Bn * LT;
  float* SFT  = ws + off; off += (long)Bn * LT;
  float* CF   = ws + off; off += (long)Bn * 512;   // CF then PF contiguous
  float* PF   = ws + off; off += (long)Bn * 512;
  float* F1   = ws + off; off += NB;
  float* F2   = ws + off; off += NB;
  float* SCA  = ws + off; off += NB;
  float* ATTA = ws + off; off += NB;
  float* SCP  = ws + off; off += LB;
  float* ATTP = ws + off; off += LB;
  float* V0   = ws + off; off += (long)Bn * DOUT;
  float* V1   = ws + off; off += (long)Bn * DOUT;
  float* POOL = ws + off;                          // 8.39M floats
  // GAT stage (full batch), peak 7M floats:
  float* AVE = POOL;                               // [0, 2M)
  float* WH  = POOL + 2 * M1;                      // [2M, 3M)  per-head
  float* MH  = POOL + 3 * M1;                      // [3M, 7M)
  float* WH2 = POOL;                               // [0, 2M)   (AVE dead)
  float* G2  = POOL + 3 * M1;                      // [3M, 5M)  (MH dead)
  // CNN chunk stage:
  float* PVA = POOL;                               // CB*L*128 = 4M
  // BIDAT stage:
  float* AVU  = POOL;                              // 2M
  float* AVTT = AVU + NB * LT;                     // 2M
  float* PVTT = AVTT + NB * LT;                    // 4M

  // ======================= comp GAT (full batch) =======================
  embed_kernel<<<dim3((unsigned)((NB * CMP + 255) / 256)), 256, 0, stream>>>(
      atoms, E_atom, AVE, NB * CMP, CMP);
  for (int h = 0; h < NHEADS; ++h) {
    mm(stream, AVE, gatW + (long)h * CMP * GF, nullptr, WH,
       (int)NB, GF, CMP, CMP, GF, GF, 0, 0);
    fvec_kernel<<<dim3((unsigned)((NB + 255) / 256)), 256, 0, stream>>>(
        WH, gatA + (long)h * 2 * GF, F1, F2, NB, GF);
    gat_att_tiled_kernel<GF><<<dim3(Nn / 32, Bn), dim3(16, 16), 0, stream>>>(
        WH, GF, 0, F1, F2, adj, MH, 256, h * GF);
  }
  mm(stream, MH, goW, nullptr, WH2, (int)NB, CMP, 256, 256, CMP, CMP, 0, 0);
  fvec_kernel<<<dim3((unsigned)((NB + 255) / 256)), 256, 0, stream>>>(
      WH2, goA, F1, F2, NB, CMP);
  gat_att_tiled_kernel<CMP><<<dim3(Nn / 32, Bn), dim3(16, 16), 0, stream>>>(
      WH2, CMP, 0, F1, F2, adj, G2, CMP, 0);
  mm(stream, G2, Wc_w, Wc_b, AV, (int)NB, LT, CMP, CMP, LT, LT, 0, 1);

  // ======================= prot CNN (chunked) =======================
  for (int c = 0; c < NCH; ++c) {
    long b0 = (long)c * CB;
    float* PVc = PV + b0 * Ln * LT;
    long tot = (long)CB * Ln * PROT;
    embed_kernel<<<dim3((unsigned)((tot + 255) / 256)), 256, 0, stream>>>(
        amino + b0 * Ln, E_amino, PVA, tot, PROT);
    conv11_kernel<<<dim3(Ln / 16, CB), 128, 0, stream>>>(PVA, conv_k + 0 * 121, conv_b + 0, PVc);
    conv11_kernel<<<dim3(Ln / 16, CB), 128, 0, stream>>>(PVc, conv_k + 1 * 121, conv_b + 1, PVA);
    conv11_kernel<<<dim3(Ln / 16, CB), 128, 0, stream>>>(PVA, conv_k + 2 * 121, conv_b + 2, PVc);
    mm(stream, PVc, Wp_w, Wp_b, PVc, (int)((long)CB * Ln), LT, PROT, PROT, LT, LT, 0, 1);
  }

  // ======================= fingerprint =======================
  mm(stream, fps, fp0, nullptr, SFT, Bn, LT, 1024, 1024, LT, LT, 0, 2);
  mm(stream, SFT, fp1, nullptr, SF, Bn, LT, LT, LT, LT, LT, 0, 2);

  // ======================= bidirectional attention =======================
  zero_kernel<<<dim3((unsigned)((2L * Bn * 512 + 255) / 256)), 256, 0, stream>>>(
      CF, 2L * Bn * 512);
  for (int i = 0; i < 4; ++i) {
    mm(stream, AV, U + (long)i * LT * LT, nullptr, AVU, (int)NB, LT, LT, LT, LT, LT, 0, 0);
    mm(stream, AV, t_c2p_w + (long)i * LT * LT, t_c2p_b + (long)i * LT, AVTT,
       (int)NB, LT, LT, LT, LT, LT, 0, 3);
    score1_kernel<<<dim3((unsigned)(NB / 32)), dim3(16, 16), 0, stream>>>(
        AV, bh_c_w + (long)i * LT * LT, bh_c_b + (long)i * LT,
        ba_c_w + (long)i * 2 * LT, ba_c_b + i, SCA, NB);
    score1_kernel<<<dim3((unsigned)(LB / 32)), dim3(16, 16), 0, stream>>>(
        PV, bh_p_w + (long)i * LT * LT, bh_p_b + (long)i * LT,
        ba_p_w + (long)i * 2 * LT, ba_p_b + i, SCP, LB);
    for (int c = 0; c < NCH; ++c) {
      long b0 = (long)c * CB;
      mm(stream, PV + b0 * Ln * LT, t_p2c_w + (long)i * LT * LT, t_p2c_b + (long)i * LT,
         PVTT, (int)((long)CB * Ln), LT, LT, LT, LT, LT, 0, 3);
      bidat_passA_kernel<<<dim3(Nn / 32, CB, LSPLIT), dim3(16, 16), 0, stream>>>(
          AVU, PV, PVTT, atoms_mask, amino_mask,
          ba_c_w + (long)i * 2 * LT + LT, SCA, (int)b0);
    }
    bidat_passB_kernel<<<dim3(Ln / 32, Bn), dim3(16, 16), 0, stream>>>(
        AVU, AVTT, PV, atoms_mask, amino_mask,
        ba_p_w + (long)i * 2 * LT + LT, SCP);
    mask_softmax_kernel<<<Bn, 256, 0, stream>>>(SCA, atoms_mask, ATTA, Nn);
    mask_softmax_kernel<<<Bn, 256, 0, stream>>>(SCP, amino_mask, ATTP, Ln);
    wsum_kernel<<<dim3(Bn, 8), 128, 0, stream>>>(AV, ATTA, CF, Nn, i * LT, 8);
    wsum_kernel<<<dim3(Bn, 8), 128, 0, stream>>>(PV, ATTP, PF, Ln, i * LT, 8);
  }

  // ======================= head =======================
  mm(stream, CF, comb_c_w, comb_c_b, V0, Bn, LT, 512, 512, LT, DOUT, 0, 0);
  mm(stream, PF, comb_p_w, comb_p_b, V0, Bn, LT, 512, 512, LT, DOUT, 256, 0);
  assemble_v_kernel<<<Bn, 128, 0, stream>>>(SF, invT, Temp, V0);
  mm(stream, V0, Wout_w,                     Wout_b,            V1, Bn, DOUT, DOUT, DOUT, DOUT, DOUT, 0, 1);
  mm(stream, V1, Wout_w + (long)DOUT * DOUT, Wout_b + DOUT,     V0, Bn, DOUT, DOUT, DOUT, DOUT, DOUT, 0, 1);
  mm(stream, V0, Wout_w + 2L * DOUT * DOUT,  Wout_b + 2 * DOUT, V1, Bn, DOUT, DOUT, DOUT, DOUT, DOUT, 0, 1);
  mm(stream, V1, out_w, out_b, out, Bn, 1, DOUT, DOUT, 1, 1, 0, 0);
}

// Round 4
// 3647.144 us; speedup vs baseline: 4.9758x; 1.9625x over previous
//
#include <hip/hip_runtime.h>
#include <math.h>

// ---------------------------------------------------------------------------
// Model constants
// ---------------------------------------------------------------------------
#define Bn   64
#define Nn   256
#define Ln   2048
#define CMP  128
#define PROT 128
#define GF   64
#define NHEADS 4
#define LT   128
#define DOUT 386   // 3*LATENT + 2
#define CB   16    // batch chunk (CNN / BIDAT passA staging)
#define NCH  (Bn / CB)
#define CBH  8     // batch chunk for BH buffer
#define LSPA 4     // passA l-split

typedef unsigned short u16;
typedef __attribute__((ext_vector_type(8))) short short8v;   // 8 bf16 (4 VGPRs)
typedef __attribute__((ext_vector_type(4))) float f32x4;
typedef __attribute__((ext_vector_type(4))) unsigned short u16x4;
typedef __attribute__((ext_vector_type(4))) unsigned int u32x4;

#define MFMA(a, b, c) __builtin_amdgcn_mfma_f32_16x16x32_bf16((a), (b), (c), 0, 0, 0)

__device__ __forceinline__ float apply_act(float v, int act) {
  if (act == 1) return v > 0.f ? v : 0.2f * v;   // lrelu ALPHA
  if (act == 2) return v > 0.f ? v : 0.1f * v;   // lrelu 0.1 (fingerprint)
  if (act == 3) return tanhf(v);
  return v;
}

__device__ __forceinline__ u16 bfc(float f) {    // fp32 -> bf16 RNE
  union { float f; unsigned u; } x; x.f = f;
  unsigned r = x.u + 0x7fffu + ((x.u >> 16) & 1u);
  return (u16)(r >> 16);
}

// byte offset into a [R][C] bf16 LDS tile, XOR-swizzled (G4: break 128B/256B
// row-stride bank aliasing).  16B-granular accesses stay within slots.
template<int C>
__device__ __forceinline__ int lofs(int r, int c) {
  return ((r * C + c) * 2) ^ ((r & 7) << 4);
}

__device__ __forceinline__ short8v ldsv(const u16* s, int byteofs) {
  return *(const short8v*)((const char*)s + byteofs);
}

// ---------------------------------------------------------------------------
// Embedding gather: out[r,:] = E[idx[r],:]
// ---------------------------------------------------------------------------
__global__ void embed_kernel(const int* __restrict__ idx, const float* __restrict__ E,
                             float* __restrict__ out, long total, int C) {
  long i = (long)blockIdx.x * blockDim.x + threadIdx.x;
  if (i >= total) return;
  long r = i / C;
  int c = (int)(i - r * (long)C);
  out[i] = E[(long)idx[r] * C + c];
}

__global__ void zero_kernel(float* __restrict__ a, long n) {
  long i = (long)blockIdx.x * blockDim.x + threadIdx.x;
  if (i < n) a[i] = 0.f;
}

// ---------------------------------------------------------------------------
// Weight prep: dst[z][n*K + k] = bf16(src[z][k*N + n])   (B -> B^T bf16)
// ---------------------------------------------------------------------------
__global__ void transp_kernel(const float* __restrict__ src, u16* __restrict__ dst,
                              int K, int N) {
  long total = (long)K * N;
  long base = (long)blockIdx.y * total;
  long idx = (long)blockIdx.x * 256 + threadIdx.x;
  if (idx >= total) return;
  int k = (int)(idx % K);
  int n = (int)(idx / K);
  dst[base + idx] = bfc(src[base + (long)k * N + n]);
}

// ---------------------------------------------------------------------------
// MFMA GEMM: C = act(A @ B + bias).  A fp32 [M,K] (lda), Bt bf16 [N,K] (pre-
// transposed weights).  M%64==0, N%64==0, K%64==0.
// OUT=0: fp32 C[row*ldc + colOff + col]
// OUT=1: bf16 C[row*ldc + col]
// OUT=2: bf16 transposed-blocked C[(row/MBc)*BSt + col*ldt + (row%MBc)]
// In-place (C==A, OUT=0) safe: block reads only its own 64 rows, writes after.
// ---------------------------------------------------------------------------
template<int ACT, int OUT>
__global__ __launch_bounds__(256) void mfma_mm_kernel(
    const float* __restrict__ A, const u16* __restrict__ Bt,
    const float* __restrict__ bias, void* __restrict__ Cp,
    int M, int N, int K, int lda, int ldc, int colOff,
    int MBc, long BSt, int ldt)
{
  __shared__ u16 sA[64 * 64];
  __shared__ u16 sB[64 * 64];
  int m0 = blockIdx.y * 64, n0 = blockIdx.x * 64;
  int tid = threadIdx.x, lane = tid & 63, wv = tid >> 6;
  int mh = wv >> 1, nh = wv & 1;
  f32x4 acc00 = {0.f,0.f,0.f,0.f};
  f32x4 acc01 = acc00, acc10 = acc00, acc11 = acc00;
  for (int k0 = 0; k0 < K; k0 += 64) {
#pragma unroll
    for (int q = tid; q < 64 * 16; q += 256) {     // A: 64x64 fp32 -> bf16
      int r = q >> 4, c4 = (q & 15) << 2;
      float4 v = *(const float4*)(A + (long)(m0 + r) * lda + k0 + c4);
      u16x4 h = { bfc(v.x), bfc(v.y), bfc(v.z), bfc(v.w) };
      *(u16x4*)((char*)sA + lofs<64>(r, c4)) = h;
    }
#pragma unroll
    for (int q = tid; q < 64 * 8; q += 256) {      // B: bf16 copy
      int r = q >> 3, c8 = (q & 7) << 3;
      *(u32x4*)((char*)sB + lofs<64>(r, c8)) =
          *(const u32x4*)(Bt + (long)(n0 + r) * K + k0 + c8);
    }
    __syncthreads();
#pragma unroll
    for (int kk = 0; kk < 64; kk += 32) {
      int kf = kk + ((lane >> 4) << 3);
      short8v a0 = ldsv(sA, lofs<64>(mh * 32 + (lane & 15), kf));
      short8v a1 = ldsv(sA, lofs<64>(mh * 32 + 16 + (lane & 15), kf));
      short8v b0 = ldsv(sB, lofs<64>(nh * 32 + (lane & 15), kf));
      short8v b1 = ldsv(sB, lofs<64>(nh * 32 + 16 + (lane & 15), kf));
      acc00 = MFMA(a0, b0, acc00);
      acc01 = MFMA(a0, b1, acc01);
      acc10 = MFMA(a1, b0, acc10);
      acc11 = MFMA(a1, b1, acc11);
    }
    __syncthreads();
  }
#pragma unroll
  for (int rt = 0; rt < 2; ++rt) {
#pragma unroll
    for (int ct = 0; ct < 2; ++ct) {
      f32x4 a = rt == 0 ? (ct == 0 ? acc00 : acc01) : (ct == 0 ? acc10 : acc11);
      int col = n0 + nh * 32 + ct * 16 + (lane & 15);
      float bv = bias ? bias[col] : 0.f;
#pragma unroll
      for (int r4 = 0; r4 < 4; ++r4) {
        int row = m0 + mh * 32 + rt * 16 + ((lane >> 4) << 2) + r4;
        float v = apply_act(a[r4] + bv, ACT);
        if (OUT == 0)
          ((float*)Cp)[(long)row * ldc + colOff + col] = v;
        else if (OUT == 1)
          ((u16*)Cp)[(long)row * ldc + col] = bfc(v);
        else
          ((u16*)Cp)[(long)(row / MBc) * BSt + (long)col * ldt + (row % MBc)] = bfc(v);
      }
    }
  }
}

template<int ACT, int OUT>
static void mmx(hipStream_t st, const float* A, const u16* Bt, const float* bias,
                void* C, int M, int N, int K, int lda, int ldc, int colOff = 0,
                int MBc = 1, long BSt = 0, int ldt = 0)
{
  dim3 grid(N / 64, M / 64);
  mfma_mm_kernel<ACT, OUT><<<grid, dim3(256), 0, st>>>(
      A, Bt, bias, C, M, N, K, lda, ldc, colOff, MBc, BSt, ldt);
}

// ---------------------------------------------------------------------------
// Legacy fp32 tiled matmul (head layers with K=386 etc.)
// ---------------------------------------------------------------------------
__global__ __launch_bounds__(256) void mm_kernel(
    const float* __restrict__ A, const float* __restrict__ Bm,
    const float* __restrict__ bias, float* __restrict__ C,
    int M, int N, int K, int lda, int ldb, int ldc, int colOff, int act)
{
  __shared__ float As[32][33];
  __shared__ float Bs[32][33];
  int tx = threadIdx.x, ty = threadIdx.y;
  int tid = ty * 16 + tx;
  int m0 = blockIdx.y * 32;
  int n0 = blockIdx.x * 32;
  float acc00 = 0.f, acc01 = 0.f, acc10 = 0.f, acc11 = 0.f;
  for (int k0 = 0; k0 < K; k0 += 32) {
#pragma unroll
    for (int t = 0; t < 4; ++t) {
      int li = tid + t * 256;
      int r = li >> 5, c = li & 31;
      int mm = m0 + r, kk = k0 + c;
      As[r][c] = (mm < M && kk < K) ? A[(long)mm * lda + kk] : 0.f;
      int kk2 = k0 + r, nn = n0 + c;
      Bs[r][c] = (kk2 < K && nn < N) ? Bm[(long)kk2 * ldb + nn] : 0.f;
    }
    __syncthreads();
#pragma unroll
    for (int kk = 0; kk < 32; ++kk) {
      float a0 = As[ty][kk], a1 = As[ty + 16][kk];
      float b0 = Bs[kk][tx], b1 = Bs[kk][tx + 16];
      acc00 += a0 * b0; acc01 += a0 * b1;
      acc10 += a1 * b0; acc11 += a1 * b1;
    }
    __syncthreads();
  }
  float accs[2][2] = {{acc00, acc01}, {acc10, acc11}};
#pragma unroll
  for (int i = 0; i < 2; ++i) {
    int m = m0 + ty + i * 16;
    if (m >= M) continue;
#pragma unroll
    for (int j = 0; j < 2; ++j) {
      int n = n0 + tx + j * 16;
      if (n >= N) continue;
      float v = accs[i][j];
      if (bias) v += bias[n];
      C[(long)m * ldc + colOff + n] = apply_act(v, act);
    }
  }
}

static void mm(hipStream_t st, const float* A, const float* Bm, const float* bias,
               float* C, int M, int N, int K, int lda, int ldb, int ldc,
               int colOff, int act)
{
  dim3 grid((N + 31) / 32, (M + 31) / 32), block(16, 16);
  mm_kernel<<<grid, block, 0, st>>>(A, Bm, bias, C, M, N, K, lda, ldb, ldc, colOff, act);
}

// ---------------------------------------------------------------------------
// f1/f2 = Wh . a[:F], Wh . a[F:]
// ---------------------------------------------------------------------------
__global__ void fvec_kernel(const float* __restrict__ Wh, const float* __restrict__ a,
                            float* __restrict__ f1, float* __restrict__ f2,
                            long rows, int F) {
  long r = (long)blockIdx.x * blockDim.x + threadIdx.x;
  if (r >= rows) return;
  const float* w = Wh + r * F;
  float s1 = 0.f, s2 = 0.f;
  for (int d = 0; d < F; ++d) { s1 += w[d] * a[d]; s2 += w[d] * a[F + d]; }
  f1[r] = s1; f2[r] = s2;
}

// ---------------------------------------------------------------------------
// Tiled GAT attention (unchanged from r3)
// ---------------------------------------------------------------------------
template<int F>
__global__ __launch_bounds__(256) void gat_att_tiled_kernel(
    const float* __restrict__ Wh, int ldW, int cW,
    const float* __restrict__ f1, const float* __restrict__ f2,
    const int* __restrict__ adj, float* __restrict__ out, int ldo, int cO)
{
  __shared__ float sE[32][257];
  __shared__ float sW[32][(F == 64) ? 68 : 132];
  __shared__ float f1s[32];
  __shared__ float mrow[32], srow[32];
  __shared__ float pred[32][9];
  int b = blockIdx.y;
  int i0 = blockIdx.x * 32;
  int tx = threadIdx.x, ty = threadIdx.y;
  int tid = ty * 16 + tx;
  const long rowb = (long)b * Nn;

  if (tid < 32) f1s[tid] = f1[rowb + i0 + tid];
  float f2v = f2[rowb + tid];
  __syncthreads();
  for (int r = 0; r < 32; ++r) {
    float e = f1s[r] + f2v;
    e = e > 0.f ? e : 0.2f * e;
    int a = adj[(rowb + i0 + r) * Nn + tid];
    sE[r][tid] = (a > 0) ? e : -9e15f;
  }
  __syncthreads();
  {
    int r = tid >> 3, s = tid & 7;
    float m = -3.4e38f;
    for (int j = s; j < 256; j += 8) m = fmaxf(m, sE[r][j]);
    pred[r][s] = m;
  }
  __syncthreads();
  if (tid < 32) {
    float m = pred[tid][0];
#pragma unroll
    for (int s = 1; s < 8; ++s) m = fmaxf(m, pred[tid][s]);
    mrow[tid] = m;
  }
  __syncthreads();
  {
    int r = tid >> 3, s = tid & 7;
    float m = mrow[r];
    float sum = 0.f;
    for (int j = s; j < 256; j += 8) {
      float v = expf(sE[r][j] - m);
      sE[r][j] = v;
      sum += v;
    }
    pred[r][s] = sum;
  }
  __syncthreads();
  if (tid < 32) {
    float s = 0.f;
#pragma unroll
    for (int t = 0; t < 8; ++t) s += pred[tid][t];
    srow[tid] = 1.f / s;
  }
  __syncthreads();
  float acc[2][F / 16] = {};
  for (int k0 = 0; k0 < 256; k0 += 32) {
    for (int li = tid; li < 32 * F; li += 256) {
      int rr = li / F, cc = li % F;
      sW[rr][cc] = Wh[(rowb + k0 + rr) * (long)ldW + cW + cc];
    }
    __syncthreads();
#pragma unroll
    for (int kk = 0; kk < 32; ++kk) {
      float a0 = sE[ty][k0 + kk], a1 = sE[ty + 16][k0 + kk];
#pragma unroll
      for (int j = 0; j < F / 16; ++j) {
        float w = sW[kk][tx + j * 16];
        acc[0][j] += a0 * w;
        acc[1][j] += a1 * w;
      }
    }
    __syncthreads();
  }
#pragma unroll
  for (int ii = 0; ii < 2; ++ii) {
    int r = ty + ii * 16;
    float sc = srow[r];
#pragma unroll
    for (int j = 0; j < F / 16; ++j) {
      float v = acc[ii][j] * sc;
      v = v > 0.f ? v : expm1f(v);   // elu
      out[(rowb + i0 + r) * (long)ldo + cO + tx + j * 16] = v;
    }
  }
}

// ---------------------------------------------------------------------------
// 11x11 conv (unchanged from r3)
// ---------------------------------------------------------------------------
__global__ __launch_bounds__(128) void conv11_kernel(
    const float* __restrict__ in, const float* __restrict__ kw,
    const float* __restrict__ bias_p, float* __restrict__ out)
{
  __shared__ float s[26][140];
  __shared__ float kk[121];
  int b = blockIdx.y;
  int l0 = blockIdx.x * 16;
  int tid = threadIdx.x;
  if (tid < 121) kk[tid] = kw[tid];
  const float* inb = in + (long)b * Ln * PROT;
  for (int r = 0; r < 26; ++r) {
    int l = l0 - 5 + r;
    for (int c = tid; c < 138; c += 128) {
      int p = c - 5;
      float v = 0.f;
      if (l >= 0 && l < Ln && p >= 0 && p < PROT) v = inb[(long)l * PROT + p];
      s[r][c] = v;
    }
  }
  __syncthreads();
  float bias = bias_p[0];
  float acc[16];
#pragma unroll
  for (int i = 0; i < 16; ++i) acc[i] = bias;
  int p = tid;
#pragma unroll
  for (int v = 0; v < 11; ++v) {
    float c[26];
#pragma unroll
    for (int u = 0; u < 26; ++u) c[u] = s[u][p + v];
#pragma unroll
    for (int u = 0; u < 11; ++u) {
      float w = kk[u * 11 + v];
#pragma unroll
      for (int i = 0; i < 16; ++i) acc[i] += c[i + u] * w;
    }
  }
  float* outb = out + (long)b * Ln * PROT;
#pragma unroll
  for (int i = 0; i < 16; ++i) {
    float vv = acc[i];
    outb[(long)(l0 + i) * PROT + p] = vv > 0.f ? vv : 0.2f * vv;
  }
}

// ---------------------------------------------------------------------------
// rowdot: SC[r] = X[r,:128] . aw + ab[0]      (rows % 16 == 0)
// ---------------------------------------------------------------------------
__global__ __launch_bounds__(256) void rowdot_kernel(
    const float* __restrict__ X, const float* __restrict__ aw,
    const float* __restrict__ ab, float* __restrict__ SC)
{
  int tid = threadIdx.x, lane = tid & 63, wv = tid >> 6;
  long r = (long)blockIdx.x * 16 + wv * 4 + (lane >> 4);
  int c0 = (lane & 15) * 8;
  const float* x = X + r * 128 + c0;
  float4 v0 = *(const float4*)x;
  float4 v1 = *(const float4*)(x + 4);
  float4 a0 = *(const float4*)(aw + c0);
  float4 a1 = *(const float4*)(aw + c0 + 4);
  float s = v0.x * a0.x + v0.y * a0.y + v0.z * a0.z + v0.w * a0.w
          + v1.x * a1.x + v1.y * a1.y + v1.z * a1.z + v1.w * a1.w;
#pragma unroll
  for (int m = 1; m < 16; m <<= 1) s += __shfl_xor(s, m, 64);
  if ((lane & 15) == 0) SC[r] = s + ab[0];
}

// ---------------------------------------------------------------------------
// BIDAT pass A (MFMA): block = 32 atom-rows x one batch; loop l chunks of 64.
//   S = avU @ pv^T (MFMA), P = tanh(S)*am*pm -> bf16 LDS,
//   atr += P @ pvtt (MFMA, pvtt staged from transposed global [d][l]),
//   epilogue: SCA += atr . w2
// ---------------------------------------------------------------------------
__global__ __launch_bounds__(256) void passA_mfma(
    const u16* __restrict__ AVUbf,   // [Bn*Nn][128] bf16
    const float* __restrict__ PV,    // [Bn][Ln][128] fp32
    const u16* __restrict__ PVTTt,   // [CB][128][Ln] bf16 (chunk-local)
    const float* __restrict__ am, const float* __restrict__ pm,
    const float* __restrict__ w2, float* __restrict__ SCA, int b0)
{
  __shared__ u16 sU[32 * 128];
  __shared__ u16 sK[64 * 128];
  __shared__ u16 sV[128 * 64];
  __shared__ u16 sP[32 * 64];
  __shared__ float am_s[32], pm_s[64], w2_s[128];
  int bl = blockIdx.y, b = b0 + bl;
  int n0 = blockIdx.x * 32;
  int tid = threadIdx.x, lane = tid & 63, wv = tid >> 6;

  for (int q = tid; q < 32 * 16; q += 256) {       // sU: bf16 copy
    int r = q >> 4, c8 = (q & 15) << 3;
    *(u32x4*)((char*)sU + lofs<128>(r, c8)) =
        *(const u32x4*)(AVUbf + ((long)b * Nn + n0 + r) * 128 + c8);
  }
  if (tid < 32) am_s[tid] = am[(long)b * Nn + n0 + tid];
  if (tid < 128) w2_s[tid] = w2[tid];

  f32x4 atr0 = {0.f,0.f,0.f,0.f};
  f32x4 atr1 = atr0, atr2 = atr0, atr3 = atr0;
  const float* pvb = PV + (long)b * Ln * 128;
  const u16* pvt = PVTTt + (long)bl * 128 * Ln;
  int lbeg = blockIdx.z * (Ln / LSPA), lend = lbeg + Ln / LSPA;

  for (int l0 = lbeg; l0 < lend; l0 += 64) {
    __syncthreads();                               // prev PV-step done
    for (int q = tid; q < 64 * 32; q += 256) {     // sK: pv fp32 -> bf16
      int r = q >> 5, c4 = (q & 31) << 2;
      float4 v = *(const float4*)(pvb + (long)(l0 + r) * 128 + c4);
      u16x4 h = { bfc(v.x), bfc(v.y), bfc(v.z), bfc(v.w) };
      *(u16x4*)((char*)sK + lofs<128>(r, c4)) = h;
    }
    for (int q = tid; q < 128 * 8; q += 256) {     // sV: pvtt^T bf16 copy
      int r = q >> 3, c8 = (q & 7) << 3;
      *(u32x4*)((char*)sV + lofs<64>(r, c8)) =
          *(const u32x4*)(pvt + (long)r * Ln + l0 + c8);
    }
    if (tid < 64) pm_s[tid] = pm[(long)b * Ln + l0 + tid];
    __syncthreads();
    // S-step: wave wv -> (smh = wv&1, l-tiles (wv>>1)*2 + {0,1})
    int smh = wv & 1;
#pragma unroll
    for (int t = 0; t < 2; ++t) {
      int lt = ((wv >> 1) << 1) + t;
      f32x4 c = {0.f,0.f,0.f,0.f};
#pragma unroll
      for (int kk = 0; kk < 128; kk += 32) {
        int kf = kk + ((lane >> 4) << 3);
        short8v a = ldsv(sU, lofs<128>(smh * 16 + (lane & 15), kf));
        short8v bb = ldsv(sK, lofs<128>(lt * 16 + (lane & 15), kf));
        c = MFMA(a, bb, c);
      }
      int lcol = lt * 16 + (lane & 15);
      float pmv = pm_s[lcol];
#pragma unroll
      for (int r4 = 0; r4 < 4; ++r4) {
        int nrow = smh * 16 + ((lane >> 4) << 2) + r4;
        float pval = tanhf(c[r4]) * am_s[nrow] * pmv;
        *(u16*)((char*)sP + lofs<64>(nrow, lcol)) = bfc(pval);
      }
    }
    __syncthreads();
    // PV-step: wave wv -> (nh = wv>>1, d-half = wv&1), 4 d-tiles, K=64 (l)
    int nh = wv >> 1, dh = wv & 1;
#pragma unroll
    for (int kk = 0; kk < 64; kk += 32) {
      int kf = kk + ((lane >> 4) << 3);
      short8v a = ldsv(sP, lofs<64>(nh * 16 + (lane & 15), kf));
      short8v b0v = ldsv(sV, lofs<64>(dh * 64 + (lane & 15), kf));
      short8v b1v = ldsv(sV, lofs<64>(dh * 64 + 16 + (lane & 15), kf));
      short8v b2v = ldsv(sV, lofs<64>(dh * 64 + 32 + (lane & 15), kf));
      short8v b3v = ldsv(sV, lofs<64>(dh * 64 + 48 + (lane & 15), kf));
      atr0 = MFMA(a, b0v, atr0);
      atr1 = MFMA(a, b1v, atr1);
      atr2 = MFMA(a, b2v, atr2);
      atr3 = MFMA(a, b3v, atr3);
    }
  }
  // epilogue: score partial = atr . w2, reduce over 16-lane col groups
  int nh = wv >> 1, dh = wv & 1;
  float pr[4];
#pragma unroll
  for (int r4 = 0; r4 < 4; ++r4) {
    float s = atr0[r4] * w2_s[dh * 64 + (lane & 15)]
            + atr1[r4] * w2_s[dh * 64 + 16 + (lane & 15)]
            + atr2[r4] * w2_s[dh * 64 + 32 + (lane & 15)]
            + atr3[r4] * w2_s[dh * 64 + 48 + (lane & 15)];
#pragma unroll
    for (int m = 1; m < 16; m <<= 1) s += __shfl_xor(s, m, 64);
    pr[r4] = s;
  }
  if ((lane & 15) == 0) {
#pragma unroll
    for (int r4 = 0; r4 < 4; ++r4) {
      int n = nh * 16 + ((lane >> 4) << 2) + r4;
      atomicAdd(&SCA[(long)b * Nn + n0 + n], pr[r4]);
    }
  }
}

// ---------------------------------------------------------------------------
// BIDAT pass B (MFMA): block = 32 amino-rows x one batch; loop n chunks of 64.
//   S^T = pv @ avU^T, P^T -> bf16 LDS, amt += P^T @ avtt (avtt^T staged),
//   epilogue: SCP += amt . w2
// ---------------------------------------------------------------------------
__global__ __launch_bounds__(256) void passB_mfma(
    const u16* __restrict__ AVUbf,   // [Bn*Nn][128]
    const u16* __restrict__ AVTTt,   // [Bn][128][256]
    const float* __restrict__ PV,
    const float* __restrict__ am, const float* __restrict__ pm,
    const float* __restrict__ w2, float* __restrict__ SCP)
{
  __shared__ u16 sPv[32 * 128];
  __shared__ u16 sQ[64 * 128];
  __shared__ u16 sW[128 * 64];
  __shared__ u16 sP[32 * 64];
  __shared__ float pm_s[32], am_s[64], w2_s[128];
  int b = blockIdx.y, l0 = blockIdx.x * 32;
  int tid = threadIdx.x, lane = tid & 63, wv = tid >> 6;

  for (int q = tid; q < 32 * 32; q += 256) {       // sPv: pv fp32 -> bf16
    int r = q >> 5, c4 = (q & 31) << 2;
    float4 v = *(const float4*)(PV + ((long)b * Ln + l0 + r) * 128 + c4);
    u16x4 h = { bfc(v.x), bfc(v.y), bfc(v.z), bfc(v.w) };
    *(u16x4*)((char*)sPv + lofs<128>(r, c4)) = h;
  }
  if (tid < 32) pm_s[tid] = pm[(long)b * Ln + l0 + tid];
  if (tid < 128) w2_s[tid] = w2[tid];

  f32x4 amt0 = {0.f,0.f,0.f,0.f};
  f32x4 amt1 = amt0, amt2 = amt0, amt3 = amt0;

  for (int n0c = 0; n0c < Nn; n0c += 64) {
    __syncthreads();
    for (int q = tid; q < 64 * 16; q += 256) {     // sQ: avU bf16 copy
      int r = q >> 4, c8 = (q & 15) << 3;
      *(u32x4*)((char*)sQ + lofs<128>(r, c8)) =
          *(const u32x4*)(AVUbf + ((long)b * Nn + n0c + r) * 128 + c8);
    }
    for (int q = tid; q < 128 * 8; q += 256) {     // sW: avtt^T bf16 copy
      int r = q >> 3, c8 = (q & 7) << 3;
      *(u32x4*)((char*)sW + lofs<64>(r, c8)) =
          *(const u32x4*)(AVTTt + (long)b * 32768 + (long)r * 256 + n0c + c8);
    }
    if (tid < 64) am_s[tid] = am[(long)b * Nn + n0c + tid];
    __syncthreads();
    // S^T step: wave -> (lmh = wv&1, n-tiles (wv>>1)*2 + {0,1})
    int lmh = wv & 1;
#pragma unroll
    for (int t = 0; t < 2; ++t) {
      int nt = ((wv >> 1) << 1) + t;
      f32x4 c = {0.f,0.f,0.f,0.f};
#pragma unroll
      for (int kk = 0; kk < 128; kk += 32) {
        int kf = kk + ((lane >> 4) << 3);
        short8v a = ldsv(sPv, lofs<128>(lmh * 16 + (lane & 15), kf));
        short8v bb = ldsv(sQ, lofs<128>(nt * 16 + (lane & 15), kf));
        c = MFMA(a, bb, c);
      }
      int ncol = nt * 16 + (lane & 15);
      float amv = am_s[ncol];
#pragma unroll
      for (int r4 = 0; r4 < 4; ++r4) {
        int lrow = lmh * 16 + ((lane >> 4) << 2) + r4;
        float pval = tanhf(c[r4]) * amv * pm_s[lrow];
        *(u16*)((char*)sP + lofs<64>(lrow, ncol)) = bfc(pval);
      }
    }
    __syncthreads();
    // PV-step: wave -> (lh = wv>>1, d-half = wv&1), K=64 (n)
    int lh = wv >> 1, dh = wv & 1;
#pragma unroll
    for (int kk = 0; kk < 64; kk += 32) {
      int kf = kk + ((lane >> 4) << 3);
      short8v a = ldsv(sP, lofs<64>(lh * 16 + (lane & 15), kf));
      short8v b0v = ldsv(sW, lofs<64>(dh * 64 + (lane & 15), kf));
      short8v b1v = ldsv(sW, lofs<64>(dh * 64 + 16 + (lane & 15), kf));
      short8v b2v = ldsv(sW, lofs<64>(dh * 64 + 32 + (lane & 15), kf));
      short8v b3v = ldsv(sW, lofs<64>(dh * 64 + 48 + (lane & 15), kf));
      amt0 = MFMA(a, b0v, amt0);
      amt1 = MFMA(a, b1v, amt1);
      amt2 = MFMA(a, b2v, amt2);
      amt3 = MFMA(a, b3v, amt3);
    }
  }
  int lh = wv >> 1, dh = wv & 1;
  float pr[4];
#pragma unroll
  for (int r4 = 0; r4 < 4; ++r4) {
    float s = amt0[r4] * w2_s[dh * 64 + (lane & 15)]
            + amt1[r4] * w2_s[dh * 64 + 16 + (lane & 15)]
            + amt2[r4] * w2_s[dh * 64 + 32 + (lane & 15)]
            + amt3[r4] * w2_s[dh * 64 + 48 + (lane & 15)];
#pragma unroll
    for (int m = 1; m < 16; m <<= 1) s += __shfl_xor(s, m, 64);
    pr[r4] = s;
  }
  if ((lane & 15) == 0) {
#pragma unroll
    for (int r4 = 0; r4 < 4; ++r4) {
      int l = lh * 16 + ((lane >> 4) << 2) + r4;
      atomicAdd(&SCP[(long)b * Ln + l0 + l], pr[r4]);
    }
  }
}

// ---------------------------------------------------------------------------
// masked softmax
// ---------------------------------------------------------------------------
__global__ __launch_bounds__(256) void mask_softmax_kernel(
    const float* __restrict__ score, const float* __restrict__ mask,
    float* __restrict__ att, int n)
{
  int b = blockIdx.x;
  int tid = threadIdx.x;
  __shared__ float red[256];
  const float* s = score + (long)b * n;
  const float* mk = mask + (long)b * n;
  float mx = -3.4e38f;
  for (int i = tid; i < n; i += 256) mx = fmaxf(mx, s[i]);
  red[tid] = mx; __syncthreads();
  for (int st = 128; st > 0; st >>= 1) { if (tid < st) red[tid] = fmaxf(red[tid], red[tid + st]); __syncthreads(); }
  mx = red[0]; __syncthreads();
  float sum = 0.f;
  for (int i = tid; i < n; i += 256) sum += expf(s[i] - mx) * mk[i];
  red[tid] = sum; __syncthreads();
  for (int st = 128; st > 0; st >>= 1) { if (tid < st) red[tid] += red[tid + st]; __syncthreads(); }
  float denom = red[0] + 1e-6f;
  for (int i = tid; i < n; i += 256) att[(long)b * n + i] = expf(s[i] - mx) * mk[i] / denom;
}

// ---------------------------------------------------------------------------
// weighted sum (t-split + atomicAdd; out pre-zeroed)
// ---------------------------------------------------------------------------
__global__ __launch_bounds__(128) void wsum_kernel(
    const float* __restrict__ x, const float* __restrict__ att,
    float* __restrict__ out, int n, int colOff, int nsplit)
{
  int b = blockIdx.x;
  int sp = blockIdx.y;
  int d = threadIdx.x;
  int chunk = n / nsplit;
  int t0 = sp * chunk, t1 = t0 + chunk;
  const float* xb = x + (long)b * n * LT + d;
  const float* ab = att + (long)b * n;
  float acc = 0.f;
  for (int t = t0; t < t1; ++t) acc += xb[(long)t * LT] * ab[t];
  atomicAdd(&out[(long)b * 512 + colOff + d], acc);
}

__global__ __launch_bounds__(128) void assemble_v_kernel(
    const float* __restrict__ sf, const float* __restrict__ invT,
    const float* __restrict__ T, float* __restrict__ v)
{
  int b = blockIdx.x;
  int t = threadIdx.x;
  v[(long)b * DOUT + 128 + t] = sf[(long)b * LT + t];
  if (t == 0) { v[(long)b * DOUT + 384] = invT[b]; v[(long)b * DOUT + 385] = T[b]; }
}

// ---------------------------------------------------------------------------
extern "C" void kernel_launch(void* const* d_in, const int* in_sizes, int n_in,
                              void* d_out, int out_size, void* d_ws, size_t ws_size,
                              hipStream_t stream) {
  const long NB = (long)Bn * Nn;    // 16384
  const long LB = (long)Bn * Ln;    // 131072
  const long M1 = 1024 * 1024;

  const int*   atoms      = (const int*)d_in[0];
  const float* atoms_mask = (const float*)d_in[1];
  const int*   adj        = (const int*)d_in[2];
  const int*   amino      = (const int*)d_in[3];
  const float* amino_mask = (const float*)d_in[4];
  const float* fps        = (const float*)d_in[5];
  const float* invT       = (const float*)d_in[6];
  const float* Temp       = (const float*)d_in[7];
  const float* E_atom     = (const float*)d_in[8];
  const float* E_amino    = (const float*)d_in[9];
  const float* gatW       = (const float*)d_in[10];
  const float* gatA       = (const float*)d_in[11];
  const float* goW        = (const float*)d_in[12];
  const float* goA        = (const float*)d_in[13];
  const float* Wc_w       = (const float*)d_in[14];
  const float* Wc_b       = (const float*)d_in[15];
  const float* conv_k     = (const float*)d_in[16];
  const float* conv_b     = (const float*)d_in[17];
  const float* Wp_w       = (const float*)d_in[18];
  const float* Wp_b       = (const float*)d_in[19];
  const float* fp0        = (const float*)d_in[20];
  const float* fp1        = (const float*)d_in[21];
  const float* U          = (const float*)d_in[22];
  const float* t_c2p_w    = (const float*)d_in[23];
  const float* t_c2p_b    = (const float*)d_in[24];
  const float* t_p2c_w    = (const float*)d_in[25];
  const float* t_p2c_b    = (const float*)d_in[26];
  const float* bh_c_w     = (const float*)d_in[27];
  const float* bh_c_b     = (const float*)d_in[28];
  const float* bh_p_w     = (const float*)d_in[29];
  const float* bh_p_b     = (const float*)d_in[30];
  const float* ba_c_w     = (const float*)d_in[31];
  const float* ba_c_b     = (const float*)d_in[32];
  const float* ba_p_w     = (const float*)d_in[33];
  const float* ba_p_b     = (const float*)d_in[34];
  const float* comb_c_w   = (const float*)d_in[35];
  const float* comb_c_b   = (const float*)d_in[36];
  const float* comb_p_w   = (const float*)d_in[37];
  const float* comb_p_b   = (const float*)d_in[38];
  const float* Wout_w     = (const float*)d_in[39];
  const float* Wout_b     = (const float*)d_in[40];
  const float* out_w      = (const float*)d_in[41];
  const float* out_b      = (const float*)d_in[42];
  float* out = (float*)d_out;

  // ---------------- workspace layout (same footprint as r3) ----------------
  float* ws = (float*)d_ws;
  long off = 0;
  float* AV   = ws + off; off += NB * LT;
  float* PV   = ws + off; off += LB * LT;
  float* SF   = ws + off; off += (long)Bn * LT;
  float* SFT  = ws + off; off += (long)Bn * LT;
  float* CF   = ws + off; off += (long)Bn * 512;
  float* PF   = ws + off; off += (long)Bn * 512;
  float* F1   = ws + off; off += NB;
  float* F2   = ws + off; off += NB;
  float* SCA  = ws + off; off += NB;
  float* ATTA = ws + off; off += NB;
  float* SCP  = ws + off; off += LB;
  float* ATTP = ws + off; off += LB;
  float* V0   = ws + off; off += (long)Bn * DOUT;
  float* V1   = ws + off; off += (long)Bn * DOUT;
  float* POOL = ws + off;
  // GAT stage: AVE[0,2M) WH[2M,3M) MH[3M,7M) WH2[0,2M) G2[3M,5M)
  float* AVE = POOL;
  float* WH  = POOL + 2 * M1;
  float* MH  = POOL + 3 * M1;
  float* WH2 = POOL;
  float* G2  = POOL + 3 * M1;
  // CNN stage: PVA [0,4M)
  float* PVA = POOL;
  // BIDAT stage: AVUbf[0,1M) AVTTt[1M,2M) PVTTt[2M,4M) BHc[4M,6M)
  u16*   AVUbf = (u16*)POOL;                     // NB*128 bf16
  u16*   AVTTt = (u16*)(POOL + 1 * M1);          // Bn*128*256 bf16
  u16*   PVTTt = (u16*)(POOL + 2 * M1);          // CB*128*Ln bf16
  float* BHc   = POOL + 4 * M1;                  // 2M floats
  // Weight cache (bf16, transposed) at [7M, 7.36M) — survives all stages
  u16* WT = (u16*)(POOL + 7 * M1);
  long wo = 0;
  u16* gatW_t  = WT + wo; wo += 4L * 64 * 128;
  u16* goW_t   = WT + wo; wo += 128L * 256;
  u16* Wc_t    = WT + wo; wo += 128L * 128;
  u16* Wp_t    = WT + wo; wo += 128L * 128;
  u16* fp0_t   = WT + wo; wo += 128L * 1024;
  u16* fp1_t   = WT + wo; wo += 128L * 128;
  u16* U_t     = WT + wo; wo += 4L * 128 * 128;
  u16* c2p_t   = WT + wo; wo += 4L * 128 * 128;
  u16* p2c_t   = WT + wo; wo += 4L * 128 * 128;
  u16* bhc_t   = WT + wo; wo += 4L * 128 * 128;
  u16* bhp_t   = WT + wo; wo += 4L * 128 * 128;
  u16* combc_t = WT + wo; wo += 128L * 512;
  u16* combp_t = WT + wo; wo += 128L * 512;

  // ======================= weight prep =======================
  {
    auto tp = [&](const float* s, u16* d, int K, int N, int cnt) {
      transp_kernel<<<dim3((unsigned)((K * N + 255) / 256), cnt), 256, 0, stream>>>(s, d, K, N);
    };
    tp(gatW, gatW_t, 128, 64, 4);
    tp(goW, goW_t, 256, 128, 1);
    tp(Wc_w, Wc_t, 128, 128, 1);
    tp(Wp_w, Wp_t, 128, 128, 1);
    tp(fp0, fp0_t, 1024, 128, 1);
    tp(fp1, fp1_t, 128, 128, 1);
    tp(U, U_t, 128, 128, 4);
    tp(t_c2p_w, c2p_t, 128, 128, 4);
    tp(t_p2c_w, p2c_t, 128, 128, 4);
    tp(bh_c_w, bhc_t, 128, 128, 4);
    tp(bh_p_w, bhp_t, 128, 128, 4);
    tp(comb_c_w, combc_t, 512, 128, 1);
    tp(comb_p_w, combp_t, 512, 128, 1);
  }

  // ======================= comp GAT =======================
  embed_kernel<<<dim3((unsigned)((NB * CMP + 255) / 256)), 256, 0, stream>>>(
      atoms, E_atom, AVE, NB * CMP, CMP);
  for (int h = 0; h < NHEADS; ++h) {
    mmx<0, 0>(stream, AVE, gatW_t + (long)h * 64 * 128, nullptr, WH,
              (int)NB, 64, 128, 128, 64);
    fvec_kernel<<<dim3((unsigned)((NB + 255) / 256)), 256, 0, stream>>>(
        WH, gatA + (long)h * 2 * GF, F1, F2, NB, GF);
    gat_att_tiled_kernel<GF><<<dim3(Nn / 32, Bn), dim3(16, 16), 0, stream>>>(
        WH, GF, 0, F1, F2, adj, MH, 256, h * GF);
  }
  mmx<0, 0>(stream, MH, goW_t, nullptr, WH2, (int)NB, 128, 256, 256, 128);
  fvec_kernel<<<dim3((unsigned)((NB + 255) / 256)), 256, 0, stream>>>(
      WH2, goA, F1, F2, NB, CMP);
  gat_att_tiled_kernel<CMP><<<dim3(Nn / 32, Bn), dim3(16, 16), 0, stream>>>(
      WH2, CMP, 0, F1, F2, adj, G2, CMP, 0);
  mmx<1, 0>(stream, G2, Wc_t, Wc_b, AV, (int)NB, 128, 128, 128, 128);

  // ======================= prot CNN =======================
  for (int c = 0; c < NCH; ++c) {
    long b0 = (long)c * CB;
    float* PVc = PV + b0 * Ln * LT;
    long tot = (long)CB * Ln * PROT;
    embed_kernel<<<dim3((unsigned)((tot + 255) / 256)), 256, 0, stream>>>(
        amino + b0 * Ln, E_amino, PVA, tot, PROT);
    conv11_kernel<<<dim3(Ln / 16, CB), 128, 0, stream>>>(PVA, conv_k + 0 * 121, conv_b + 0, PVc);
    conv11_kernel<<<dim3(Ln / 16, CB), 128, 0, stream>>>(PVc, conv_k + 1 * 121, conv_b + 1, PVA);
    conv11_kernel<<<dim3(Ln / 16, CB), 128, 0, stream>>>(PVA, conv_k + 2 * 121, conv_b + 2, PVc);
    mmx<1, 0>(stream, PVc, Wp_t, Wp_b, PVc, (int)((long)CB * Ln), 128, 128, 128, 128);
  }

  // ======================= fingerprint =======================
  mmx<2, 0>(stream, fps, fp0_t, nullptr, SFT, Bn, 128, 1024, 1024, 128);
  mmx<2, 0>(stream, SFT, fp1_t, nullptr, SF, Bn, 128, 128, 128, 128);

  // ======================= bidirectional attention =======================
  zero_kernel<<<dim3((unsigned)((2L * Bn * 512 + 255) / 256)), 256, 0, stream>>>(
      CF, 2L * Bn * 512);
  for (int i = 0; i < 4; ++i) {
    // avU (bf16), avT_t (bf16, transposed-blocked [b][d][n])
    mmx<0, 1>(stream, AV, U_t + (long)i * 16384, nullptr, AVUbf,
              (int)NB, 128, 128, 128, 128);
    mmx<3, 2>(stream, AV, c2p_t + (long)i * 16384, t_c2p_b + (long)i * 128, AVTTt,
              (int)NB, 128, 128, 128, 0, 0, 256, 128L * 256, 256);
    // score part 1 (atoms): BH = tanh(AV@bh_c+b), SCA = BH.w1 + b
    mmx<3, 0>(stream, AV, bhc_t + (long)i * 16384, bh_c_b + (long)i * 128, BHc,
              (int)NB, 128, 128, 128, 128);
    rowdot_kernel<<<dim3((unsigned)(NB / 16)), 256, 0, stream>>>(
        BHc, ba_c_w + (long)i * 256, ba_c_b + i, SCA);
    // score part 1 (amino), chunked
    for (int cb = 0; cb < Bn / CBH; ++cb) {
      long r0 = (long)cb * CBH * Ln;
      mmx<3, 0>(stream, PV + r0 * 128, bhp_t + (long)i * 16384, bh_p_b + (long)i * 128,
                BHc, (int)(CBH * Ln), 128, 128, 128, 128);
      rowdot_kernel<<<dim3((unsigned)(CBH * Ln / 16)), 256, 0, stream>>>(
          BHc, ba_p_w + (long)i * 256, ba_p_b + i, SCP + r0);
    }
    // pass A per CB-chunk: PVTTt = tanh(PV@t_p2c+b)^T then fused attention
    for (int c = 0; c < NCH; ++c) {
      long b0 = (long)c * CB;
      mmx<3, 2>(stream, PV + b0 * Ln * 128, p2c_t + (long)i * 16384,
                t_p2c_b + (long)i * 128, PVTTt,
                (int)((long)CB * Ln), 128, 128, 128, 0, 0, 2048, 128L * 2048, 2048);
      passA_mfma<<<dim3(Nn / 32, CB, LSPA), 256, 0, stream>>>(
          AVUbf, PV, PVTTt, atoms_mask, amino_mask,
          ba_c_w + (long)i * 256 + 128, SCA, (int)b0);
    }
    // pass B full batch
    passB_mfma<<<dim3(Ln / 32, Bn), 256, 0, stream>>>(
        AVUbf, AVTTt, PV, atoms_mask, amino_mask,
        ba_p_w + (long)i * 256 + 128, SCP);
    mask_softmax_kernel<<<Bn, 256, 0, stream>>>(SCA, atoms_mask, ATTA, Nn);
    mask_softmax_kernel<<<Bn, 256, 0, stream>>>(SCP, amino_mask, ATTP, Ln);
    wsum_kernel<<<dim3(Bn, 8), 128, 0, stream>>>(AV, ATTA, CF, Nn, i * LT, 8);
    wsum_kernel<<<dim3(Bn, 8), 128, 0, stream>>>(PV, ATTP, PF, Ln, i * LT, 8);
  }

  // ======================= head =======================
  mmx<0, 0>(stream, CF, combc_t, comb_c_b, V0, Bn, 128, 512, 512, DOUT, 0);
  mmx<0, 0>(stream, PF, combp_t, comb_p_b, V0, Bn, 128, 512, 512, DOUT, 256);
  assemble_v_kernel<<<Bn, 128, 0, stream>>>(SF, invT, Temp, V0);
  mm(stream, V0, Wout_w,                     Wout_b,            V1, Bn, DOUT, DOUT, DOUT, DOUT, DOUT, 0, 1);
  mm(stream, V1, Wout_w + (long)DOUT * DOUT, Wout_b + DOUT,     V0, Bn, DOUT, DOUT, DOUT, DOUT, DOUT, 0, 1);
  mm(stream, V0, Wout_w + 2L * DOUT * DOUT,  Wout_b + 2 * DOUT, V1, Bn, DOUT, DOUT, DOUT, DOUT, DOUT, 0, 1);
  mm(stream, V1, out_w, out_b, out, Bn, 1, DOUT, DOUT, 1, 1, 0, 0);
}

// Round 6
// 2216.239 us; speedup vs baseline: 8.1884x; 1.6456x over previous
//
#include <hip/hip_runtime.h>
#include <math.h>

// ---------------------------------------------------------------------------
// Model constants
// ---------------------------------------------------------------------------
#define Bn   64
#define Nn   256
#define Ln   2048
#define CMP  128
#define PROT 128
#define GF   64
#define NHEADS 4
#define LT   128
#define DOUT 386   // 3*LATENT + 2
#define CB   16    // batch chunk (CNN staging)
#define NCH  (Bn / CB)
#define FLSP 4     // bidat_fused l-split

typedef unsigned short u16;
typedef __attribute__((ext_vector_type(8))) short short8v;   // 8 bf16 (4 VGPRs)
typedef __attribute__((ext_vector_type(4))) float f32x4;
typedef __attribute__((ext_vector_type(4))) unsigned short u16x4;
typedef __attribute__((ext_vector_type(4))) unsigned int u32x4;

#define MFMA(a, b, c) __builtin_amdgcn_mfma_f32_16x16x32_bf16((a), (b), (c), 0, 0, 0)

__device__ __forceinline__ float apply_act(float v, int act) {
  if (act == 1) return v > 0.f ? v : 0.2f * v;   // lrelu ALPHA
  if (act == 2) return v > 0.f ? v : 0.1f * v;   // lrelu 0.1 (fingerprint)
  if (act == 3) return tanhf(v);
  return v;
}

__device__ __forceinline__ u16 bfc(float f) {    // fp32 -> bf16 RNE
  union { float f; unsigned u; } x; x.f = f;
  unsigned r = x.u + 0x7fffu + ((x.u >> 16) & 1u);
  return (u16)(r >> 16);
}

// byte offset into a [R][C] bf16 LDS tile, XOR-swizzled (G4).
template<int C>
__device__ __forceinline__ int lofs(int r, int c) {
  return ((r * C + c) * 2) ^ ((r & 7) << 4);
}

__device__ __forceinline__ short8v ldsv(const u16* s, int byteofs) {
  return *(const short8v*)((const char*)s + byteofs);
}

// ---------------------------------------------------------------------------
// Embedding gather
// ---------------------------------------------------------------------------
__global__ void embed_kernel(const int* __restrict__ idx, const float* __restrict__ E,
                             float* __restrict__ out, long total, int C) {
  long i = (long)blockIdx.x * blockDim.x + threadIdx.x;
  if (i >= total) return;
  long r = i / C;
  int c = (int)(i - r * (long)C);
  out[i] = E[(long)idx[r] * C + c];
}

__global__ void zero_kernel(float* __restrict__ a, long n) {
  long i = (long)blockIdx.x * blockDim.x + threadIdx.x;
  if (i < n) a[i] = 0.f;
}

// ---------------------------------------------------------------------------
// Weight prep: dst[z][n*K + k] = bf16(src[z][k*N + n])
// ---------------------------------------------------------------------------
__global__ void transp_kernel(const float* __restrict__ src, u16* __restrict__ dst,
                              int K, int N) {
  long total = (long)K * N;
  long base = (long)blockIdx.y * total;
  long idx = (long)blockIdx.x * 256 + threadIdx.x;
  if (idx >= total) return;
  int k = (int)(idx % K);
  int n = (int)(idx / K);
  dst[base + idx] = bfc(src[base + (long)k * N + n]);
}

// ---------------------------------------------------------------------------
// pack bvec/aw/ab for mmdot (av side / pv side), 2056 floats each:
//   [0,1024) bvec (8 groups x 128), [1024,2048) aw, [2048,2056) ab
// groups 0-3: BH part (score part-1);  groups 4-7: trans part (q / r vectors)
// ---------------------------------------------------------------------------
__global__ void pack_kernel(
    const float* __restrict__ bh_c_b, const float* __restrict__ t_c2p_b,
    const float* __restrict__ ba_c_w, const float* __restrict__ ba_c_b,
    const float* __restrict__ ba_p_w, const float* __restrict__ bh_p_b,
    const float* __restrict__ t_p2c_b, const float* __restrict__ ba_p_b,
    float* __restrict__ pk_a, float* __restrict__ pk_p)
{
  int idx = blockIdx.x * 256 + threadIdx.x;
  if (idx < 1024) {
    int g = idx >> 7, j = idx & 127;
    pk_a[idx] = g < 4 ? bh_c_b[g * 128 + j] : t_c2p_b[(g - 4) * 128 + j];
    pk_p[idx] = g < 4 ? bh_p_b[g * 128 + j] : t_p2c_b[(g - 4) * 128 + j];
  } else if (idx < 2048) {
    int k = idx - 1024; int g = k >> 7, j = k & 127;
    pk_a[idx] = g < 4 ? ba_c_w[g * 256 + j] : ba_p_w[(g - 4) * 256 + 128 + j];
    pk_p[idx] = g < 4 ? ba_p_w[g * 256 + j] : ba_c_w[(g - 4) * 256 + 128 + j];
  } else if (idx < 2056) {
    int g = idx - 2048;
    pk_a[idx] = g < 4 ? ba_c_b[g] : 0.f;
    pk_p[idx] = g < 4 ? ba_p_b[g] : 0.f;
  }
}

// ---------------------------------------------------------------------------
// MFMA GEMM: C = act(A @ B + bias).  A fp32 [M,K], Bt bf16 [N,K].
// OUT=0: fp32 C[row*ldc+colOff+col];  OUT=1: bf16 C[row*ldc+col]
// ---------------------------------------------------------------------------
template<int ACT, int OUT>
__global__ __launch_bounds__(256) void mfma_mm_kernel(
    const float* __restrict__ A, const u16* __restrict__ Bt,
    const float* __restrict__ bias, void* __restrict__ Cp,
    int M, int N, int K, int lda, int ldc, int colOff)
{
  __shared__ u16 sA[64 * 64];
  __shared__ u16 sB[64 * 64];
  int m0 = blockIdx.y * 64, n0 = blockIdx.x * 64;
  int tid = threadIdx.x, lane = tid & 63, wv = tid >> 6;
  int mh = wv >> 1, nh = wv & 1;
  f32x4 acc00 = {0.f,0.f,0.f,0.f};
  f32x4 acc01 = acc00, acc10 = acc00, acc11 = acc00;
  for (int k0 = 0; k0 < K; k0 += 64) {
#pragma unroll
    for (int q = tid; q < 64 * 16; q += 256) {
      int r = q >> 4, c4 = (q & 15) << 2;
      float4 v = *(const float4*)(A + (long)(m0 + r) * lda + k0 + c4);
      u16x4 h = { bfc(v.x), bfc(v.y), bfc(v.z), bfc(v.w) };
      *(u16x4*)((char*)sA + lofs<64>(r, c4)) = h;
    }
#pragma unroll
    for (int q = tid; q < 64 * 8; q += 256) {
      int r = q >> 3, c8 = (q & 7) << 3;
      *(u32x4*)((char*)sB + lofs<64>(r, c8)) =
          *(const u32x4*)(Bt + (long)(n0 + r) * K + k0 + c8);
    }
    __syncthreads();
#pragma unroll
    for (int kk = 0; kk < 64; kk += 32) {
      int kf = kk + ((lane >> 4) << 3);
      short8v a0 = ldsv(sA, lofs<64>(mh * 32 + (lane & 15), kf));
      short8v a1 = ldsv(sA, lofs<64>(mh * 32 + 16 + (lane & 15), kf));
      short8v b0 = ldsv(sB, lofs<64>(nh * 32 + (lane & 15), kf));
      short8v b1 = ldsv(sB, lofs<64>(nh * 32 + 16 + (lane & 15), kf));
      acc00 = MFMA(a0, b0, acc00);
      acc01 = MFMA(a0, b1, acc01);
      acc10 = MFMA(a1, b0, acc10);
      acc11 = MFMA(a1, b1, acc11);
    }
    __syncthreads();
  }
#pragma unroll
  for (int rt = 0; rt < 2; ++rt) {
#pragma unroll
    for (int ct = 0; ct < 2; ++ct) {
      f32x4 a = rt == 0 ? (ct == 0 ? acc00 : acc01) : (ct == 0 ? acc10 : acc11);
      int col = n0 + nh * 32 + ct * 16 + (lane & 15);
      float bv = bias ? bias[col] : 0.f;
#pragma unroll
      for (int r4 = 0; r4 < 4; ++r4) {
        int row = m0 + mh * 32 + rt * 16 + ((lane >> 4) << 2) + r4;
        float v = apply_act(a[r4] + bv, ACT);
        if (OUT == 0)
          ((float*)Cp)[(long)row * ldc + colOff + col] = v;
        else
          ((u16*)Cp)[(long)row * ldc + col] = bfc(v);
      }
    }
  }
}

template<int ACT, int OUT>
static void mmx(hipStream_t st, const float* A, const u16* Bt, const float* bias,
                void* C, int M, int N, int K, int lda, int ldc, int colOff = 0)
{
  dim3 grid(N / 64, M / 64);
  mfma_mm_kernel<ACT, OUT><<<grid, dim3(256), 0, st>>>(
      A, Bt, bias, C, M, N, K, lda, ldc, colOff);
}

// ---------------------------------------------------------------------------
// mmdot: out[g][row] = sum_col tanh((X@W_g)[row,col] + bvec_g[col]) * aw_g[col]
//        + ab_g,   for 8 weight groups.  X [M,128] fp32, Wcat [8][128][128] bf16.
// Block: 128 rows, stages X once, loops groups.
// ---------------------------------------------------------------------------
__global__ __launch_bounds__(256) void mmdot_kernel(
    const float* __restrict__ X, const u16* __restrict__ Wcat,
    const float* __restrict__ pk, float* __restrict__ out, long M)
{
  __shared__ u16 sX[128 * 128];
  __shared__ u16 sW[128 * 128];
  __shared__ float bv_s[128], aw_s[128];
  long m0 = (long)blockIdx.x * 128;
  int tid = threadIdx.x, lane = tid & 63, wv = tid >> 6;
  for (int q = tid; q < 128 * 32; q += 256) {
    int r = q >> 5, c4 = (q & 31) << 2;
    float4 v = *(const float4*)(X + (m0 + r) * 128 + c4);
    u16x4 h = { bfc(v.x), bfc(v.y), bfc(v.z), bfc(v.w) };
    *(u16x4*)((char*)sX + lofs<128>(r, c4)) = h;
  }
  for (int g = 0; g < 8; ++g) {
    __syncthreads();                       // sX ready / protect sW reuse
    for (int q = tid; q < 128 * 16; q += 256) {
      int r = q >> 4, c8 = (q & 15) << 3;
      *(u32x4*)((char*)sW + lofs<128>(r, c8)) =
          *(const u32x4*)(Wcat + (long)g * 16384 + (long)r * 128 + c8);
    }
    if (tid < 128) { bv_s[tid] = pk[g * 128 + tid]; aw_s[tid] = pk[1024 + g * 128 + tid]; }
    __syncthreads();
    float ab = pk[2048 + g];
#pragma unroll
    for (int rt = 0; rt < 2; ++rt) {
      float p[4] = {0.f, 0.f, 0.f, 0.f};
      for (int lt = 0; lt < 8; ++lt) {
        f32x4 c = {0.f,0.f,0.f,0.f};
#pragma unroll
        for (int kk = 0; kk < 128; kk += 32) {
          int kf = kk + ((lane >> 4) << 3);
          short8v a = ldsv(sX, lofs<128>(wv * 32 + rt * 16 + (lane & 15), kf));
          short8v bb = ldsv(sW, lofs<128>(lt * 16 + (lane & 15), kf));
          c = MFMA(a, bb, c);
        }
        int col = lt * 16 + (lane & 15);
        float bv = bv_s[col], awv = aw_s[col];
#pragma unroll
        for (int r4 = 0; r4 < 4; ++r4)
          p[r4] += tanhf(c[r4] + bv) * awv;
      }
#pragma unroll
      for (int r4 = 0; r4 < 4; ++r4) {
        float s = p[r4];
        s += __shfl_xor(s, 1, 64); s += __shfl_xor(s, 2, 64);
        s += __shfl_xor(s, 4, 64); s += __shfl_xor(s, 8, 64);
        if ((lane & 15) == 0) {
          long row = m0 + wv * 32 + rt * 16 + ((lane >> 4) << 2) + r4;
          out[(long)g * M + row] = s + ab;
        }
      }
    }
  }
}

// ---------------------------------------------------------------------------
// bidat_fused: S = avU @ pv^T (MFMA, computed ONCE), then
//   SCA[n] += am[n] * sum_l tanh(S) * (pm*q)[l]
//   SCP[l] += pm[l] * sum_n tanh(S) * (am*r)[n]
// Block: 128 n-rows x one batch; l range Ln/FLSP in chunks of 128.
// ---------------------------------------------------------------------------
__global__ __launch_bounds__(256) void bidat_fused(
    const u16* __restrict__ AVUbf,   // [Bn*Nn][128] bf16 (this iteration)
    const float* __restrict__ PV,    // [Bn][Ln][128] fp32
    const float* __restrict__ qv,    // [Bn*Ln]
    const float* __restrict__ rv,    // [Bn*Nn]
    const float* __restrict__ am, const float* __restrict__ pm,
    float* __restrict__ SCA, float* __restrict__ SCP)
{
  __shared__ u16 sU[128 * 128];
  __shared__ u16 sK[128 * 128];
  __shared__ float qm_s[128], pm_s[128], amr_s[128], am_sh[128];
  __shared__ float scp_red[4][128];
  int b = blockIdx.y;
  int n0 = blockIdx.x * 128;
  int tid = threadIdx.x, lane = tid & 63, wv = tid >> 6;

  for (int q = tid; q < 128 * 16; q += 256) {
    int r = q >> 4, c8 = (q & 15) << 3;
    *(u32x4*)((char*)sU + lofs<128>(r, c8)) =
        *(const u32x4*)(AVUbf + ((long)b * Nn + n0 + r) * 128 + c8);
  }
  if (tid < 128) {
    float amv = am[(long)b * Nn + n0 + tid];
    am_sh[tid] = amv;
    amr_s[tid] = amv * rv[(long)b * Nn + n0 + tid];
  }
  float sca_r[2][4] = {{0.f,0.f,0.f,0.f},{0.f,0.f,0.f,0.f}};
  const float* pvb = PV + (long)b * Ln * 128;
  int lbeg = blockIdx.z * (Ln / FLSP);

  for (int l0 = lbeg; l0 < lbeg + Ln / FLSP; l0 += 128) {
    __syncthreads();                       // protect sK / scp_red from prev
    for (int q = tid; q < 128 * 32; q += 256) {
      int r = q >> 5, c4 = (q & 31) << 2;
      float4 v = *(const float4*)(pvb + (long)(l0 + r) * 128 + c4);
      u16x4 h = { bfc(v.x), bfc(v.y), bfc(v.z), bfc(v.w) };
      *(u16x4*)((char*)sK + lofs<128>(r, c4)) = h;
    }
    if (tid < 128) {
      float pmv = pm[(long)b * Ln + l0 + tid];
      pm_s[tid] = pmv;
      qm_s[tid] = pmv * qv[(long)b * Ln + l0 + tid];
    }
    __syncthreads();
    for (int lt = 0; lt < 8; ++lt) {
      float sp = 0.f;
      float qmv = qm_s[lt * 16 + (lane & 15)];
#pragma unroll
      for (int rt = 0; rt < 2; ++rt) {
        f32x4 c = {0.f,0.f,0.f,0.f};
#pragma unroll
        for (int kk = 0; kk < 128; kk += 32) {
          int kf = kk + ((lane >> 4) << 3);
          short8v a = ldsv(sU, lofs<128>(wv * 32 + rt * 16 + (lane & 15), kf));
          short8v bb = ldsv(sK, lofs<128>(lt * 16 + (lane & 15), kf));
          c = MFMA(a, bb, c);
        }
#pragma unroll
        for (int r4 = 0; r4 < 4; ++r4) {
          int nr = wv * 32 + rt * 16 + ((lane >> 4) << 2) + r4;
          float t = tanhf(c[r4]);
          sca_r[rt][r4] += t * qmv;
          sp += t * amr_s[nr];
        }
      }
      sp += __shfl_xor(sp, 16, 64);
      sp += __shfl_xor(sp, 32, 64);
      if (lane < 16) scp_red[wv][lt * 16 + lane] = sp;
    }
    __syncthreads();
    if (tid < 128) {
      float v = scp_red[0][tid] + scp_red[1][tid] + scp_red[2][tid] + scp_red[3][tid];
      atomicAdd(&SCP[(long)b * Ln + l0 + tid], v * pm_s[tid]);
    }
  }
#pragma unroll
  for (int rt = 0; rt < 2; ++rt)
#pragma unroll
    for (int r4 = 0; r4 < 4; ++r4) {
      float s = sca_r[rt][r4];
      s += __shfl_xor(s, 1, 64); s += __shfl_xor(s, 2, 64);
      s += __shfl_xor(s, 4, 64); s += __shfl_xor(s, 8, 64);
      if ((lane & 15) == 0) {
        int nr = wv * 32 + rt * 16 + ((lane >> 4) << 2) + r4;
        atomicAdd(&SCA[(long)b * Nn + n0 + nr], s * am_sh[nr]);
      }
    }
}

// ---------------------------------------------------------------------------
// Legacy fp32 tiled matmul (head layers, K=386)
// ---------------------------------------------------------------------------
__global__ __launch_bounds__(256) void mm_kernel(
    const float* __restrict__ A, const float* __restrict__ Bm,
    const float* __restrict__ bias, float* __restrict__ C,
    int M, int N, int K, int lda, int ldb, int ldc, int colOff, int act)
{
  __shared__ float As[32][33];
  __shared__ float Bs[32][33];
  int tx = threadIdx.x, ty = threadIdx.y;
  int tid = ty * 16 + tx;
  int m0 = blockIdx.y * 32;
  int n0 = blockIdx.x * 32;
  float acc00 = 0.f, acc01 = 0.f, acc10 = 0.f, acc11 = 0.f;
  for (int k0 = 0; k0 < K; k0 += 32) {
#pragma unroll
    for (int t = 0; t < 4; ++t) {
      int li = tid + t * 256;
      int r = li >> 5, c = li & 31;
      int mm = m0 + r, kk = k0 + c;
      As[r][c] = (mm < M && kk < K) ? A[(long)mm * lda + kk] : 0.f;
      int kk2 = k0 + r, nn = n0 + c;
      Bs[r][c] = (kk2 < K && nn < N) ? Bm[(long)kk2 * ldb + nn] : 0.f;
    }
    __syncthreads();
#pragma unroll
    for (int kk = 0; kk < 32; ++kk) {
      float a0 = As[ty][kk], a1 = As[ty + 16][kk];
      float b0 = Bs[kk][tx], b1 = Bs[kk][tx + 16];
      acc00 += a0 * b0; acc01 += a0 * b1;
      acc10 += a1 * b0; acc11 += a1 * b1;
    }
    __syncthreads();
  }
  float accs[2][2] = {{acc00, acc01}, {acc10, acc11}};
#pragma unroll
  for (int i = 0; i < 2; ++i) {
    int m = m0 + ty + i * 16;
    if (m >= M) continue;
#pragma unroll
    for (int j = 0; j < 2; ++j) {
      int n = n0 + tx + j * 16;
      if (n >= N) continue;
      float v = accs[i][j];
      if (bias) v += bias[n];
      C[(long)m * ldc + colOff + n] = apply_act(v, act);
    }
  }
}

static void mm(hipStream_t st, const float* A, const float* Bm, const float* bias,
               float* C, int M, int N, int K, int lda, int ldb, int ldc,
               int colOff, int act)
{
  dim3 grid((N + 31) / 32, (M + 31) / 32), block(16, 16);
  mm_kernel<<<grid, block, 0, st>>>(A, Bm, bias, C, M, N, K, lda, ldb, ldc, colOff, act);
}

// ---------------------------------------------------------------------------
// f1/f2 = Wh . a[:F], Wh . a[F:]
// ---------------------------------------------------------------------------
__global__ void fvec_kernel(const float* __restrict__ Wh, const float* __restrict__ a,
                            float* __restrict__ f1, float* __restrict__ f2,
                            long rows, int F) {
  long r = (long)blockIdx.x * blockDim.x + threadIdx.x;
  if (r >= rows) return;
  const float* w = Wh + r * F;
  float s1 = 0.f, s2 = 0.f;
  for (int d = 0; d < F; ++d) { s1 += w[d] * a[d]; s2 += w[d] * a[F + d]; }
  f1[r] = s1; f2[r] = s2;
}

// ---------------------------------------------------------------------------
// Tiled GAT attention (validated r3)
// ---------------------------------------------------------------------------
template<int F>
__global__ __launch_bounds__(256) void gat_att_tiled_kernel(
    const float* __restrict__ Wh, int ldW, int cW,
    const float* __restrict__ f1, const float* __restrict__ f2,
    const int* __restrict__ adj, float* __restrict__ out, int ldo, int cO)
{
  __shared__ float sE[32][257];
  __shared__ float sW[32][(F == 64) ? 68 : 132];
  __shared__ float f1s[32];
  __shared__ float mrow[32], srow[32];
  __shared__ float pred[32][9];
  int b = blockIdx.y;
  int i0 = blockIdx.x * 32;
  int tx = threadIdx.x, ty = threadIdx.y;
  int tid = ty * 16 + tx;
  const long rowb = (long)b * Nn;

  if (tid < 32) f1s[tid] = f1[rowb + i0 + tid];
  float f2v = f2[rowb + tid];
  __syncthreads();
  for (int r = 0; r < 32; ++r) {
    float e = f1s[r] + f2v;
    e = e > 0.f ? e : 0.2f * e;
    int a = adj[(rowb + i0 + r) * Nn + tid];
    sE[r][tid] = (a > 0) ? e : -9e15f;
  }
  __syncthreads();
  {
    int r = tid >> 3, s = tid & 7;
    float m = -3.4e38f;
    for (int j = s; j < 256; j += 8) m = fmaxf(m, sE[r][j]);
    pred[r][s] = m;
  }
  __syncthreads();
  if (tid < 32) {
    float m = pred[tid][0];
#pragma unroll
    for (int s = 1; s < 8; ++s) m = fmaxf(m, pred[tid][s]);
    mrow[tid] = m;
  }
  __syncthreads();
  {
    int r = tid >> 3, s = tid & 7;
    float m = mrow[r];
    float sum = 0.f;
    for (int j = s; j < 256; j += 8) {
      float v = expf(sE[r][j] - m);
      sE[r][j] = v;
      sum += v;
    }
    pred[r][s] = sum;
  }
  __syncthreads();
  if (tid < 32) {
    float s = 0.f;
#pragma unroll
    for (int t = 0; t < 8; ++t) s += pred[tid][t];
    srow[tid] = 1.f / s;
  }
  __syncthreads();
  float acc[2][F / 16] = {};
  for (int k0 = 0; k0 < 256; k0 += 32) {
    for (int li = tid; li < 32 * F; li += 256) {
      int rr = li / F, cc = li % F;
      sW[rr][cc] = Wh[(rowb + k0 + rr) * (long)ldW + cW + cc];
    }
    __syncthreads();
#pragma unroll
    for (int kk = 0; kk < 32; ++kk) {
      float a0 = sE[ty][k0 + kk], a1 = sE[ty + 16][k0 + kk];
#pragma unroll
      for (int j = 0; j < F / 16; ++j) {
        float w = sW[kk][tx + j * 16];
        acc[0][j] += a0 * w;
        acc[1][j] += a1 * w;
      }
    }
    __syncthreads();
  }
#pragma unroll
  for (int ii = 0; ii < 2; ++ii) {
    int r = ty + ii * 16;
    float sc = srow[r];
#pragma unroll
    for (int j = 0; j < F / 16; ++j) {
      float v = acc[ii][j] * sc;
      v = v > 0.f ? v : expm1f(v);   // elu
      out[(rowb + i0 + r) * (long)ldo + cO + tx + j * 16] = v;
    }
  }
}

// ---------------------------------------------------------------------------
// 11x11 conv (validated r3)
// ---------------------------------------------------------------------------
__global__ __launch_bounds__(128) void conv11_kernel(
    const float* __restrict__ in, const float* __restrict__ kw,
    const float* __restrict__ bias_p, float* __restrict__ out)
{
  __shared__ float s[26][140];
  __shared__ float kk[121];
  int b = blockIdx.y;
  int l0 = blockIdx.x * 16;
  int tid = threadIdx.x;
  if (tid < 121) kk[tid] = kw[tid];
  const float* inb = in + (long)b * Ln * PROT;
  for (int r = 0; r < 26; ++r) {
    int l = l0 - 5 + r;
    for (int c = tid; c < 138; c += 128) {
      int p = c - 5;
      float v = 0.f;
      if (l >= 0 && l < Ln && p >= 0 && p < PROT) v = inb[(long)l * PROT + p];
      s[r][c] = v;
    }
  }
  __syncthreads();
  float bias = bias_p[0];
  float acc[16];
#pragma unroll
  for (int i = 0; i < 16; ++i) acc[i] = bias;
  int p = tid;
#pragma unroll
  for (int v = 0; v < 11; ++v) {
    float c[26];
#pragma unroll
    for (int u = 0; u < 26; ++u) c[u] = s[u][p + v];
#pragma unroll
    for (int u = 0; u < 11; ++u) {
      float w = kk[u * 11 + v];
#pragma unroll
      for (int i = 0; i < 16; ++i) acc[i] += c[i + u] * w;
    }
  }
  float* outb = out + (long)b * Ln * PROT;
#pragma unroll
  for (int i = 0; i < 16; ++i) {
    float vv = acc[i];
    outb[(long)(l0 + i) * PROT + p] = vv > 0.f ? vv : 0.2f * vv;
  }
}

// ---------------------------------------------------------------------------
// masked softmax
// ---------------------------------------------------------------------------
__global__ __launch_bounds__(256) void mask_softmax_kernel(
    const float* __restrict__ score, const float* __restrict__ mask,
    float* __restrict__ att, int n)
{
  int b = blockIdx.x;
  int tid = threadIdx.x;
  __shared__ float red[256];
  const float* s = score + (long)b * n;
  const float* mk = mask + (long)b * n;
  float mx = -3.4e38f;
  for (int i = tid; i < n; i += 256) mx = fmaxf(mx, s[i]);
  red[tid] = mx; __syncthreads();
  for (int st = 128; st > 0; st >>= 1) { if (tid < st) red[tid] = fmaxf(red[tid], red[tid + st]); __syncthreads(); }
  mx = red[0]; __syncthreads();
  float sum = 0.f;
  for (int i = tid; i < n; i += 256) sum += expf(s[i] - mx) * mk[i];
  red[tid] = sum; __syncthreads();
  for (int st = 128; st > 0; st >>= 1) { if (tid < st) red[tid] += red[tid + st]; __syncthreads(); }
  float denom = red[0] + 1e-6f;
  for (int i = tid; i < n; i += 256) att[(long)b * n + i] = expf(s[i] - mx) * mk[i] / denom;
}

// ---------------------------------------------------------------------------
// weighted sum (t-split + atomicAdd; out pre-zeroed)
// ---------------------------------------------------------------------------
__global__ __launch_bounds__(128) void wsum_kernel(
    const float* __restrict__ x, const float* __restrict__ att,
    float* __restrict__ out, int n, int colOff, int nsplit)
{
  int b = blockIdx.x;
  int sp = blockIdx.y;
  int d = threadIdx.x;
  int chunk = n / nsplit;
  int t0 = sp * chunk, t1 = t0 + chunk;
  const float* xb = x + (long)b * n * LT + d;
  const float* ab = att + (long)b * n;
  float acc = 0.f;
  for (int t = t0; t < t1; ++t) acc += xb[(long)t * LT] * ab[t];
  atomicAdd(&out[(long)b * 512 + colOff + d], acc);
}

__global__ __launch_bounds__(128) void assemble_v_kernel(
    const float* __restrict__ sf, const float* __restrict__ invT,
    const float* __restrict__ T, float* __restrict__ v)
{
  int b = blockIdx.x;
  int t = threadIdx.x;
  v[(long)b * DOUT + 128 + t] = sf[(long)b * LT + t];
  if (t == 0) { v[(long)b * DOUT + 384] = invT[b]; v[(long)b * DOUT + 385] = T[b]; }
}

// ---------------------------------------------------------------------------
extern "C" void kernel_launch(void* const* d_in, const int* in_sizes, int n_in,
                              void* d_out, int out_size, void* d_ws, size_t ws_size,
                              hipStream_t stream) {
  const long NB = (long)Bn * Nn;    // 16384
  const long LB = (long)Bn * Ln;    // 131072
  const long M1 = 1024 * 1024;

  const int*   atoms      = (const int*)d_in[0];
  const float* atoms_mask = (const float*)d_in[1];
  const int*   adj        = (const int*)d_in[2];
  const int*   amino      = (const int*)d_in[3];
  const float* amino_mask = (const float*)d_in[4];
  const float* fps        = (const float*)d_in[5];
  const float* invT       = (const float*)d_in[6];
  const float* Temp       = (const float*)d_in[7];
  const float* E_atom     = (const float*)d_in[8];
  const float* E_amino    = (const float*)d_in[9];
  const float* gatW       = (const float*)d_in[10];
  const float* gatA       = (const float*)d_in[11];
  const float* goW        = (const float*)d_in[12];
  const float* goA        = (const float*)d_in[13];
  const float* Wc_w       = (const float*)d_in[14];
  const float* Wc_b       = (const float*)d_in[15];
  const float* conv_k     = (const float*)d_in[16];
  const float* conv_b     = (const float*)d_in[17];
  const float* Wp_w       = (const float*)d_in[18];
  const float* Wp_b       = (const float*)d_in[19];
  const float* fp0        = (const float*)d_in[20];
  const float* fp1        = (const float*)d_in[21];
  const float* U          = (const float*)d_in[22];
  const float* t_c2p_w    = (const float*)d_in[23];
  const float* t_c2p_b    = (const float*)d_in[24];
  const float* t_p2c_w    = (const float*)d_in[25];
  const float* t_p2c_b    = (const float*)d_in[26];
  const float* bh_c_w     = (const float*)d_in[27];
  const float* bh_c_b     = (const float*)d_in[28];
  const float* bh_p_w     = (const float*)d_in[29];
  const float* bh_p_b     = (const float*)d_in[30];
  const float* ba_c_w     = (const float*)d_in[31];
  const float* ba_c_b     = (const float*)d_in[32];
  const float* ba_p_w     = (const float*)d_in[33];
  const float* ba_p_b     = (const float*)d_in[34];
  const float* comb_c_w   = (const float*)d_in[35];
  const float* comb_c_b   = (const float*)d_in[36];
  const float* comb_p_w   = (const float*)d_in[37];
  const float* comb_p_b   = (const float*)d_in[38];
  const float* Wout_w     = (const float*)d_in[39];
  const float* Wout_b     = (const float*)d_in[40];
  const float* out_w      = (const float*)d_in[41];
  const float* out_b      = (const float*)d_in[42];
  float* out = (float*)d_out;

  // ---------------- workspace layout ----------------
  float* ws = (float*)d_ws;
  long off = 0;
  float* AV   = ws + off; off += NB * LT;          // 2M
  float* PV   = ws + off; off += LB * LT;          // 16M
  float* SF   = ws + off; off += (long)Bn * LT;
  float* SFT  = ws + off; off += (long)Bn * LT;
  float* CF   = ws + off; off += (long)Bn * 512;   // CF then PF contiguous
  float* PF   = ws + off; off += (long)Bn * 512;
  float* F1   = ws + off; off += NB;
  float* F2   = ws + off; off += NB;
  float* ATTA = ws + off; off += NB;
  float* ATTP = ws + off; off += LB;
  float* V0   = ws + off; off += (long)Bn * DOUT;
  float* V1   = ws + off; off += (long)Bn * DOUT;
  float* POOL = ws + off;                          // 8.39M floats
  // GAT stage: AVE[0,2M) WH[2M,3M) MH[3M,7M) WH2[0,2M) G2[3M,5M)
  float* AVE = POOL;
  float* WH  = POOL + 2 * M1;
  float* MH  = POOL + 3 * M1;
  float* WH2 = POOL;
  float* G2  = POOL + 3 * M1;
  // CNN stage: PVA [0,4M)
  float* PVA = POOL;
  // BIDAT stage: AVUbf4 [0,4M), OUTP [4M,5.05M), OUTA after
  u16*   AVUbf4 = (u16*)POOL;                      // 4 * NB * 128 u16
  float* OUTP = POOL + 4 * M1;                     // [8][LB]: g<4 SCP1, g>=4 Q
  float* OUTA = OUTP + 8 * LB;                     // [8][NB]: g<4 SCA1, g>=4 R
  // Weight cache at [7M, ...):
  u16* WT = (u16*)(POOL + 7 * M1);
  long wo = 0;
  u16* gatW_t  = WT + wo; wo += 4L * 64 * 128;
  u16* goW_t   = WT + wo; wo += 128L * 256;
  u16* Wc_t    = WT + wo; wo += 128L * 128;
  u16* Wp_t    = WT + wo; wo += 128L * 128;
  u16* fp0_t   = WT + wo; wo += 128L * 1024;
  u16* fp1_t   = WT + wo; wo += 128L * 128;
  u16* U_t     = WT + wo; wo += 4L * 128 * 128;
  u16* wcat_a  = WT + wo; wo += 8L * 128 * 128;    // [bh_c(4) | t_c2p(4)]
  u16* wcat_p  = WT + wo; wo += 8L * 128 * 128;    // [bh_p(4) | t_p2c(4)]
  u16* combc_t = WT + wo; wo += 128L * 512;
  u16* combp_t = WT + wo; wo += 128L * 512;
  float* pk_a = (float*)(WT + wo);                 // 2056 floats
  float* pk_p = pk_a + 2056;

  // ======================= weight prep =======================
  {
    auto tp = [&](const float* s, u16* d, int K, int N, int cnt) {
      transp_kernel<<<dim3((unsigned)((K * N + 255) / 256), cnt), 256, 0, stream>>>(s, d, K, N);
    };
    tp(gatW, gatW_t, 128, 64, 4);
    tp(goW, goW_t, 256, 128, 1);
    tp(Wc_w, Wc_t, 128, 128, 1);
    tp(Wp_w, Wp_t, 128, 128, 1);
    tp(fp0, fp0_t, 1024, 128, 1);
    tp(fp1, fp1_t, 128, 128, 1);
    tp(U, U_t, 128, 128, 4);
    tp(bh_c_w, wcat_a, 128, 128, 4);
    tp(t_c2p_w, wcat_a + 4L * 16384, 128, 128, 4);
    tp(bh_p_w, wcat_p, 128, 128, 4);
    tp(t_p2c_w, wcat_p + 4L * 16384, 128, 128, 4);
    tp(comb_c_w, combc_t, 512, 128, 1);
    tp(comb_p_w, combp_t, 512, 128, 1);
    pack_kernel<<<dim3(9), 256, 0, stream>>>(bh_c_b, t_c2p_b, ba_c_w, ba_c_b,
                                             ba_p_w, bh_p_b, t_p2c_b, ba_p_b,
                                             pk_a, pk_p);
  }

  // ======================= comp GAT =======================
  embed_kernel<<<dim3((unsigned)((NB * CMP + 255) / 256)), 256, 0, stream>>>(
      atoms, E_atom, AVE, NB * CMP, CMP);
  for (int h = 0; h < NHEADS; ++h) {
    mmx<0, 0>(stream, AVE, gatW_t + (long)h * 64 * 128, nullptr, WH,
              (int)NB, 64, 128, 128, 64);
    fvec_kernel<<<dim3((unsigned)((NB + 255) / 256)), 256, 0, stream>>>(
        WH, gatA + (long)h * 2 * GF, F1, F2, NB, GF);
    gat_att_tiled_kernel<GF><<<dim3(Nn / 32, Bn), dim3(16, 16), 0, stream>>>(
        WH, GF, 0, F1, F2, adj, MH, 256, h * GF);
  }
  mmx<0, 0>(stream, MH, goW_t, nullptr, WH2, (int)NB, 128, 256, 256, 128);
  fvec_kernel<<<dim3((unsigned)((NB + 255) / 256)), 256, 0, stream>>>(
      WH2, goA, F1, F2, NB, CMP);
  gat_att_tiled_kernel<CMP><<<dim3(Nn / 32, Bn), dim3(16, 16), 0, stream>>>(
      WH2, CMP, 0, F1, F2, adj, G2, CMP, 0);
  mmx<1, 0>(stream, G2, Wc_t, Wc_b, AV, (int)NB, 128, 128, 128, 128);

  // ======================= prot CNN =======================
  for (int c = 0; c < NCH; ++c) {
    long b0 = (long)c * CB;
    float* PVc = PV + b0 * Ln * LT;
    long tot = (long)CB * Ln * PROT;
    embed_kernel<<<dim3((unsigned)((tot + 255) / 256)), 256, 0, stream>>>(
        amino + b0 * Ln, E_amino, PVA, tot, PROT);
    conv11_kernel<<<dim3(Ln / 16, CB), 128, 0, stream>>>(PVA, conv_k + 0 * 121, conv_b + 0, PVc);
    conv11_kernel<<<dim3(Ln / 16, CB), 128, 0, stream>>>(PVc, conv_k + 1 * 121, conv_b + 1, PVA);
    conv11_kernel<<<dim3(Ln / 16, CB), 128, 0, stream>>>(PVA, conv_k + 2 * 121, conv_b + 2, PVc);
    mmx<1, 0>(stream, PVc, Wp_t, Wp_b, PVc, (int)((long)CB * Ln), 128, 128, 128, 128);
  }

  // ======================= fingerprint =======================
  mmx<2, 0>(stream, fps, fp0_t, nullptr, SFT, Bn, 128, 1024, 1024, 128);
  mmx<2, 0>(stream, SFT, fp1_t, nullptr, SF, Bn, 128, 128, 128, 128);

  // ======================= bidirectional attention =======================
  // precompute: SCP1/Q (pv side), SCA1/R (av side), avU bf16 x4
  mmdot_kernel<<<dim3((unsigned)(LB / 128)), 256, 0, stream>>>(PV, wcat_p, pk_p, OUTP, LB);
  mmdot_kernel<<<dim3((unsigned)(NB / 128)), 256, 0, stream>>>(AV, wcat_a, pk_a, OUTA, NB);
  for (int i = 0; i < 4; ++i)
    mmx<0, 1>(stream, AV, U_t + (long)i * 16384, nullptr, AVUbf4 + (long)i * NB * 128,
              (int)NB, 128, 128, 128, 128);
  zero_kernel<<<dim3((unsigned)((2L * Bn * 512 + 255) / 256)), 256, 0, stream>>>(
      CF, 2L * Bn * 512);
  for (int i = 0; i < 4; ++i) {
    bidat_fused<<<dim3(Nn / 128, Bn, FLSP), 256, 0, stream>>>(
        AVUbf4 + (long)i * NB * 128, PV,
        OUTP + (long)(4 + i) * LB, OUTA + (long)(4 + i) * NB,
        atoms_mask, amino_mask,
        OUTA + (long)i * NB, OUTP + (long)i * LB);
    mask_softmax_kernel<<<Bn, 256, 0, stream>>>(OUTA + (long)i * NB, atoms_mask, ATTA, Nn);
    mask_softmax_kernel<<<Bn, 256, 0, stream>>>(OUTP + (long)i * LB, amino_mask, ATTP, Ln);
    wsum_kernel<<<dim3(Bn, 8), 128, 0, stream>>>(AV, ATTA, CF, Nn, i * LT, 8);
    wsum_kernel<<<dim3(Bn, 8), 128, 0, stream>>>(PV, ATTP, PF, Ln, i * LT, 8);
  }

  // ======================= head =======================
  mmx<0, 0>(stream, CF, combc_t, comb_c_b, V0, Bn, 128, 512, 512, DOUT, 0);
  mmx<0, 0>(stream, PF, combp_t, comb_p_b, V0, Bn, 128, 512, 512, DOUT, 256);
  assemble_v_kernel<<<Bn, 128, 0, stream>>>(SF, invT, Temp, V0);
  mm(stream, V0, Wout_w,                     Wout_b,            V1, Bn, DOUT, DOUT, DOUT, DOUT, DOUT, 0, 1);
  mm(stream, V1, Wout_w + (long)DOUT * DOUT, Wout_b + DOUT,     V0, Bn, DOUT, DOUT, DOUT, DOUT, DOUT, 0, 1);
  mm(stream, V0, Wout_w + 2L * DOUT * DOUT,  Wout_b + 2 * DOUT, V1, Bn, DOUT, DOUT, DOUT, DOUT, DOUT, 0, 1);
  mm(stream, V1, out_w, out_b, out, Bn, 1, DOUT, DOUT, 1, 1, 0, 0);
}

// Round 7
// 1471.646 us; speedup vs baseline: 12.3315x; 1.5060x over previous
//
#include <hip/hip_runtime.h>
#include <math.h>

// ---------------------------------------------------------------------------
// Model constants
// ---------------------------------------------------------------------------
#define Bn   64
#define Nn   256
#define Ln   2048
#define CMP  128
#define PROT 128
#define GF   64
#define NHEADS 4
#define LT   128
#define DOUT 386   // 3*LATENT + 2
#define CB   32    // batch chunk (CNN staging)
#define NCH  (Bn / CB)
#define FLSP 4     // bidat_fused l-split

typedef unsigned short u16;
typedef __attribute__((ext_vector_type(8))) short short8v;   // 8 bf16 (4 VGPRs)
typedef __attribute__((ext_vector_type(4))) float f32x4;
typedef __attribute__((ext_vector_type(4))) unsigned short u16x4;
typedef __attribute__((ext_vector_type(4))) unsigned int u32x4;

#define MFMA(a, b, c) __builtin_amdgcn_mfma_f32_16x16x32_bf16((a), (b), (c), 0, 0, 0)

__device__ __forceinline__ float apply_act(float v, int act) {
  if (act == 1) return v > 0.f ? v : 0.2f * v;   // lrelu ALPHA
  if (act == 2) return v > 0.f ? v : 0.1f * v;   // lrelu 0.1 (fingerprint)
  if (act == 3) return tanhf(v);
  return v;
}

__device__ __forceinline__ u16 bfc(float f) {    // fp32 -> bf16 RNE
  union { float f; unsigned u; } x; x.f = f;
  unsigned r = x.u + 0x7fffu + ((x.u >> 16) & 1u);
  return (u16)(r >> 16);
}

__device__ __forceinline__ float bf2f(u16 h) {
  union { unsigned u; float f; } x; x.u = ((unsigned)h) << 16; return x.f;
}

// fast tanh: 1 - 2/(e^{2x}+1); exact at saturation, ~1e-7 abs err
__device__ __forceinline__ float ftanh(float x) {
  float e = __expf(2.f * x);
  return 1.f - 2.f / (e + 1.f);
}

// byte offset into a [R][C] bf16 LDS tile, XOR-swizzled.
// C=128: rows stride 256B -> use 16 slots (r&15); C=64: 8 slots (r&7).
template<int C>
__device__ __forceinline__ int lofs(int r, int c) {
  if (C == 128) return ((r * C + c) * 2) ^ ((r & 15) << 4);
  return ((r * C + c) * 2) ^ ((r & 7) << 4);
}

__device__ __forceinline__ short8v ldsv(const u16* s, int byteofs) {
  return *(const short8v*)((const char*)s + byteofs);
}

// ---------------------------------------------------------------------------
// Embedding gather
// ---------------------------------------------------------------------------
__global__ void embed_kernel(const int* __restrict__ idx, const float* __restrict__ E,
                             float* __restrict__ out, long total, int C) {
  long i = (long)blockIdx.x * blockDim.x + threadIdx.x;
  if (i >= total) return;
  long r = i / C;
  int c = (int)(i - r * (long)C);
  out[i] = E[(long)idx[r] * C + c];
}

__global__ void zero_kernel(float* __restrict__ a, long n) {
  long i = (long)blockIdx.x * blockDim.x + threadIdx.x;
  if (i < n) a[i] = 0.f;
}

// ---------------------------------------------------------------------------
// Weight prep: dst[z][n*K + k] = bf16(src[z][k*N + n])
// ---------------------------------------------------------------------------
__global__ void transp_kernel(const float* __restrict__ src, u16* __restrict__ dst,
                              int K, int N) {
  long total = (long)K * N;
  long base = (long)blockIdx.y * total;
  long idx = (long)blockIdx.x * 256 + threadIdx.x;
  if (idx >= total) return;
  int k = (int)(idx % K);
  int n = (int)(idx / K);
  dst[base + idx] = bfc(src[base + (long)k * N + n]);
}

// batched 128x128 transposes from 8 distinct sources
struct Ptr8 { const float* p[8]; };
__global__ void transp8_kernel(Ptr8 srcs, u16* __restrict__ dst) {
  int y = blockIdx.y;
  int idx = blockIdx.x * 256 + threadIdx.x;   // 0..16383
  int k = idx & 127, n = idx >> 7;
  dst[(long)y * 16384 + idx] = bfc(srcs.p[y][k * 128 + n]);
}

// ---------------------------------------------------------------------------
// pack bvec/aw/ab for mmdot (unchanged semantics, r6-validated)
// ---------------------------------------------------------------------------
__global__ void pack_kernel(
    const float* __restrict__ bh_c_b, const float* __restrict__ t_c2p_b,
    const float* __restrict__ ba_c_w, const float* __restrict__ ba_c_b,
    const float* __restrict__ ba_p_w, const float* __restrict__ bh_p_b,
    const float* __restrict__ t_p2c_b, const float* __restrict__ ba_p_b,
    float* __restrict__ pk_a, float* __restrict__ pk_p)
{
  int idx = blockIdx.x * 256 + threadIdx.x;
  if (idx < 1024) {
    int g = idx >> 7, j = idx & 127;
    pk_a[idx] = g < 4 ? bh_c_b[g * 128 + j] : t_c2p_b[(g - 4) * 128 + j];
    pk_p[idx] = g < 4 ? bh_p_b[g * 128 + j] : t_p2c_b[(g - 4) * 128 + j];
  } else if (idx < 2048) {
    int k = idx - 1024; int g = k >> 7, j = k & 127;
    pk_a[idx] = g < 4 ? ba_c_w[g * 256 + j] : ba_p_w[(g - 4) * 256 + 128 + j];
    pk_p[idx] = g < 4 ? ba_p_w[g * 256 + j] : ba_c_w[(g - 4) * 256 + 128 + j];
  } else if (idx < 2056) {
    int g = idx - 2048;
    pk_a[idx] = g < 4 ? ba_c_b[g] : 0.f;
    pk_p[idx] = g < 4 ? ba_p_b[g] : 0.f;
  }
}

// ---------------------------------------------------------------------------
// MFMA GEMM: C = act(A @ B + bias).  A fp32 [M,K], Bt bf16 [N,K].
// OUT=0: fp32 C[row*ldc+colOff+col];  OUT=1: bf16 C[row*ldc+col]
// ---------------------------------------------------------------------------
template<int ACT, int OUT>
__global__ __launch_bounds__(256) void mfma_mm_kernel(
    const float* __restrict__ A, const u16* __restrict__ Bt,
    const float* __restrict__ bias, void* __restrict__ Cp,
    int M, int N, int K, int lda, int ldc, int colOff)
{
  __shared__ u16 sA[64 * 64];
  __shared__ u16 sB[64 * 64];
  int m0 = blockIdx.y * 64, n0 = blockIdx.x * 64;
  int tid = threadIdx.x, lane = tid & 63, wv = tid >> 6;
  int mh = wv >> 1, nh = wv & 1;
  f32x4 acc00 = {0.f,0.f,0.f,0.f};
  f32x4 acc01 = acc00, acc10 = acc00, acc11 = acc00;
  for (int k0 = 0; k0 < K; k0 += 64) {
#pragma unroll
    for (int q = tid; q < 64 * 16; q += 256) {
      int r = q >> 4, c4 = (q & 15) << 2;
      float4 v = *(const float4*)(A + (long)(m0 + r) * lda + k0 + c4);
      u16x4 h = { bfc(v.x), bfc(v.y), bfc(v.z), bfc(v.w) };
      *(u16x4*)((char*)sA + lofs<64>(r, c4)) = h;
    }
#pragma unroll
    for (int q = tid; q < 64 * 8; q += 256) {
      int r = q >> 3, c8 = (q & 7) << 3;
      *(u32x4*)((char*)sB + lofs<64>(r, c8)) =
          *(const u32x4*)(Bt + (long)(n0 + r) * K + k0 + c8);
    }
    __syncthreads();
#pragma unroll
    for (int kk = 0; kk < 64; kk += 32) {
      int kf = kk + ((lane >> 4) << 3);
      short8v a0 = ldsv(sA, lofs<64>(mh * 32 + (lane & 15), kf));
      short8v a1 = ldsv(sA, lofs<64>(mh * 32 + 16 + (lane & 15), kf));
      short8v b0 = ldsv(sB, lofs<64>(nh * 32 + (lane & 15), kf));
      short8v b1 = ldsv(sB, lofs<64>(nh * 32 + 16 + (lane & 15), kf));
      acc00 = MFMA(a0, b0, acc00);
      acc01 = MFMA(a0, b1, acc01);
      acc10 = MFMA(a1, b0, acc10);
      acc11 = MFMA(a1, b1, acc11);
    }
    __syncthreads();
  }
#pragma unroll
  for (int rt = 0; rt < 2; ++rt) {
#pragma unroll
    for (int ct = 0; ct < 2; ++ct) {
      f32x4 a = rt == 0 ? (ct == 0 ? acc00 : acc01) : (ct == 0 ? acc10 : acc11);
      int col = n0 + nh * 32 + ct * 16 + (lane & 15);
      float bv = bias ? bias[col] : 0.f;
#pragma unroll
      for (int r4 = 0; r4 < 4; ++r4) {
        int row = m0 + mh * 32 + rt * 16 + ((lane >> 4) << 2) + r4;
        float v = apply_act(a[r4] + bv, ACT);
        if (OUT == 0)
          ((float*)Cp)[(long)row * ldc + colOff + col] = v;
        else
          ((u16*)Cp)[(long)row * ldc + col] = bfc(v);
      }
    }
  }
}

template<int ACT, int OUT>
static void mmx(hipStream_t st, const float* A, const u16* Bt, const float* bias,
                void* C, int M, int N, int K, int lda, int ldc, int colOff = 0)
{
  dim3 grid(N / 64, M / 64);
  mfma_mm_kernel<ACT, OUT><<<grid, dim3(256), 0, st>>>(
      A, Bt, bias, C, M, N, K, lda, ldc, colOff);
}

// ---------------------------------------------------------------------------
// mmdot v2: out[g][row] = sum_col ftanh((X@W_g)[row,col]+bvec)*aw + ab
// grid (M/128, 2): y selects 4 groups.  W staged in 64-row halves (48KB LDS).
// ---------------------------------------------------------------------------
__global__ __launch_bounds__(256) void mmdot_kernel(
    const float* __restrict__ X, const u16* __restrict__ Wcat,
    const float* __restrict__ pk, float* __restrict__ out, long M)
{
  __shared__ u16 sX[128 * 128];    // 32 KB
  __shared__ u16 sW[64 * 128];     // 16 KB
  __shared__ float bv_s[64], aw_s[64];
  long m0 = (long)blockIdx.x * 128;
  int g0 = blockIdx.y * 4;
  int tid = threadIdx.x, lane = tid & 63, wv = tid >> 6;
  for (int q = tid; q < 128 * 32; q += 256) {
    int r = q >> 5, c4 = (q & 31) << 2;
    float4 v = *(const float4*)(X + (m0 + r) * 128 + c4);
    u16x4 h = { bfc(v.x), bfc(v.y), bfc(v.z), bfc(v.w) };
    *(u16x4*)((char*)sX + lofs<128>(r, c4)) = h;
  }
  for (int gi = 0; gi < 4; ++gi) {
    int g = g0 + gi;
    float p[2][4] = {{0.f,0.f,0.f,0.f},{0.f,0.f,0.f,0.f}};
    for (int hh = 0; hh < 2; ++hh) {
      __syncthreads();                 // sX ready / protect sW+bv reuse
      for (int q = tid; q < 64 * 16; q += 256) {
        int r = q >> 4, c8 = (q & 15) << 3;
        *(u32x4*)((char*)sW + lofs<128>(r, c8)) =
            *(const u32x4*)(Wcat + (long)g * 16384 + (long)(hh * 64 + r) * 128 + c8);
      }
      if (tid < 64) {
        bv_s[tid] = pk[g * 128 + hh * 64 + tid];
        aw_s[tid] = pk[1024 + g * 128 + hh * 64 + tid];
      }
      __syncthreads();
      for (int lt = 0; lt < 4; ++lt) {
        int col = lt * 16 + (lane & 15);
        float bv = bv_s[col], awv = aw_s[col];
#pragma unroll
        for (int rt = 0; rt < 2; ++rt) {
          f32x4 c = {0.f,0.f,0.f,0.f};
#pragma unroll
          for (int kk = 0; kk < 128; kk += 32) {
            int kf = kk + ((lane >> 4) << 3);
            short8v a = ldsv(sX, lofs<128>(wv * 32 + rt * 16 + (lane & 15), kf));
            short8v bb = ldsv(sW, lofs<128>(lt * 16 + (lane & 15), kf));
            c = MFMA(a, bb, c);
          }
#pragma unroll
          for (int r4 = 0; r4 < 4; ++r4)
            p[rt][r4] += ftanh(c[r4] + bv) * awv;
        }
      }
    }
    float ab = pk[2048 + g];
#pragma unroll
    for (int rt = 0; rt < 2; ++rt)
#pragma unroll
      for (int r4 = 0; r4 < 4; ++r4) {
        float s = p[rt][r4];
        s += __shfl_xor(s, 1, 64); s += __shfl_xor(s, 2, 64);
        s += __shfl_xor(s, 4, 64); s += __shfl_xor(s, 8, 64);
        if ((lane & 15) == 0) {
          long row = m0 + wv * 32 + rt * 16 + ((lane >> 4) << 2) + r4;
          out[(long)g * M + row] = s + ab;
        }
      }
  }
}

// ---------------------------------------------------------------------------
// bidat_fused (4 iterations merged): blockIdx.z = lz*4 + it
// ---------------------------------------------------------------------------
__global__ __launch_bounds__(256) void bidat_fused(
    const u16* __restrict__ AVUbf4,  // [4][Bn*Nn][128] bf16
    const float* __restrict__ PV,    // [Bn][Ln][128] fp32
    float* __restrict__ OUTP,        // [8][Bn*Ln]: g<4 SCP, g>=4 q
    float* __restrict__ OUTA,        // [8][Bn*Nn]: g<4 SCA, g>=4 r
    const float* __restrict__ am, const float* __restrict__ pm)
{
  __shared__ u16 sU[128 * 128];
  __shared__ u16 sK[128 * 128];
  __shared__ float qm_s[128], pm_s[128], amr_s[128], am_sh[128];
  __shared__ float scp_red[4][128];
  const long NBt = (long)Bn * Nn, LBt = (long)Bn * Ln;
  int b = blockIdx.y;
  int n0 = blockIdx.x * 128;
  int zz = blockIdx.z;
  int it = zz & 3, lz = zz >> 2;
  const u16* AVUbf = AVUbf4 + (long)it * NBt * 128;
  const float* qv = OUTP + (long)(4 + it) * LBt;
  const float* rv = OUTA + (long)(4 + it) * NBt;
  float* SCA = OUTA + (long)it * NBt;
  float* SCP = OUTP + (long)it * LBt;
  int tid = threadIdx.x, lane = tid & 63, wv = tid >> 6;

  for (int q = tid; q < 128 * 16; q += 256) {
    int r = q >> 4, c8 = (q & 15) << 3;
    *(u32x4*)((char*)sU + lofs<128>(r, c8)) =
        *(const u32x4*)(AVUbf + ((long)b * Nn + n0 + r) * 128 + c8);
  }
  if (tid < 128) {
    float amv = am[(long)b * Nn + n0 + tid];
    am_sh[tid] = amv;
    amr_s[tid] = amv * rv[(long)b * Nn + n0 + tid];
  }
  float sca_r[2][4] = {{0.f,0.f,0.f,0.f},{0.f,0.f,0.f,0.f}};
  const float* pvb = PV + (long)b * Ln * 128;
  int lbeg = lz * (Ln / FLSP);

  for (int l0 = lbeg; l0 < lbeg + Ln / FLSP; l0 += 128) {
    __syncthreads();                       // protect sK / scp_red from prev
    for (int q = tid; q < 128 * 32; q += 256) {
      int r = q >> 5, c4 = (q & 31) << 2;
      float4 v = *(const float4*)(pvb + (long)(l0 + r) * 128 + c4);
      u16x4 h = { bfc(v.x), bfc(v.y), bfc(v.z), bfc(v.w) };
      *(u16x4*)((char*)sK + lofs<128>(r, c4)) = h;
    }
    if (tid < 128) {
      float pmv = pm[(long)b * Ln + l0 + tid];
      pm_s[tid] = pmv;
      qm_s[tid] = pmv * qv[(long)b * Ln + l0 + tid];
    }
    __syncthreads();
    for (int lt = 0; lt < 8; ++lt) {
      float sp = 0.f;
      float qmv = qm_s[lt * 16 + (lane & 15)];
#pragma unroll
      for (int rt = 0; rt < 2; ++rt) {
        f32x4 c = {0.f,0.f,0.f,0.f};
#pragma unroll
        for (int kk = 0; kk < 128; kk += 32) {
          int kf = kk + ((lane >> 4) << 3);
          short8v a = ldsv(sU, lofs<128>(wv * 32 + rt * 16 + (lane & 15), kf));
          short8v bb = ldsv(sK, lofs<128>(lt * 16 + (lane & 15), kf));
          c = MFMA(a, bb, c);
        }
#pragma unroll
        for (int r4 = 0; r4 < 4; ++r4) {
          int nr = wv * 32 + rt * 16 + ((lane >> 4) << 2) + r4;
          float t = ftanh(c[r4]);
          sca_r[rt][r4] += t * qmv;
          sp += t * amr_s[nr];
        }
      }
      sp += __shfl_xor(sp, 16, 64);
      sp += __shfl_xor(sp, 32, 64);
      if (lane < 16) scp_red[wv][lt * 16 + lane] = sp;
    }
    __syncthreads();
    if (tid < 128) {
      float v = scp_red[0][tid] + scp_red[1][tid] + scp_red[2][tid] + scp_red[3][tid];
      atomicAdd(&SCP[(long)b * Ln + l0 + tid], v * pm_s[tid]);
    }
  }
#pragma unroll
  for (int rt = 0; rt < 2; ++rt)
#pragma unroll
    for (int r4 = 0; r4 < 4; ++r4) {
      float s = sca_r[rt][r4];
      s += __shfl_xor(s, 1, 64); s += __shfl_xor(s, 2, 64);
      s += __shfl_xor(s, 4, 64); s += __shfl_xor(s, 8, 64);
      if ((lane & 15) == 0) {
        int nr = wv * 32 + rt * 16 + ((lane >> 4) << 2) + r4;
        atomicAdd(&SCA[(long)b * Nn + n0 + nr], s * am_sh[nr]);
      }
    }
}

// ---------------------------------------------------------------------------
// Legacy fp32 tiled matmul (head layers, K=386)
// ---------------------------------------------------------------------------
__global__ __launch_bounds__(256) void mm_kernel(
    const float* __restrict__ A, const float* __restrict__ Bm,
    const float* __restrict__ bias, float* __restrict__ C,
    int M, int N, int K, int lda, int ldb, int ldc, int colOff, int act)
{
  __shared__ float As[32][33];
  __shared__ float Bs[32][33];
  int tx = threadIdx.x, ty = threadIdx.y;
  int tid = ty * 16 + tx;
  int m0 = blockIdx.y * 32;
  int n0 = blockIdx.x * 32;
  float acc00 = 0.f, acc01 = 0.f, acc10 = 0.f, acc11 = 0.f;
  for (int k0 = 0; k0 < K; k0 += 32) {
#pragma unroll
    for (int t = 0; t < 4; ++t) {
      int li = tid + t * 256;
      int r = li >> 5, c = li & 31;
      int mm = m0 + r, kk = k0 + c;
      As[r][c] = (mm < M && kk < K) ? A[(long)mm * lda + kk] : 0.f;
      int kk2 = k0 + r, nn = n0 + c;
      Bs[r][c] = (kk2 < K && nn < N) ? Bm[(long)kk2 * ldb + nn] : 0.f;
    }
    __syncthreads();
#pragma unroll
    for (int kk = 0; kk < 32; ++kk) {
      float a0 = As[ty][kk], a1 = As[ty + 16][kk];
      float b0 = Bs[kk][tx], b1 = Bs[kk][tx + 16];
      acc00 += a0 * b0; acc01 += a0 * b1;
      acc10 += a1 * b0; acc11 += a1 * b1;
    }
    __syncthreads();
  }
  float accs[2][2] = {{acc00, acc01}, {acc10, acc11}};
#pragma unroll
  for (int i = 0; i < 2; ++i) {
    int m = m0 + ty + i * 16;
    if (m >= M) continue;
#pragma unroll
    for (int j = 0; j < 2; ++j) {
      int n = n0 + tx + j * 16;
      if (n >= N) continue;
      float v = accs[i][j];
      if (bias) v += bias[n];
      C[(long)m * ldc + colOff + n] = apply_act(v, act);
    }
  }
}

static void mm(hipStream_t st, const float* A, const float* Bm, const float* bias,
               float* C, int M, int N, int K, int lda, int ldb, int ldc,
               int colOff, int act)
{
  dim3 grid((N + 31) / 32, (M + 31) / 32), block(16, 16);
  mm_kernel<<<grid, block, 0, st>>>(A, Bm, bias, C, M, N, K, lda, ldb, ldc, colOff, act);
}

// ---------------------------------------------------------------------------
// f1/f2 = Wh_h . a_h[:F], Wh_h . a_h[F:]   (bf16 Wh; grid.y = head)
// ---------------------------------------------------------------------------
__global__ void fvec_kernel(const u16* __restrict__ Wh, int ldW, int F,
                            const float* __restrict__ a,
                            float* __restrict__ f1, float* __restrict__ f2,
                            long rows) {
  int h = blockIdx.y;
  long r = (long)blockIdx.x * blockDim.x + threadIdx.x;
  if (r >= rows) return;
  const u16* w = Wh + r * ldW + h * F;
  const float* av = a + (long)h * 2 * F;
  float s1 = 0.f, s2 = 0.f;
  for (int d = 0; d < F; ++d) {
    float wv = bf2f(w[d]);
    s1 += wv * av[d]; s2 += wv * av[F + d];
  }
  f1[(long)h * rows + r] = s1; f2[(long)h * rows + r] = s2;
}

// ---------------------------------------------------------------------------
// Tiled GAT attention (bf16 Wh input, grid.z = head)
// ---------------------------------------------------------------------------
template<int F>
__global__ __launch_bounds__(256) void gat_att_tiled_kernel(
    const u16* __restrict__ Wh, int ldW,
    const float* __restrict__ f1, const float* __restrict__ f2,
    const int* __restrict__ adj, float* __restrict__ out, int ldo)
{
  __shared__ float sE[32][257];
  __shared__ float sW[32][(F == 64) ? 68 : 132];
  __shared__ float f1s[32];
  __shared__ float mrow[32], srow[32];
  __shared__ float pred[32][9];
  int b = blockIdx.y;
  int i0 = blockIdx.x * 32;
  int h = blockIdx.z;
  int cW = h * F, cO = h * F;
  int tx = threadIdx.x, ty = threadIdx.y;
  int tid = ty * 16 + tx;
  const long rowb = (long)b * Nn;
  const float* f1h = f1 + (long)h * Bn * Nn;
  const float* f2h = f2 + (long)h * Bn * Nn;

  if (tid < 32) f1s[tid] = f1h[rowb + i0 + tid];
  float f2v = f2h[rowb + tid];
  __syncthreads();
  for (int r = 0; r < 32; ++r) {
    float e = f1s[r] + f2v;
    e = e > 0.f ? e : 0.2f * e;
    int a = adj[(rowb + i0 + r) * Nn + tid];
    sE[r][tid] = (a > 0) ? e : -9e15f;
  }
  __syncthreads();
  {
    int r = tid >> 3, s = tid & 7;
    float m = -3.4e38f;
    for (int j = s; j < 256; j += 8) m = fmaxf(m, sE[r][j]);
    pred[r][s] = m;
  }
  __syncthreads();
  if (tid < 32) {
    float m = pred[tid][0];
#pragma unroll
    for (int s = 1; s < 8; ++s) m = fmaxf(m, pred[tid][s]);
    mrow[tid] = m;
  }
  __syncthreads();
  {
    int r = tid >> 3, s = tid & 7;
    float m = mrow[r];
    float sum = 0.f;
    for (int j = s; j < 256; j += 8) {
      float v = __expf(sE[r][j] - m);
      sE[r][j] = v;
      sum += v;
    }
    pred[r][s] = sum;
  }
  __syncthreads();
  if (tid < 32) {
    float s = 0.f;
#pragma unroll
    for (int t = 0; t < 8; ++t) s += pred[tid][t];
    srow[tid] = 1.f / s;
  }
  __syncthreads();
  float acc[2][F / 16] = {};
  for (int k0 = 0; k0 < 256; k0 += 32) {
    for (int li = tid; li < 32 * F; li += 256) {
      int rr = li / F, cc = li % F;
      sW[rr][cc] = bf2f(Wh[(rowb + k0 + rr) * (long)ldW + cW + cc]);
    }
    __syncthreads();
#pragma unroll
    for (int kk = 0; kk < 32; ++kk) {
      float a0 = sE[ty][k0 + kk], a1 = sE[ty + 16][k0 + kk];
#pragma unroll
      for (int j = 0; j < F / 16; ++j) {
        float w = sW[kk][tx + j * 16];
        acc[0][j] += a0 * w;
        acc[1][j] += a1 * w;
      }
    }
    __syncthreads();
  }
#pragma unroll
  for (int ii = 0; ii < 2; ++ii) {
    int r = ty + ii * 16;
    float sc = srow[r];
#pragma unroll
    for (int j = 0; j < F / 16; ++j) {
      float v = acc[ii][j] * sc;
      v = v > 0.f ? v : expm1f(v);   // elu
      out[(rowb + i0 + r) * (long)ldo + cO + tx + j * 16] = v;
    }
  }
}

// ---------------------------------------------------------------------------
// 11x11 conv (validated r3)
// ---------------------------------------------------------------------------
__global__ __launch_bounds__(128) void conv11_kernel(
    const float* __restrict__ in, const float* __restrict__ kw,
    const float* __restrict__ bias_p, float* __restrict__ out)
{
  __shared__ float s[26][140];
  __shared__ float kk[121];
  int b = blockIdx.y;
  int l0 = blockIdx.x * 16;
  int tid = threadIdx.x;
  if (tid < 121) kk[tid] = kw[tid];
  const float* inb = in + (long)b * Ln * PROT;
  for (int r = 0; r < 26; ++r) {
    int l = l0 - 5 + r;
    for (int c = tid; c < 138; c += 128) {
      int p = c - 5;
      float v = 0.f;
      if (l >= 0 && l < Ln && p >= 0 && p < PROT) v = inb[(long)l * PROT + p];
      s[r][c] = v;
    }
  }
  __syncthreads();
  float bias = bias_p[0];
  float acc[16];
#pragma unroll
  for (int i = 0; i < 16; ++i) acc[i] = bias;
  int p = tid;
#pragma unroll
  for (int v = 0; v < 11; ++v) {
    float c[26];
#pragma unroll
    for (int u = 0; u < 26; ++u) c[u] = s[u][p + v];
#pragma unroll
    for (int u = 0; u < 11; ++u) {
      float w = kk[u * 11 + v];
#pragma unroll
      for (int i = 0; i < 16; ++i) acc[i] += c[i + u] * w;
    }
  }
  float* outb = out + (long)b * Ln * PROT;
#pragma unroll
  for (int i = 0; i < 16; ++i) {
    float vv = acc[i];
    outb[(long)(l0 + i) * PROT + p] = vv > 0.f ? vv : 0.2f * vv;
  }
}

// ---------------------------------------------------------------------------
// masked softmax (grid.y = iteration; stride = gridDim.x*n)
// ---------------------------------------------------------------------------
__global__ __launch_bounds__(256) void mask_softmax_kernel(
    const float* __restrict__ score, const float* __restrict__ mask,
    float* __restrict__ att, int n)
{
  int b = blockIdx.x;
  long st = (long)blockIdx.y * gridDim.x * n;
  int tid = threadIdx.x;
  __shared__ float red[256];
  const float* s = score + st + (long)b * n;
  const float* mk = mask + (long)b * n;
  float mx = -3.4e38f;
  for (int i = tid; i < n; i += 256) mx = fmaxf(mx, s[i]);
  red[tid] = mx; __syncthreads();
  for (int stp = 128; stp > 0; stp >>= 1) { if (tid < stp) red[tid] = fmaxf(red[tid], red[tid + stp]); __syncthreads(); }
  mx = red[0]; __syncthreads();
  float sum = 0.f;
  for (int i = tid; i < n; i += 256) sum += __expf(s[i] - mx) * mk[i];
  red[tid] = sum; __syncthreads();
  for (int stp = 128; stp > 0; stp >>= 1) { if (tid < stp) red[tid] += red[tid + stp]; __syncthreads(); }
  float denom = red[0] + 1e-6f;
  for (int i = tid; i < n; i += 256)
    att[st + (long)b * n + i] = __expf(s[i] - mx) * mk[i] / denom;
}

// ---------------------------------------------------------------------------
// weighted sum (grid.z = iteration; t-split via grid.y; out pre-zeroed)
// ---------------------------------------------------------------------------
__global__ __launch_bounds__(128) void wsum_kernel(
    const float* __restrict__ x, const float* __restrict__ att,
    float* __restrict__ out, int n, int nsplit)
{
  int b = blockIdx.x;
  int sp = blockIdx.y;
  int it = blockIdx.z;
  int d = threadIdx.x;
  int chunk = n / nsplit;
  int t0 = sp * chunk, t1 = t0 + chunk;
  const float* xb = x + (long)b * n * LT + d;
  const float* ab = att + (long)it * gridDim.x * n + (long)b * n;
  float acc = 0.f;
#pragma unroll 8
  for (int t = t0; t < t1; ++t) acc += xb[(long)t * LT] * ab[t];
  atomicAdd(&out[(long)b * 512 + it * LT + d], acc);
}

__global__ __launch_bounds__(128) void assemble_v_kernel(
    const float* __restrict__ sf, const float* __restrict__ invT,
    const float* __restrict__ T, float* __restrict__ v)
{
  int b = blockIdx.x;
  int t = threadIdx.x;
  v[(long)b * DOUT + 128 + t] = sf[(long)b * LT + t];
  if (t == 0) { v[(long)b * DOUT + 384] = invT[b]; v[(long)b * DOUT + 385] = T[b]; }
}

// ---------------------------------------------------------------------------
extern "C" void kernel_launch(void* const* d_in, const int* in_sizes, int n_in,
                              void* d_out, int out_size, void* d_ws, size_t ws_size,
                              hipStream_t stream) {
  const long NB = (long)Bn * Nn;    // 16384
  const long LB = (long)Bn * Ln;    // 131072
  const long M1 = 1024 * 1024;

  const int*   atoms      = (const int*)d_in[0];
  const float* atoms_mask = (const float*)d_in[1];
  const int*   adj        = (const int*)d_in[2];
  const int*   amino      = (const int*)d_in[3];
  const float* amino_mask = (const float*)d_in[4];
  const float* fps        = (const float*)d_in[5];
  const float* invT       = (const float*)d_in[6];
  const float* Temp       = (const float*)d_in[7];
  const float* E_atom     = (const float*)d_in[8];
  const float* E_amino    = (const float*)d_in[9];
  const float* gatW       = (const float*)d_in[10];
  const float* gatA       = (const float*)d_in[11];
  const float* goW        = (const float*)d_in[12];
  const float* goA        = (const float*)d_in[13];
  const float* Wc_w       = (const float*)d_in[14];
  const float* Wc_b       = (const float*)d_in[15];
  const float* conv_k     = (const float*)d_in[16];
  const float* conv_b     = (const float*)d_in[17];
  const float* Wp_w       = (const float*)d_in[18];
  const float* Wp_b       = (const float*)d_in[19];
  const float* fp0        = (const float*)d_in[20];
  const float* fp1        = (const float*)d_in[21];
  const float* U          = (const float*)d_in[22];
  const float* t_c2p_w    = (const float*)d_in[23];
  const float* t_c2p_b    = (const float*)d_in[24];
  const float* t_p2c_w    = (const float*)d_in[25];
  const float* t_p2c_b    = (const float*)d_in[26];
  const float* bh_c_w     = (const float*)d_in[27];
  const float* bh_c_b     = (const float*)d_in[28];
  const float* bh_p_w     = (const float*)d_in[29];
  const float* bh_p_b     = (const float*)d_in[30];
  const float* ba_c_w     = (const float*)d_in[31];
  const float* ba_c_b     = (const float*)d_in[32];
  const float* ba_p_w     = (const float*)d_in[33];
  const float* ba_p_b     = (const float*)d_in[34];
  const float* comb_c_w   = (const float*)d_in[35];
  const float* comb_c_b   = (const float*)d_in[36];
  const float* comb_p_w   = (const float*)d_in[37];
  const float* comb_p_b   = (const float*)d_in[38];
  const float* Wout_w     = (const float*)d_in[39];
  const float* Wout_b     = (const float*)d_in[40];
  const float* out_w      = (const float*)d_in[41];
  const float* out_b      = (const float*)d_in[42];
  float* out = (float*)d_out;

  // ---------------- workspace layout ----------------
  float* ws = (float*)d_ws;
  long off = 0;
  float* AV    = ws + off; off += NB * LT;          // 2M
  float* PV    = ws + off; off += LB * LT;          // 16M
  float* SF    = ws + off; off += (long)Bn * LT;
  float* SFT   = ws + off; off += (long)Bn * LT;
  float* CF    = ws + off; off += (long)Bn * 512;   // CF then PF contiguous
  float* PF    = ws + off; off += (long)Bn * 512;
  float* F1    = ws + off; off += 4 * NB;
  float* F2    = ws + off; off += 4 * NB;
  float* ATTA4 = ws + off; off += 4 * NB;
  float* ATTP4 = ws + off; off += 4 * LB;
  float* V0    = ws + off; off += (long)Bn * DOUT;
  float* V1    = ws + off; off += (long)Bn * DOUT;
  // weight cache (persistent, outside pool)
  u16* WT = (u16*)(ws + off);
  long wo = 0;
  u16* gatW_t  = WT + wo; wo += 4L * 64 * 128;      // [256][128]
  u16* goW_t   = WT + wo; wo += 128L * 256;
  u16* T23     = WT + wo; wo += 23L * 16384;
  u16* fp0_t   = WT + wo; wo += 128L * 1024;
  u16* combc_t = WT + wo; wo += 128L * 512;
  u16* combp_t = WT + wo; wo += 128L * 512;
  off += (wo + 1) / 2;
  float* pk_a = ws + off; off += 2056;
  float* pk_p = ws + off; off += 2056;
  float* POOL = ws + off;                           // 8.39M floats
  u16* Wc_t   = T23;
  u16* Wp_t   = T23 + 16384;
  u16* fp1_t  = T23 + 2L * 16384;
  u16* U_t    = T23 + 3L * 16384;                   // 4 mats
  u16* wcat_a = T23 + 7L * 16384;                   // [bh_c(4) | t_c2p(4)]
  u16* wcat_p = T23 + 15L * 16384;                  // [bh_p(4) | t_p2c(4)]
  // pool aliases:
  float* AVE   = POOL;                              // [0,2M)
  u16*   WH4bf = (u16*)(POOL + 2 * M1);             // NB*256 u16 -> [2M,4M)
  float* MH    = POOL + 4 * M1;                     // [4M,8M)
  u16*   WH2bf = (u16*)POOL;                        // [0,1M)
  float* G2    = POOL + 4 * M1;                     // [4M,6M) (MH dead)
  float* PVA   = POOL;                              // CNN: [0,8M)
  u16*   AVUbf4 = (u16*)POOL;                       // [0,4M)
  float* OUTP  = POOL + 4 * M1;                     // [8][LB]
  float* OUTA  = POOL + 5 * M1;                     // [8][NB]

  // ======================= weight prep =======================
  transp_kernel<<<dim3(32, 4), 256, 0, stream>>>(gatW, gatW_t, 128, 64);
  transp_kernel<<<dim3(128), 256, 0, stream>>>(goW, goW_t, 256, 128);
  transp_kernel<<<dim3(512), 256, 0, stream>>>(fp0, fp0_t, 1024, 128);
  transp_kernel<<<dim3(256), 256, 0, stream>>>(comb_c_w, combc_t, 512, 128);
  transp_kernel<<<dim3(256), 256, 0, stream>>>(comb_p_w, combp_t, 512, 128);
  {
    Ptr8 a1 = {{Wc_w, Wp_w, fp1, U, U + 16384, U + 32768, U + 49152, bh_c_w}};
    Ptr8 a2 = {{bh_c_w + 16384, bh_c_w + 32768, bh_c_w + 49152,
                t_c2p_w, t_c2p_w + 16384, t_c2p_w + 32768, t_c2p_w + 49152,
                bh_p_w}};
    Ptr8 a3 = {{bh_p_w + 16384, bh_p_w + 32768, bh_p_w + 49152,
                t_p2c_w, t_p2c_w + 16384, t_p2c_w + 32768, t_p2c_w + 49152,
                bh_p_w}};
    transp8_kernel<<<dim3(64, 8), 256, 0, stream>>>(a1, T23);
    transp8_kernel<<<dim3(64, 8), 256, 0, stream>>>(a2, T23 + 8L * 16384);
    transp8_kernel<<<dim3(64, 7), 256, 0, stream>>>(a3, T23 + 16L * 16384);
  }
  pack_kernel<<<dim3(9), 256, 0, stream>>>(bh_c_b, t_c2p_b, ba_c_w, ba_c_b,
                                           ba_p_w, bh_p_b, t_p2c_b, ba_p_b,
                                           pk_a, pk_p);

  // ======================= comp GAT (heads batched) =======================
  embed_kernel<<<dim3((unsigned)((NB * CMP + 255) / 256)), 256, 0, stream>>>(
      atoms, E_atom, AVE, NB * CMP, CMP);
  mmx<0, 1>(stream, AVE, gatW_t, nullptr, WH4bf, (int)NB, 256, 128, 128, 256);
  fvec_kernel<<<dim3((unsigned)((NB + 255) / 256), 4), 256, 0, stream>>>(
      WH4bf, 256, GF, gatA, F1, F2, NB);
  gat_att_tiled_kernel<GF><<<dim3(Nn / 32, Bn, 4), dim3(16, 16), 0, stream>>>(
      WH4bf, 256, F1, F2, adj, MH, 256);
  mmx<0, 1>(stream, MH, goW_t, nullptr, WH2bf, (int)NB, 128, 256, 256, 128);
  fvec_kernel<<<dim3((unsigned)((NB + 255) / 256), 1), 256, 0, stream>>>(
      WH2bf, 128, CMP, goA, F1, F2, NB);
  gat_att_tiled_kernel<CMP><<<dim3(Nn / 32, Bn, 1), dim3(16, 16), 0, stream>>>(
      WH2bf, 128, F1, F2, adj, G2, 128);
  mmx<1, 0>(stream, G2, Wc_t, Wc_b, AV, (int)NB, 128, 128, 128, 128);

  // ======================= prot CNN (CB=32, 2 chunks) =======================
  for (int c = 0; c < NCH; ++c) {
    long b0 = (long)c * CB;
    float* PVc = PV + b0 * Ln * LT;
    long tot = (long)CB * Ln * PROT;
    embed_kernel<<<dim3((unsigned)((tot + 255) / 256)), 256, 0, stream>>>(
        amino + b0 * Ln, E_amino, PVA, tot, PROT);
    conv11_kernel<<<dim3(Ln / 16, CB), 128, 0, stream>>>(PVA, conv_k + 0 * 121, conv_b + 0, PVc);
    conv11_kernel<<<dim3(Ln / 16, CB), 128, 0, stream>>>(PVc, conv_k + 1 * 121, conv_b + 1, PVA);
    conv11_kernel<<<dim3(Ln / 16, CB), 128, 0, stream>>>(PVA, conv_k + 2 * 121, conv_b + 2, PVc);
    mmx<1, 0>(stream, PVc, Wp_t, Wp_b, PVc, (int)((long)CB * Ln), 128, 128, 128, 128);
  }

  // ======================= fingerprint =======================
  mmx<2, 0>(stream, fps, fp0_t, nullptr, SFT, Bn, 128, 1024, 1024, 128);
  mmx<2, 0>(stream, SFT, fp1_t, nullptr, SF, Bn, 128, 128, 128, 128);

  // ======================= bidirectional attention =======================
  mmdot_kernel<<<dim3((unsigned)(LB / 128), 2), 256, 0, stream>>>(PV, wcat_p, pk_p, OUTP, LB);
  mmdot_kernel<<<dim3((unsigned)(NB / 128), 2), 256, 0, stream>>>(AV, wcat_a, pk_a, OUTA, NB);
  for (int i = 0; i < 4; ++i)
    mmx<0, 1>(stream, AV, U_t + (long)i * 16384, nullptr, AVUbf4 + (long)i * NB * 128,
              (int)NB, 128, 128, 128, 128);
  zero_kernel<<<dim3((unsigned)((2L * Bn * 512 + 255) / 256)), 256, 0, stream>>>(
      CF, 2L * Bn * 512);
  bidat_fused<<<dim3(Nn / 128, Bn, FLSP * 4), 256, 0, stream>>>(
      AVUbf4, PV, OUTP, OUTA, atoms_mask, amino_mask);
  mask_softmax_kernel<<<dim3(Bn, 4), 256, 0, stream>>>(OUTA, atoms_mask, ATTA4, Nn);
  mask_softmax_kernel<<<dim3(Bn, 4), 256, 0, stream>>>(OUTP, amino_mask, ATTP4, Ln);
  wsum_kernel<<<dim3(Bn, 8, 4), 128, 0, stream>>>(AV, ATTA4, CF, Nn, 8);
  wsum_kernel<<<dim3(Bn, 8, 4), 128, 0, stream>>>(PV, ATTP4, PF, Ln, 8);

  // ======================= head =======================
  mmx<0, 0>(stream, CF, combc_t, comb_c_b, V0, Bn, 128, 512, 512, DOUT, 0);
  mmx<0, 0>(stream, PF, combp_t, comb_p_b, V0, Bn, 128, 512, 512, DOUT, 256);
  assemble_v_kernel<<<Bn, 128, 0, stream>>>(SF, invT, Temp, V0);
  mm(stream, V0, Wout_w,                     Wout_b,            V1, Bn, DOUT, DOUT, DOUT, DOUT, DOUT, 0, 1);
  mm(stream, V1, Wout_w + (long)DOUT * DOUT, Wout_b + DOUT,     V0, Bn, DOUT, DOUT, DOUT, DOUT, DOUT, 0, 1);
  mm(stream, V0, Wout_w + 2L * DOUT * DOUT,  Wout_b + 2 * DOUT, V1, Bn, DOUT, DOUT, DOUT, DOUT, DOUT, 0, 1);
  mm(stream, V1, out_w, out_b, out, Bn, 1, DOUT, DOUT, 1, 1, 0, 0);
}

// Round 8
// 1441.894 us; speedup vs baseline: 12.5859x; 1.0206x over previous
//
#include <hip/hip_runtime.h>
#include <math.h>

// ---------------------------------------------------------------------------
// Model constants
// ---------------------------------------------------------------------------
#define Bn   64
#define Nn   256
#define Ln   2048
#define CMP  128
#define PROT 128
#define GF   64
#define NHEADS 4
#define LT   128
#define DOUT 386   // 3*LATENT + 2
#define CB   32    // batch chunk (CNN staging)
#define NCH  (Bn / CB)
#define FLSP 4     // bidat_fused l-split

typedef unsigned short u16;
typedef __attribute__((ext_vector_type(8))) short short8v;   // 8 bf16 (4 VGPRs)
typedef __attribute__((ext_vector_type(4))) float f32x4;
typedef __attribute__((ext_vector_type(4))) unsigned short u16x4;
typedef __attribute__((ext_vector_type(4))) unsigned int u32x4;

#define MFMA(a, b, c) __builtin_amdgcn_mfma_f32_16x16x32_bf16((a), (b), (c), 0, 0, 0)

__device__ __forceinline__ float apply_act(float v, int act) {
  if (act == 1) return v > 0.f ? v : 0.2f * v;   // lrelu ALPHA
  if (act == 2) return v > 0.f ? v : 0.1f * v;   // lrelu 0.1 (fingerprint)
  if (act == 3) return tanhf(v);
  return v;
}

__device__ __forceinline__ u16 bfc(float f) {    // fp32 -> bf16 RNE
  union { float f; unsigned u; } x; x.f = f;
  unsigned r = x.u + 0x7fffu + ((x.u >> 16) & 1u);
  return (u16)(r >> 16);
}

__device__ __forceinline__ float bf2f(u16 h) {
  union { unsigned u; float f; } x; x.u = ((unsigned)h) << 16; return x.f;
}

// fast tanh: 1 - 2*rcp(2^(2*log2e*x)+1); HW exp2+rcp, ~1e-6 abs err, saturates
__device__ __forceinline__ float ftanh(float x) {
  float e = __builtin_amdgcn_exp2f(x * 2.885390081777927f);
  return 1.f - 2.f * __builtin_amdgcn_rcpf(e + 1.f);
}

// byte offset into a [R][C] bf16 LDS tile, XOR-swizzled (r7-validated: 0 conflicts)
template<int C>
__device__ __forceinline__ int lofs(int r, int c) {
  if (C == 128) return ((r * C + c) * 2) ^ ((r & 15) << 4);
  return ((r * C + c) * 2) ^ ((r & 7) << 4);
}

__device__ __forceinline__ short8v ldsv(const u16* s, int byteofs) {
  return *(const short8v*)((const char*)s + byteofs);
}

// ---------------------------------------------------------------------------
// Embedding gather (atoms only now)
// ---------------------------------------------------------------------------
__global__ void embed_kernel(const int* __restrict__ idx, const float* __restrict__ E,
                             float* __restrict__ out, long total, int C) {
  long i = (long)blockIdx.x * blockDim.x + threadIdx.x;
  if (i >= total) return;
  long r = i / C;
  int c = (int)(i - r * (long)C);
  out[i] = E[(long)idx[r] * C + c];
}

__global__ void zero_kernel(float* __restrict__ a, long n) {
  long i = (long)blockIdx.x * blockDim.x + threadIdx.x;
  if (i < n) a[i] = 0.f;
}

// ---------------------------------------------------------------------------
// Weight prep: dst[z][n*K + k] = bf16(src[z][k*N + n])
// ---------------------------------------------------------------------------
__global__ void transp_kernel(const float* __restrict__ src, u16* __restrict__ dst,
                              int K, int N) {
  long total = (long)K * N;
  long base = (long)blockIdx.y * total;
  long idx = (long)blockIdx.x * 256 + threadIdx.x;
  if (idx >= total) return;
  int k = (int)(idx % K);
  int n = (int)(idx / K);
  dst[base + idx] = bfc(src[base + (long)k * N + n]);
}

// batched 128x128 transposes from 8 distinct sources
struct Ptr8 { const float* p[8]; };
__global__ void transp8_kernel(Ptr8 srcs, u16* __restrict__ dst) {
  int y = blockIdx.y;
  int idx = blockIdx.x * 256 + threadIdx.x;   // 0..16383
  int k = idx & 127, n = idx >> 7;
  dst[(long)y * 16384 + idx] = bfc(srcs.p[y][k * 128 + n]);
}

// ---------------------------------------------------------------------------
// pack bvec/aw/ab for mmdot (r6-validated)
// ---------------------------------------------------------------------------
__global__ void pack_kernel(
    const float* __restrict__ bh_c_b, const float* __restrict__ t_c2p_b,
    const float* __restrict__ ba_c_w, const float* __restrict__ ba_c_b,
    const float* __restrict__ ba_p_w, const float* __restrict__ bh_p_b,
    const float* __restrict__ t_p2c_b, const float* __restrict__ ba_p_b,
    float* __restrict__ pk_a, float* __restrict__ pk_p)
{
  int idx = blockIdx.x * 256 + threadIdx.x;
  if (idx < 1024) {
    int g = idx >> 7, j = idx & 127;
    pk_a[idx] = g < 4 ? bh_c_b[g * 128 + j] : t_c2p_b[(g - 4) * 128 + j];
    pk_p[idx] = g < 4 ? bh_p_b[g * 128 + j] : t_p2c_b[(g - 4) * 128 + j];
  } else if (idx < 2048) {
    int k = idx - 1024; int g = k >> 7, j = k & 127;
    pk_a[idx] = g < 4 ? ba_c_w[g * 256 + j] : ba_p_w[(g - 4) * 256 + 128 + j];
    pk_p[idx] = g < 4 ? ba_p_w[g * 256 + j] : ba_c_w[(g - 4) * 256 + 128 + j];
  } else if (idx < 2056) {
    int g = idx - 2048;
    pk_a[idx] = g < 4 ? ba_c_b[g] : 0.f;
    pk_p[idx] = g < 4 ? ba_p_b[g] : 0.f;
  }
}

// ---------------------------------------------------------------------------
// MFMA GEMM: C = act(A @ B + bias).  A fp32 [M,K], Bt bf16 [N,K].
// OUT=0: fp32 C[row*ldc+colOff+col];  OUT=1: bf16 C[row*ldc+col]
// ---------------------------------------------------------------------------
template<int ACT, int OUT>
__global__ __launch_bounds__(256) void mfma_mm_kernel(
    const float* __restrict__ A, const u16* __restrict__ Bt,
    const float* __restrict__ bias, void* __restrict__ Cp,
    int M, int N, int K, int lda, int ldc, int colOff)
{
  __shared__ u16 sA[64 * 64];
  __shared__ u16 sB[64 * 64];
  int m0 = blockIdx.y * 64, n0 = blockIdx.x * 64;
  int tid = threadIdx.x, lane = tid & 63, wv = tid >> 6;
  int mh = wv >> 1, nh = wv & 1;
  f32x4 acc00 = {0.f,0.f,0.f,0.f};
  f32x4 acc01 = acc00, acc10 = acc00, acc11 = acc00;
  for (int k0 = 0; k0 < K; k0 += 64) {
#pragma unroll
    for (int q = tid; q < 64 * 16; q += 256) {
      int r = q >> 4, c4 = (q & 15) << 2;
      float4 v = *(const float4*)(A + (long)(m0 + r) * lda + k0 + c4);
      u16x4 h = { bfc(v.x), bfc(v.y), bfc(v.z), bfc(v.w) };
      *(u16x4*)((char*)sA + lofs<64>(r, c4)) = h;
    }
#pragma unroll
    for (int q = tid; q < 64 * 8; q += 256) {
      int r = q >> 3, c8 = (q & 7) << 3;
      *(u32x4*)((char*)sB + lofs<64>(r, c8)) =
          *(const u32x4*)(Bt + (long)(n0 + r) * K + k0 + c8);
    }
    __syncthreads();
#pragma unroll
    for (int kk = 0; kk < 64; kk += 32) {
      int kf = kk + ((lane >> 4) << 3);
      short8v a0 = ldsv(sA, lofs<64>(mh * 32 + (lane & 15), kf));
      short8v a1 = ldsv(sA, lofs<64>(mh * 32 + 16 + (lane & 15), kf));
      short8v b0 = ldsv(sB, lofs<64>(nh * 32 + (lane & 15), kf));
      short8v b1 = ldsv(sB, lofs<64>(nh * 32 + 16 + (lane & 15), kf));
      acc00 = MFMA(a0, b0, acc00);
      acc01 = MFMA(a0, b1, acc01);
      acc10 = MFMA(a1, b0, acc10);
      acc11 = MFMA(a1, b1, acc11);
    }
    __syncthreads();
  }
#pragma unroll
  for (int rt = 0; rt < 2; ++rt) {
#pragma unroll
    for (int ct = 0; ct < 2; ++ct) {
      f32x4 a = rt == 0 ? (ct == 0 ? acc00 : acc01) : (ct == 0 ? acc10 : acc11);
      int col = n0 + nh * 32 + ct * 16 + (lane & 15);
      float bv = bias ? bias[col] : 0.f;
#pragma unroll
      for (int r4 = 0; r4 < 4; ++r4) {
        int row = m0 + mh * 32 + rt * 16 + ((lane >> 4) << 2) + r4;
        float v = apply_act(a[r4] + bv, ACT);
        if (OUT == 0)
          ((float*)Cp)[(long)row * ldc + colOff + col] = v;
        else
          ((u16*)Cp)[(long)row * ldc + col] = bfc(v);
      }
    }
  }
}

template<int ACT, int OUT>
static void mmx(hipStream_t st, const float* A, const u16* Bt, const float* bias,
                void* C, int M, int N, int K, int lda, int ldc, int colOff = 0)
{
  dim3 grid(N / 64, M / 64);
  mfma_mm_kernel<ACT, OUT><<<grid, dim3(256), 0, st>>>(
      A, Bt, bias, C, M, N, K, lda, ldc, colOff);
}

// ---------------------------------------------------------------------------
// mmdot: out[g][row] = sum_col ftanh((X@W_g)[row,col]+bvec)*aw + ab
// grid (M/128, 2): y selects 4 groups.  XBF: X is bf16 (copy-stage).
// ---------------------------------------------------------------------------
template<int XBF>
__global__ __launch_bounds__(256) void mmdot_kernel(
    const void* __restrict__ Xp, const u16* __restrict__ Wcat,
    const float* __restrict__ pk, float* __restrict__ out, long M)
{
  __shared__ u16 sX[128 * 128];    // 32 KB
  __shared__ u16 sW[64 * 128];     // 16 KB
  __shared__ float bv_s[64], aw_s[64];
  long m0 = (long)blockIdx.x * 128;
  int g0 = blockIdx.y * 4;
  int tid = threadIdx.x, lane = tid & 63, wv = tid >> 6;
  if (XBF) {
    const u16* X = (const u16*)Xp;
    for (int q = tid; q < 128 * 16; q += 256) {
      int r = q >> 4, c8 = (q & 15) << 3;
      *(u32x4*)((char*)sX + lofs<128>(r, c8)) =
          *(const u32x4*)(X + (m0 + r) * 128 + c8);
    }
  } else {
    const float* X = (const float*)Xp;
    for (int q = tid; q < 128 * 32; q += 256) {
      int r = q >> 5, c4 = (q & 31) << 2;
      float4 v = *(const float4*)(X + (m0 + r) * 128 + c4);
      u16x4 h = { bfc(v.x), bfc(v.y), bfc(v.z), bfc(v.w) };
      *(u16x4*)((char*)sX + lofs<128>(r, c4)) = h;
    }
  }
  for (int gi = 0; gi < 4; ++gi) {
    int g = g0 + gi;
    float p[2][4] = {{0.f,0.f,0.f,0.f},{0.f,0.f,0.f,0.f}};
    for (int hh = 0; hh < 2; ++hh) {
      __syncthreads();                 // sX ready / protect sW+bv reuse
      for (int q = tid; q < 64 * 16; q += 256) {
        int r = q >> 4, c8 = (q & 15) << 3;
        *(u32x4*)((char*)sW + lofs<128>(r, c8)) =
            *(const u32x4*)(Wcat + (long)g * 16384 + (long)(hh * 64 + r) * 128 + c8);
      }
      if (tid < 64) {
        bv_s[tid] = pk[g * 128 + hh * 64 + tid];
        aw_s[tid] = pk[1024 + g * 128 + hh * 64 + tid];
      }
      __syncthreads();
      for (int lt = 0; lt < 4; ++lt) {
        int col = lt * 16 + (lane & 15);
        float bv = bv_s[col], awv = aw_s[col];
#pragma unroll
        for (int rt = 0; rt < 2; ++rt) {
          f32x4 c = {0.f,0.f,0.f,0.f};
#pragma unroll
          for (int kk = 0; kk < 128; kk += 32) {
            int kf = kk + ((lane >> 4) << 3);
            short8v a = ldsv(sX, lofs<128>(wv * 32 + rt * 16 + (lane & 15), kf));
            short8v bb = ldsv(sW, lofs<128>(lt * 16 + (lane & 15), kf));
            c = MFMA(a, bb, c);
          }
#pragma unroll
          for (int r4 = 0; r4 < 4; ++r4)
            p[rt][r4] += ftanh(c[r4] + bv) * awv;
        }
      }
    }
    float ab = pk[2048 + g];
#pragma unroll
    for (int rt = 0; rt < 2; ++rt)
#pragma unroll
      for (int r4 = 0; r4 < 4; ++r4) {
        float s = p[rt][r4];
        s += __shfl_xor(s, 1, 64); s += __shfl_xor(s, 2, 64);
        s += __shfl_xor(s, 4, 64); s += __shfl_xor(s, 8, 64);
        if ((lane & 15) == 0) {
          long row = m0 + wv * 32 + rt * 16 + ((lane >> 4) << 2) + r4;
          out[(long)g * M + row] = s + ab;
        }
      }
  }
}

// ---------------------------------------------------------------------------
// bidat_fused v3: A-frags in registers, PV pre-converted bf16, fast tanh.
// blockIdx.z = lz*4 + it.
// ---------------------------------------------------------------------------
__global__ __launch_bounds__(256) void bidat_fused(
    const u16* __restrict__ AVU4,    // [Bn*Nn][512] bf16 (4 iters concat)
    const u16* __restrict__ PVbf,    // [Bn][Ln][128] bf16
    float* __restrict__ OUTP,        // [8][Bn*Ln]: g<4 SCP, g>=4 q
    float* __restrict__ OUTA,        // [8][Bn*Nn]: g<4 SCA, g>=4 r
    const float* __restrict__ am, const float* __restrict__ pm)
{
  __shared__ u16 sK[128 * 128];      // 32 KB
  __shared__ float qm_s[128], pm_s[128], amr_s[128], am_sh[128];
  __shared__ float scp_red[4][128];
  const long NBt = (long)Bn * Nn, LBt = (long)Bn * Ln;
  int b = blockIdx.y;
  int n0 = blockIdx.x * 128;
  int zz = blockIdx.z;
  int it = zz & 3, lz = zz >> 2;
  const float* qv = OUTP + (long)(4 + it) * LBt;
  const float* rv = OUTA + (long)(4 + it) * NBt;
  float* SCA = OUTA + (long)it * NBt;
  float* SCP = OUTP + (long)it * LBt;
  int tid = threadIdx.x, lane = tid & 63, wv = tid >> 6;

  // A-fragments in registers (each wave only needs its own 32 rows)
  short8v af[2][4];
  {
    long rbase = (long)b * Nn + n0 + wv * 32 + (lane & 15);
    int cbase = it * 128 + ((lane >> 4) << 3);
#pragma unroll
    for (int rt = 0; rt < 2; ++rt)
#pragma unroll
      for (int k4 = 0; k4 < 4; ++k4)
        af[rt][k4] = *(const short8v*)(AVU4 + (rbase + rt * 16) * 512 + cbase + k4 * 32);
  }
  if (tid < 128) {
    float amv = am[(long)b * Nn + n0 + tid];
    am_sh[tid] = amv;
    amr_s[tid] = amv * rv[(long)b * Nn + n0 + tid];
  }
  float sca_r[2][4] = {{0.f,0.f,0.f,0.f},{0.f,0.f,0.f,0.f}};
  const u16* pvb = PVbf + (long)b * Ln * 128;
  int lbeg = lz * (Ln / FLSP);

  for (int l0 = lbeg; l0 < lbeg + Ln / FLSP; l0 += 128) {
    __syncthreads();                       // protect sK / scp_red from prev
    for (int q = tid; q < 128 * 16; q += 256) {
      int r = q >> 4, c8 = (q & 15) << 3;
      *(u32x4*)((char*)sK + lofs<128>(r, c8)) =
          *(const u32x4*)(pvb + (long)(l0 + r) * 128 + c8);
    }
    if (tid < 128) {
      float pmv = pm[(long)b * Ln + l0 + tid];
      pm_s[tid] = pmv;
      qm_s[tid] = pmv * qv[(long)b * Ln + l0 + tid];
    }
    __syncthreads();
    for (int lt = 0; lt < 8; ++lt) {
      float sp = 0.f;
      float qmv = qm_s[lt * 16 + (lane & 15)];
#pragma unroll
      for (int rt = 0; rt < 2; ++rt) {
        f32x4 c = {0.f,0.f,0.f,0.f};
#pragma unroll
        for (int k4 = 0; k4 < 4; ++k4) {
          short8v bb = ldsv(sK, lofs<128>(lt * 16 + (lane & 15),
                                          k4 * 32 + ((lane >> 4) << 3)));
          c = MFMA(af[rt][k4], bb, c);
        }
#pragma unroll
        for (int r4 = 0; r4 < 4; ++r4) {
          int nr = wv * 32 + rt * 16 + ((lane >> 4) << 2) + r4;
          float t = ftanh(c[r4]);
          sca_r[rt][r4] += t * qmv;
          sp += t * amr_s[nr];
        }
      }
      sp += __shfl_xor(sp, 16, 64);
      sp += __shfl_xor(sp, 32, 64);
      if (lane < 16) scp_red[wv][lt * 16 + lane] = sp;
    }
    __syncthreads();
    if (tid < 128) {
      float v = scp_red[0][tid] + scp_red[1][tid] + scp_red[2][tid] + scp_red[3][tid];
      atomicAdd(&SCP[(long)b * Ln + l0 + tid], v * pm_s[tid]);
    }
  }
#pragma unroll
  for (int rt = 0; rt < 2; ++rt)
#pragma unroll
    for (int r4 = 0; r4 < 4; ++r4) {
      float s = sca_r[rt][r4];
      s += __shfl_xor(s, 1, 64); s += __shfl_xor(s, 2, 64);
      s += __shfl_xor(s, 4, 64); s += __shfl_xor(s, 8, 64);
      if ((lane & 15) == 0) {
        int nr = wv * 32 + rt * 16 + ((lane >> 4) << 2) + r4;
        atomicAdd(&SCA[(long)b * Nn + n0 + nr], s * am_sh[nr]);
      }
    }
}

// ---------------------------------------------------------------------------
// Legacy fp32 tiled matmul (head layers, K=386)
// ---------------------------------------------------------------------------
__global__ __launch_bounds__(256) void mm_kernel(
    const float* __restrict__ A, const float* __restrict__ Bm,
    const float* __restrict__ bias, float* __restrict__ C,
    int M, int N, int K, int lda, int ldb, int ldc, int colOff, int act)
{
  __shared__ float As[32][33];
  __shared__ float Bs[32][33];
  int tx = threadIdx.x, ty = threadIdx.y;
  int tid = ty * 16 + tx;
  int m0 = blockIdx.y * 32;
  int n0 = blockIdx.x * 32;
  float acc00 = 0.f, acc01 = 0.f, acc10 = 0.f, acc11 = 0.f;
  for (int k0 = 0; k0 < K; k0 += 32) {
#pragma unroll
    for (int t = 0; t < 4; ++t) {
      int li = tid + t * 256;
      int r = li >> 5, c = li & 31;
      int mm = m0 + r, kk = k0 + c;
      As[r][c] = (mm < M && kk < K) ? A[(long)mm * lda + kk] : 0.f;
      int kk2 = k0 + r, nn = n0 + c;
      Bs[r][c] = (kk2 < K && nn < N) ? Bm[(long)kk2 * ldb + nn] : 0.f;
    }
    __syncthreads();
#pragma unroll
    for (int kk = 0; kk < 32; ++kk) {
      float a0 = As[ty][kk], a1 = As[ty + 16][kk];
      float b0 = Bs[kk][tx], b1 = Bs[kk][tx + 16];
      acc00 += a0 * b0; acc01 += a0 * b1;
      acc10 += a1 * b0; acc11 += a1 * b1;
    }
    __syncthreads();
  }
  float accs[2][2] = {{acc00, acc01}, {acc10, acc11}};
#pragma unroll
  for (int i = 0; i < 2; ++i) {
    int m = m0 + ty + i * 16;
    if (m >= M) continue;
#pragma unroll
    for (int j = 0; j < 2; ++j) {
      int n = n0 + tx + j * 16;
      if (n >= N) continue;
      float v = accs[i][j];
      if (bias) v += bias[n];
      C[(long)m * ldc + colOff + n] = apply_act(v, act);
    }
  }
}

static void mm(hipStream_t st, const float* A, const float* Bm, const float* bias,
               float* C, int M, int N, int K, int lda, int ldb, int ldc,
               int colOff, int act)
{
  dim3 grid((N + 31) / 32, (M + 31) / 32), block(16, 16);
  mm_kernel<<<grid, block, 0, st>>>(A, Bm, bias, C, M, N, K, lda, ldb, ldc, colOff, act);
}

// ---------------------------------------------------------------------------
// f1/f2 = Wh_h . a_h[:F], Wh_h . a_h[F:]   (bf16 Wh; grid.y = head)
// ---------------------------------------------------------------------------
__global__ void fvec_kernel(const u16* __restrict__ Wh, int ldW, int F,
                            const float* __restrict__ a,
                            float* __restrict__ f1, float* __restrict__ f2,
                            long rows) {
  int h = blockIdx.y;
  long r = (long)blockIdx.x * blockDim.x + threadIdx.x;
  if (r >= rows) return;
  const u16* w = Wh + r * ldW + h * F;
  const float* av = a + (long)h * 2 * F;
  float s1 = 0.f, s2 = 0.f;
  for (int d = 0; d < F; ++d) {
    float wv = bf2f(w[d]);
    s1 += wv * av[d]; s2 += wv * av[F + d];
  }
  f1[(long)h * rows + r] = s1; f2[(long)h * rows + r] = s2;
}

// ---------------------------------------------------------------------------
// Tiled GAT attention (bf16 Wh input, grid.z = head) — r7-validated
// ---------------------------------------------------------------------------
template<int F>
__global__ __launch_bounds__(256) void gat_att_tiled_kernel(
    const u16* __restrict__ Wh, int ldW,
    const float* __restrict__ f1, const float* __restrict__ f2,
    const int* __restrict__ adj, float* __restrict__ out, int ldo)
{
  __shared__ float sE[32][257];
  __shared__ float sW[32][(F == 64) ? 68 : 132];
  __shared__ float f1s[32];
  __shared__ float mrow[32], srow[32];
  __shared__ float pred[32][9];
  int b = blockIdx.y;
  int i0 = blockIdx.x * 32;
  int h = blockIdx.z;
  int cW = h * F, cO = h * F;
  int tx = threadIdx.x, ty = threadIdx.y;
  int tid = ty * 16 + tx;
  const long rowb = (long)b * Nn;
  const float* f1h = f1 + (long)h * Bn * Nn;
  const float* f2h = f2 + (long)h * Bn * Nn;

  if (tid < 32) f1s[tid] = f1h[rowb + i0 + tid];
  float f2v = f2h[rowb + tid];
  __syncthreads();
  for (int r = 0; r < 32; ++r) {
    float e = f1s[r] + f2v;
    e = e > 0.f ? e : 0.2f * e;
    int a = adj[(rowb + i0 + r) * Nn + tid];
    sE[r][tid] = (a > 0) ? e : -9e15f;
  }
  __syncthreads();
  {
    int r = tid >> 3, s = tid & 7;
    float m = -3.4e38f;
    for (int j = s; j < 256; j += 8) m = fmaxf(m, sE[r][j]);
    pred[r][s] = m;
  }
  __syncthreads();
  if (tid < 32) {
    float m = pred[tid][0];
#pragma unroll
    for (int s = 1; s < 8; ++s) m = fmaxf(m, pred[tid][s]);
    mrow[tid] = m;
  }
  __syncthreads();
  {
    int r = tid >> 3, s = tid & 7;
    float m = mrow[r];
    float sum = 0.f;
    for (int j = s; j < 256; j += 8) {
      float v = __expf(sE[r][j] - m);
      sE[r][j] = v;
      sum += v;
    }
    pred[r][s] = sum;
  }
  __syncthreads();
  if (tid < 32) {
    float s = 0.f;
#pragma unroll
    for (int t = 0; t < 8; ++t) s += pred[tid][t];
    srow[tid] = 1.f / s;
  }
  __syncthreads();
  float acc[2][F / 16] = {};
  for (int k0 = 0; k0 < 256; k0 += 32) {
    for (int li = tid; li < 32 * F; li += 256) {
      int rr = li / F, cc = li % F;
      sW[rr][cc] = bf2f(Wh[(rowb + k0 + rr) * (long)ldW + cW + cc]);
    }
    __syncthreads();
#pragma unroll
    for (int kk = 0; kk < 32; ++kk) {
      float a0 = sE[ty][k0 + kk], a1 = sE[ty + 16][k0 + kk];
#pragma unroll
      for (int j = 0; j < F / 16; ++j) {
        float w = sW[kk][tx + j * 16];
        acc[0][j] += a0 * w;
        acc[1][j] += a1 * w;
      }
    }
    __syncthreads();
  }
#pragma unroll
  for (int ii = 0; ii < 2; ++ii) {
    int r = ty + ii * 16;
    float sc = srow[r];
#pragma unroll
    for (int j = 0; j < F / 16; ++j) {
      float v = acc[ii][j] * sc;
      v = v > 0.f ? v : expm1f(v);   // elu
      out[(rowb + i0 + r) * (long)ldo + cO + tx + j * 16] = v;
    }
  }
}

// ---------------------------------------------------------------------------
// 11x11 conv (validated r3).  conv11e fuses the amino embedding (layer 1).
// ---------------------------------------------------------------------------
__global__ __launch_bounds__(128) void conv11_kernel(
    const float* __restrict__ in, const float* __restrict__ kw,
    const float* __restrict__ bias_p, float* __restrict__ out)
{
  __shared__ float s[26][140];
  __shared__ float kk[121];
  int b = blockIdx.y;
  int l0 = blockIdx.x * 16;
  int tid = threadIdx.x;
  if (tid < 121) kk[tid] = kw[tid];
  const float* inb = in + (long)b * Ln * PROT;
  for (int r = 0; r < 26; ++r) {
    int l = l0 - 5 + r;
    for (int c = tid; c < 138; c += 128) {
      int p = c - 5;
      float v = 0.f;
      if (l >= 0 && l < Ln && p >= 0 && p < PROT) v = inb[(long)l * PROT + p];
      s[r][c] = v;
    }
  }
  __syncthreads();
  float bias = bias_p[0];
  float acc[16];
#pragma unroll
  for (int i = 0; i < 16; ++i) acc[i] = bias;
  int p = tid;
#pragma unroll
  for (int v = 0; v < 11; ++v) {
    float c[26];
#pragma unroll
    for (int u = 0; u < 26; ++u) c[u] = s[u][p + v];
#pragma unroll
    for (int u = 0; u < 11; ++u) {
      float w = kk[u * 11 + v];
#pragma unroll
      for (int i = 0; i < 16; ++i) acc[i] += c[i + u] * w;
    }
  }
  float* outb = out + (long)b * Ln * PROT;
#pragma unroll
  for (int i = 0; i < 16; ++i) {
    float vv = acc[i];
    outb[(long)(l0 + i) * PROT + p] = vv > 0.f ? vv : 0.2f * vv;
  }
}

__global__ __launch_bounds__(128) void conv11e_kernel(
    const int* __restrict__ amino, const float* __restrict__ E,
    const float* __restrict__ kw, const float* __restrict__ bias_p,
    float* __restrict__ out)
{
  __shared__ float s[26][140];
  __shared__ float kk[121];
  int b = blockIdx.y;
  int l0 = blockIdx.x * 16;
  int tid = threadIdx.x;
  if (tid < 121) kk[tid] = kw[tid];
  const int* amb = amino + (long)b * Ln;
  for (int r = 0; r < 26; ++r) {
    int l = l0 - 5 + r;
    int idx = (l >= 0 && l < Ln) ? amb[l] : -1;
    const float* Er = E + (long)(idx < 0 ? 0 : idx) * PROT;
    for (int c = tid; c < 138; c += 128) {
      int p = c - 5;
      float v = 0.f;
      if (idx >= 0 && p >= 0 && p < PROT) v = Er[p];
      s[r][c] = v;
    }
  }
  __syncthreads();
  float bias = bias_p[0];
  float acc[16];
#pragma unroll
  for (int i = 0; i < 16; ++i) acc[i] = bias;
  int p = tid;
#pragma unroll
  for (int v = 0; v < 11; ++v) {
    float c[26];
#pragma unroll
    for (int u = 0; u < 26; ++u) c[u] = s[u][p + v];
#pragma unroll
    for (int u = 0; u < 11; ++u) {
      float w = kk[u * 11 + v];
#pragma unroll
      for (int i = 0; i < 16; ++i) acc[i] += c[i + u] * w;
    }
  }
  float* outb = out + (long)b * Ln * PROT;
#pragma unroll
  for (int i = 0; i < 16; ++i) {
    float vv = acc[i];
    outb[(long)(l0 + i) * PROT + p] = vv > 0.f ? vv : 0.2f * vv;
  }
}

// ---------------------------------------------------------------------------
// masked softmax (grid.y = iteration)
// ---------------------------------------------------------------------------
__global__ __launch_bounds__(256) void mask_softmax_kernel(
    const float* __restrict__ score, const float* __restrict__ mask,
    float* __restrict__ att, int n)
{
  int b = blockIdx.x;
  long st = (long)blockIdx.y * gridDim.x * n;
  int tid = threadIdx.x;
  __shared__ float red[256];
  const float* s = score + st + (long)b * n;
  const float* mk = mask + (long)b * n;
  float mx = -3.4e38f;
  for (int i = tid; i < n; i += 256) mx = fmaxf(mx, s[i]);
  red[tid] = mx; __syncthreads();
  for (int stp = 128; stp > 0; stp >>= 1) { if (tid < stp) red[tid] = fmaxf(red[tid], red[tid + stp]); __syncthreads(); }
  mx = red[0]; __syncthreads();
  float sum = 0.f;
  for (int i = tid; i < n; i += 256) sum += __expf(s[i] - mx) * mk[i];
  red[tid] = sum; __syncthreads();
  for (int stp = 128; stp > 0; stp >>= 1) { if (tid < stp) red[tid] += red[tid + stp]; __syncthreads(); }
  float denom = red[0] + 1e-6f;
  for (int i = tid; i < n; i += 256)
    att[st + (long)b * n + i] = __expf(s[i] - mx) * mk[i] / denom;
}

// ---------------------------------------------------------------------------
// weighted sum (grid.z = iteration; XBF: x is bf16)
// ---------------------------------------------------------------------------
template<int XBF>
__global__ __launch_bounds__(128) void wsum_kernel(
    const void* __restrict__ xp, const float* __restrict__ att,
    float* __restrict__ out, int n, int nsplit)
{
  int b = blockIdx.x;
  int sp = blockIdx.y;
  int it = blockIdx.z;
  int d = threadIdx.x;
  int chunk = n / nsplit;
  int t0 = sp * chunk, t1 = t0 + chunk;
  const float* ab = att + (long)it * gridDim.x * n + (long)b * n;
  float acc = 0.f;
  if (XBF) {
    const u16* xb = (const u16*)xp + (long)b * n * LT + d;
#pragma unroll 8
    for (int t = t0; t < t1; ++t) acc += bf2f(xb[(long)t * LT]) * ab[t];
  } else {
    const float* xb = (const float*)xp + (long)b * n * LT + d;
#pragma unroll 8
    for (int t = t0; t < t1; ++t) acc += xb[(long)t * LT] * ab[t];
  }
  atomicAdd(&out[(long)b * 512 + it * LT + d], acc);
}

__global__ __launch_bounds__(128) void assemble_v_kernel(
    const float* __restrict__ sf, const float* __restrict__ invT,
    const float* __restrict__ T, float* __restrict__ v)
{
  int b = blockIdx.x;
  int t = threadIdx.x;
  v[(long)b * DOUT + 128 + t] = sf[(long)b * LT + t];
  if (t == 0) { v[(long)b * DOUT + 384] = invT[b]; v[(long)b * DOUT + 385] = T[b]; }
}

// ---------------------------------------------------------------------------
extern "C" void kernel_launch(void* const* d_in, const int* in_sizes, int n_in,
                              void* d_out, int out_size, void* d_ws, size_t ws_size,
                              hipStream_t stream) {
  const long NB = (long)Bn * Nn;    // 16384
  const long LB = (long)Bn * Ln;    // 131072
  const long M1 = 1024 * 1024;

  const int*   atoms      = (const int*)d_in[0];
  const float* atoms_mask = (const float*)d_in[1];
  const int*   adj        = (const int*)d_in[2];
  const int*   amino      = (const int*)d_in[3];
  const float* amino_mask = (const float*)d_in[4];
  const float* fps        = (const float*)d_in[5];
  const float* invT       = (const float*)d_in[6];
  const float* Temp       = (const float*)d_in[7];
  const float* E_atom     = (const float*)d_in[8];
  const float* E_amino    = (const float*)d_in[9];
  const float* gatW       = (const float*)d_in[10];
  const float* gatA       = (const float*)d_in[11];
  const float* goW        = (const float*)d_in[12];
  const float* goA        = (const float*)d_in[13];
  const float* Wc_w       = (const float*)d_in[14];
  const float* Wc_b       = (const float*)d_in[15];
  const float* conv_k     = (const float*)d_in[16];
  const float* conv_b     = (const float*)d_in[17];
  const float* Wp_w       = (const float*)d_in[18];
  const float* Wp_b       = (const float*)d_in[19];
  const float* fp0        = (const float*)d_in[20];
  const float* fp1        = (const float*)d_in[21];
  const float* U          = (const float*)d_in[22];
  const float* t_c2p_w    = (const float*)d_in[23];
  const float* t_c2p_b    = (const float*)d_in[24];
  const float* t_p2c_w    = (const float*)d_in[25];
  const float* t_p2c_b    = (const float*)d_in[26];
  const float* bh_c_w     = (const float*)d_in[27];
  const float* bh_c_b     = (const float*)d_in[28];
  const float* bh_p_w     = (const float*)d_in[29];
  const float* bh_p_b     = (const float*)d_in[30];
  const float* ba_c_w     = (const float*)d_in[31];
  const float* ba_c_b     = (const float*)d_in[32];
  const float* ba_p_w     = (const float*)d_in[33];
  const float* ba_p_b     = (const float*)d_in[34];
  const float* comb_c_w   = (const float*)d_in[35];
  const float* comb_c_b   = (const float*)d_in[36];
  const float* comb_p_w   = (const float*)d_in[37];
  const float* comb_p_b   = (const float*)d_in[38];
  const float* Wout_w     = (const float*)d_in[39];
  const float* Wout_b     = (const float*)d_in[40];
  const float* out_w      = (const float*)d_in[41];
  const float* out_b      = (const float*)d_in[42];
  float* out = (float*)d_out;

  // ---------------- workspace layout (~97 MB, < r7's proven 114 MB) --------
  float* ws = (float*)d_ws;
  long off = 0;
  float* AV    = ws + off; off += NB * LT;          // 2M fp32
  u16*   PVbf  = (u16*)(ws + off); off += LB * LT / 2;  // 4.19M float-equiv
  float* SF    = ws + off; off += (long)Bn * LT;
  float* SFT   = ws + off; off += (long)Bn * LT;
  float* CF    = ws + off; off += (long)Bn * 512;   // CF then PF contiguous
  float* PF    = ws + off; off += (long)Bn * 512;
  float* F1    = ws + off; off += 4 * NB;
  float* F2    = ws + off; off += 4 * NB;
  float* ATTA4 = ws + off; off += 4 * NB;
  float* ATTP4 = ws + off; off += 4 * LB;
  float* V0    = ws + off; off += (long)Bn * DOUT;
  float* V1    = ws + off; off += (long)Bn * DOUT;
  // weight cache (persistent)
  u16* WT = (u16*)(ws + off);
  long wo = 0;
  u16* gatW_t  = WT + wo; wo += 4L * 64 * 128;      // [256][128]
  u16* goW_t   = WT + wo; wo += 128L * 256;
  u16* T23     = WT + wo; wo += 23L * 16384;
  u16* fp0_t   = WT + wo; wo += 128L * 1024;
  u16* combc_t = WT + wo; wo += 128L * 512;
  u16* combp_t = WT + wo; wo += 128L * 512;
  off += (wo + 1) / 2;
  float* pk_a = ws + off; off += 2056;
  float* pk_p = ws + off; off += 2056;
  float* POOL = ws + off;                           // needs 16.78M floats
  u16* Wc_t   = T23;
  u16* Wp_t   = T23 + 16384;
  u16* fp1_t  = T23 + 2L * 16384;
  u16* U_t    = T23 + 3L * 16384;                   // 4 mats contiguous
  u16* wcat_a = T23 + 7L * 16384;                   // [bh_c(4) | t_c2p(4)]
  u16* wcat_p = T23 + 15L * 16384;                  // [bh_p(4) | t_p2c(4)]
  // pool aliases:
  float* AVE   = POOL;                              // [0,2M)
  u16*   WH4bf = (u16*)(POOL + 2 * M1);             // [2M,4M)
  float* MH    = POOL + 4 * M1;                     // [4M,8.19M)
  u16*   WH2bf = (u16*)POOL;                        // [0,1M)
  float* G2    = POOL + 4 * M1;                     // (MH dead)
  float* PVA   = POOL;                              // CNN ping [0,8.39M)
  float* PVB   = POOL + 8 * M1;                     // CNN pong [8.39M,16.78M)
  u16*   AVU4  = (u16*)POOL;                        // [NB][512] u16 = [0,4M)
  float* OUTP  = POOL + 4 * M1;                     // [8][LB] = 1M
  float* OUTA  = POOL + 5 * M1;                     // [8][NB]

  // ======================= weight prep =======================
  transp_kernel<<<dim3(32, 4), 256, 0, stream>>>(gatW, gatW_t, 128, 64);
  transp_kernel<<<dim3(128), 256, 0, stream>>>(goW, goW_t, 256, 128);
  transp_kernel<<<dim3(512), 256, 0, stream>>>(fp0, fp0_t, 1024, 128);
  transp_kernel<<<dim3(256), 256, 0, stream>>>(comb_c_w, combc_t, 512, 128);
  transp_kernel<<<dim3(256), 256, 0, stream>>>(comb_p_w, combp_t, 512, 128);
  {
    Ptr8 a1 = {{Wc_w, Wp_w, fp1, U, U + 16384, U + 32768, U + 49152, bh_c_w}};
    Ptr8 a2 = {{bh_c_w + 16384, bh_c_w + 32768, bh_c_w + 49152,
                t_c2p_w, t_c2p_w + 16384, t_c2p_w + 32768, t_c2p_w + 49152,
                bh_p_w}};
    Ptr8 a3 = {{bh_p_w + 16384, bh_p_w + 32768, bh_p_w + 49152,
                t_p2c_w, t_p2c_w + 16384, t_p2c_w + 32768, t_p2c_w + 49152,
                bh_p_w}};
    transp8_kernel<<<dim3(64, 8), 256, 0, stream>>>(a1, T23);
    transp8_kernel<<<dim3(64, 8), 256, 0, stream>>>(a2, T23 + 8L * 16384);
    transp8_kernel<<<dim3(64, 7), 256, 0, stream>>>(a3, T23 + 16L * 16384);
  }
  pack_kernel<<<dim3(9), 256, 0, stream>>>(bh_c_b, t_c2p_b, ba_c_w, ba_c_b,
                                           ba_p_w, bh_p_b, t_p2c_b, ba_p_b,
                                           pk_a, pk_p);

  // ======================= comp GAT (heads batched) =======================
  embed_kernel<<<dim3((unsigned)((NB * CMP + 255) / 256)), 256, 0, stream>>>(
      atoms, E_atom, AVE, NB * CMP, CMP);
  mmx<0, 1>(stream, AVE, gatW_t, nullptr, WH4bf, (int)NB, 256, 128, 128, 256);
  fvec_kernel<<<dim3((unsigned)((NB + 255) / 256), 4), 256, 0, stream>>>(
      WH4bf, 256, GF, gatA, F1, F2, NB);
  gat_att_tiled_kernel<GF><<<dim3(Nn / 32, Bn, 4), dim3(16, 16), 0, stream>>>(
      WH4bf, 256, F1, F2, adj, MH, 256);
  mmx<0, 1>(stream, MH, goW_t, nullptr, WH2bf, (int)NB, 128, 256, 256, 128);
  fvec_kernel<<<dim3((unsigned)((NB + 255) / 256), 1), 256, 0, stream>>>(
      WH2bf, 128, CMP, goA, F1, F2, NB);
  gat_att_tiled_kernel<CMP><<<dim3(Nn / 32, Bn, 1), dim3(16, 16), 0, stream>>>(
      WH2bf, 128, F1, F2, adj, G2, 128);
  mmx<1, 0>(stream, G2, Wc_t, Wc_b, AV, (int)NB, 128, 128, 128, 128);

  // ======================= prot CNN (embed fused into conv1) ===============
  for (int c = 0; c < NCH; ++c) {
    long b0 = (long)c * CB;
    conv11e_kernel<<<dim3(Ln / 16, CB), 128, 0, stream>>>(
        amino + b0 * Ln, E_amino, conv_k + 0 * 121, conv_b + 0, PVA);
    conv11_kernel<<<dim3(Ln / 16, CB), 128, 0, stream>>>(PVA, conv_k + 1 * 121, conv_b + 1, PVB);
    conv11_kernel<<<dim3(Ln / 16, CB), 128, 0, stream>>>(PVB, conv_k + 2 * 121, conv_b + 2, PVA);
    mmx<1, 1>(stream, PVA, Wp_t, Wp_b, PVbf + b0 * Ln * 128,
              (int)((long)CB * Ln), 128, 128, 128, 128);
  }

  // ======================= fingerprint =======================
  mmx<2, 0>(stream, fps, fp0_t, nullptr, SFT, Bn, 128, 1024, 1024, 128);
  mmx<2, 0>(stream, SFT, fp1_t, nullptr, SF, Bn, 128, 128, 128, 128);

  // ======================= bidirectional attention =======================
  mmdot_kernel<1><<<dim3((unsigned)(LB / 128), 2), 256, 0, stream>>>(
      PVbf, wcat_p, pk_p, OUTP, LB);
  mmdot_kernel<0><<<dim3((unsigned)(NB / 128), 2), 256, 0, stream>>>(
      AV, wcat_a, pk_a, OUTA, NB);
  mmx<0, 1>(stream, AV, U_t, nullptr, AVU4, (int)NB, 512, 128, 128, 512);
  zero_kernel<<<dim3((unsigned)((2L * Bn * 512 + 255) / 256)), 256, 0, stream>>>(
      CF, 2L * Bn * 512);
  bidat_fused<<<dim3(Nn / 128, Bn, FLSP * 4), 256, 0, stream>>>(
      AVU4, PVbf, OUTP, OUTA, atoms_mask, amino_mask);
  mask_softmax_kernel<<<dim3(Bn, 4), 256, 0, stream>>>(OUTA, atoms_mask, ATTA4, Nn);
  mask_softmax_kernel<<<dim3(Bn, 4), 256, 0, stream>>>(OUTP, amino_mask, ATTP4, Ln);
  wsum_kernel<0><<<dim3(Bn, 8, 4), 128, 0, stream>>>(AV, ATTA4, CF, Nn, 8);
  wsum_kernel<1><<<dim3(Bn, 8, 4), 128, 0, stream>>>(PVbf, ATTP4, PF, Ln, 8);

  // ======================= head =======================
  mmx<0, 0>(stream, CF, combc_t, comb_c_b, V0, Bn, 128, 512, 512, DOUT, 0);
  mmx<0, 0>(stream, PF, combp_t, comb_p_b, V0, Bn, 128, 512, 512, DOUT, 256);
  assemble_v_kernel<<<Bn, 128, 0, stream>>>(SF, invT, Temp, V0);
  mm(stream, V0, Wout_w,                     Wout_b,            V1, Bn, DOUT, DOUT, DOUT, DOUT, DOUT, 0, 1);
  mm(stream, V1, Wout_w + (long)DOUT * DOUT, Wout_b + DOUT,     V0, Bn, DOUT, DOUT, DOUT, DOUT, DOUT, 0, 1);
  mm(stream, V0, Wout_w + 2L * DOUT * DOUT,  Wout_b + 2 * DOUT, V1, Bn, DOUT, DOUT, DOUT, DOUT, DOUT, 0, 1);
  mm(stream, V1, out_w, out_b, out, Bn, 1, DOUT, DOUT, 1, 1, 0, 0);
}

// Round 9
// 1193.956 us; speedup vs baseline: 15.1995x; 1.2077x over previous
//
#include <hip/hip_runtime.h>
#include <math.h>

// ---------------------------------------------------------------------------
// Model constants
// ---------------------------------------------------------------------------
#define Bn   64
#define Nn   256
#define Ln   2048
#define CMP  128
#define PROT 128
#define GF   64
#define NHEADS 4
#define LT   128
#define DOUT 386   // 3*LATENT + 2
#define CB   32    // batch chunk (CNN staging)
#define NCH  (Bn / CB)
#define FLSP 4     // bidat_fused l-split

typedef unsigned short u16;
typedef unsigned long long u64;
typedef __attribute__((ext_vector_type(8))) short short8v;   // 8 bf16 (4 VGPRs)
typedef __attribute__((ext_vector_type(4))) float f32x4;
typedef __attribute__((ext_vector_type(4))) unsigned short u16x4;
typedef __attribute__((ext_vector_type(4))) unsigned int u32x4;

#define MFMA(a, b, c) __builtin_amdgcn_mfma_f32_16x16x32_bf16((a), (b), (c), 0, 0, 0)

__device__ __forceinline__ float apply_act(float v, int act) {
  if (act == 1) return v > 0.f ? v : 0.2f * v;   // lrelu ALPHA
  if (act == 2) return v > 0.f ? v : 0.1f * v;   // lrelu 0.1 (fingerprint)
  if (act == 3) return tanhf(v);
  return v;
}

__device__ __forceinline__ u16 bfc(float f) {    // fp32 -> bf16 RNE
  union { float f; unsigned u; } x; x.f = f;
  unsigned r = x.u + 0x7fffu + ((x.u >> 16) & 1u);
  return (u16)(r >> 16);
}

__device__ __forceinline__ float bf2f(u16 h) {
  union { unsigned u; float f; } x; x.u = ((unsigned)h) << 16; return x.f;
}

// fast tanh: 1 - 2*rcp(2^(2*log2e*x)+1); HW exp2+rcp, ~1e-6 abs err, saturates
__device__ __forceinline__ float ftanh(float x) {
  float e = __builtin_amdgcn_exp2f(x * 2.885390081777927f);
  return 1.f - 2.f * __builtin_amdgcn_rcpf(e + 1.f);
}

// byte offset into a [R][C] bf16 LDS tile, XOR-swizzled (r7-validated: 0 conflicts)
template<int C>
__device__ __forceinline__ int lofs(int r, int c) {
  if (C == 256) return ((r * C + c) * 2) ^ ((r & 15) << 4);
  if (C == 128) return ((r * C + c) * 2) ^ ((r & 15) << 4);
  return ((r * C + c) * 2) ^ ((r & 7) << 4);
}

__device__ __forceinline__ short8v ldsv(const u16* s, int byteofs) {
  return *(const short8v*)((const char*)s + byteofs);
}

// ---------------------------------------------------------------------------
// Embedding gather (atoms only)
// ---------------------------------------------------------------------------
__global__ void embed_kernel(const int* __restrict__ idx, const float* __restrict__ E,
                             float* __restrict__ out, long total, int C) {
  long i = (long)blockIdx.x * blockDim.x + threadIdx.x;
  if (i >= total) return;
  long r = i / C;
  int c = (int)(i - r * (long)C);
  out[i] = E[(long)idx[r] * C + c];
}

__global__ void zero_kernel(float* __restrict__ a, long n) {
  long i = (long)blockIdx.x * blockDim.x + threadIdx.x;
  if (i < n) a[i] = 0.f;
}

// adjacency -> bitmask [NB rows][4 u64]
__global__ void packadj_kernel(const int* __restrict__ adj, u64* __restrict__ adjb) {
  long idx = (long)blockIdx.x * 256 + threadIdx.x;
  int lane = threadIdx.x & 63;
  bool bit = adj[idx] > 0;
  u64 m = __ballot(bit);
  if (lane == 0) adjb[idx >> 6] = m;
}

// ---------------------------------------------------------------------------
// Weight prep: dst[z][n*K + k] = bf16(src[z][k*N + n])
// ---------------------------------------------------------------------------
__global__ void transp_kernel(const float* __restrict__ src, u16* __restrict__ dst,
                              int K, int N) {
  long total = (long)K * N;
  long base = (long)blockIdx.y * total;
  long idx = (long)blockIdx.x * 256 + threadIdx.x;
  if (idx >= total) return;
  int k = (int)(idx % K);
  int n = (int)(idx / K);
  dst[base + idx] = bfc(src[base + (long)k * N + n]);
}

struct Ptr8 { const float* p[8]; };
__global__ void transp8_kernel(Ptr8 srcs, u16* __restrict__ dst) {
  int y = blockIdx.y;
  int idx = blockIdx.x * 256 + threadIdx.x;   // 0..16383
  int k = idx & 127, n = idx >> 7;
  dst[(long)y * 16384 + idx] = bfc(srcs.p[y][k * 128 + n]);
}

// wv[0,1024): gat head vectors w[h][which][128]; wv[1024,1536): go vectors [2][256]
__global__ void wvec_kernel(const float* __restrict__ gatW, const float* __restrict__ gatA,
                            const float* __restrict__ goW, const float* __restrict__ goA,
                            float* __restrict__ wv) {
  int idx = blockIdx.x * 256 + threadIdx.x;
  if (idx < 1024) {
    int h = idx >> 8, wq = (idx >> 7) & 1, d = idx & 127;
    const float* W = gatW + ((long)h * 128 + d) * 64;
    const float* a = gatA + h * 128 + wq * 64;
    float s = 0.f;
    for (int f = 0; f < 64; ++f) s += W[f] * a[f];
    wv[idx] = s;
  } else if (idx < 1536) {
    int k = idx - 1024; int wq = k >> 8, d = k & 255;
    const float* W = goW + (long)d * 128;
    const float* a = goA + wq * 128;
    float s = 0.f;
    for (int f = 0; f < 128; ++f) s += W[f] * a[f];
    wv[idx] = s;
  }
}

// f1/f2 for 4 heads from AVE: one wave per row
__global__ __launch_bounds__(256) void favv_kernel(
    const float* __restrict__ AVE, const float* __restrict__ wv,
    float* __restrict__ f1, float* __restrict__ f2, long rows)
{
  __shared__ float w[1024];
  int tid = threadIdx.x;
  for (int q = tid; q < 1024; q += 256) w[q] = wv[q];
  __syncthreads();
  long r = (long)blockIdx.x * 4 + (tid >> 6);
  int lane = tid & 63;
  float a0 = AVE[r * 128 + lane], a1 = AVE[r * 128 + 64 + lane];
#pragma unroll
  for (int h = 0; h < 4; ++h) {
    float s1 = a0 * w[h * 256 + lane] + a1 * w[h * 256 + 64 + lane];
    float s2 = a0 * w[h * 256 + 128 + lane] + a1 * w[h * 256 + 192 + lane];
#pragma unroll
    for (int m = 32; m; m >>= 1) { s1 += __shfl_xor(s1, m, 64); s2 += __shfl_xor(s2, m, 64); }
    if (lane == 0) { f1[(long)h * rows + r] = s1; f2[(long)h * rows + r] = s2; }
  }
}

// f1/f2 from MH [rows][256] with gv = wv+1024
__global__ __launch_bounds__(256) void fmh_kernel(
    const float* __restrict__ MH, const float* __restrict__ gv,
    float* __restrict__ f1, float* __restrict__ f2, long rows)
{
  __shared__ float w[512];
  int tid = threadIdx.x;
  for (int q = tid; q < 512; q += 256) w[q] = gv[q];
  __syncthreads();
  long r = (long)blockIdx.x * 4 + (tid >> 6);
  int lane = tid & 63;
  const float* m = MH + r * 256;
  float s1 = 0.f, s2 = 0.f;
#pragma unroll
  for (int t = 0; t < 4; ++t) {
    float a = m[t * 64 + lane];
    s1 += a * w[t * 64 + lane];
    s2 += a * w[256 + t * 64 + lane];
  }
#pragma unroll
  for (int mm = 32; mm; mm >>= 1) { s1 += __shfl_xor(s1, mm, 64); s2 += __shfl_xor(s2, mm, 64); }
  if (lane == 0) { f1[r] = s1; f2[r] = s2; }
}

// ---------------------------------------------------------------------------
// pack bvec/aw/ab for mmdot (r6-validated)
// ---------------------------------------------------------------------------
__global__ void pack_kernel(
    const float* __restrict__ bh_c_b, const float* __restrict__ t_c2p_b,
    const float* __restrict__ ba_c_w, const float* __restrict__ ba_c_b,
    const float* __restrict__ ba_p_w, const float* __restrict__ bh_p_b,
    const float* __restrict__ t_p2c_b, const float* __restrict__ ba_p_b,
    float* __restrict__ pk_a, float* __restrict__ pk_p)
{
  int idx = blockIdx.x * 256 + threadIdx.x;
  if (idx < 1024) {
    int g = idx >> 7, j = idx & 127;
    pk_a[idx] = g < 4 ? bh_c_b[g * 128 + j] : t_c2p_b[(g - 4) * 128 + j];
    pk_p[idx] = g < 4 ? bh_p_b[g * 128 + j] : t_p2c_b[(g - 4) * 128 + j];
  } else if (idx < 2048) {
    int k = idx - 1024; int g = k >> 7, j = k & 127;
    pk_a[idx] = g < 4 ? ba_c_w[g * 256 + j] : ba_p_w[(g - 4) * 256 + 128 + j];
    pk_p[idx] = g < 4 ? ba_p_w[g * 256 + j] : ba_c_w[(g - 4) * 256 + 128 + j];
  } else if (idx < 2056) {
    int g = idx - 2048;
    pk_a[idx] = g < 4 ? ba_c_b[g] : 0.f;
    pk_p[idx] = g < 4 ? ba_p_b[g] : 0.f;
  }
}

// ---------------------------------------------------------------------------
// MFMA GEMM: C = act(A @ B + bias).  A fp32 [M,K], Bt bf16 [N,K].
// OUT=0: fp32 C[row*ldc+colOff+col];  OUT=1: bf16 C[row*ldc+col]
// OUT=2: bf16 transposed-blocked C[(row/MBc)*BSt + col*ldt + (row%MBc)]
// ---------------------------------------------------------------------------
template<int ACT, int OUT>
__global__ __launch_bounds__(256) void mfma_mm_kernel(
    const float* __restrict__ A, const u16* __restrict__ Bt,
    const float* __restrict__ bias, void* __restrict__ Cp,
    int M, int N, int K, int lda, int ldc, int colOff,
    int MBc, long BSt, int ldt)
{
  __shared__ u16 sA[64 * 64];
  __shared__ u16 sB[64 * 64];
  int m0 = blockIdx.y * 64, n0 = blockIdx.x * 64;
  int tid = threadIdx.x, lane = tid & 63, wv = tid >> 6;
  int mh = wv >> 1, nh = wv & 1;
  f32x4 acc00 = {0.f,0.f,0.f,0.f};
  f32x4 acc01 = acc00, acc10 = acc00, acc11 = acc00;
  for (int k0 = 0; k0 < K; k0 += 64) {
#pragma unroll
    for (int q = tid; q < 64 * 16; q += 256) {
      int r = q >> 4, c4 = (q & 15) << 2;
      float4 v = *(const float4*)(A + (long)(m0 + r) * lda + k0 + c4);
      u16x4 h = { bfc(v.x), bfc(v.y), bfc(v.z), bfc(v.w) };
      *(u16x4*)((char*)sA + lofs<64>(r, c4)) = h;
    }
#pragma unroll
    for (int q = tid; q < 64 * 8; q += 256) {
      int r = q >> 3, c8 = (q & 7) << 3;
      *(u32x4*)((char*)sB + lofs<64>(r, c8)) =
          *(const u32x4*)(Bt + (long)(n0 + r) * K + k0 + c8);
    }
    __syncthreads();
#pragma unroll
    for (int kk = 0; kk < 64; kk += 32) {
      int kf = kk + ((lane >> 4) << 3);
      short8v a0 = ldsv(sA, lofs<64>(mh * 32 + (lane & 15), kf));
      short8v a1 = ldsv(sA, lofs<64>(mh * 32 + 16 + (lane & 15), kf));
      short8v b0 = ldsv(sB, lofs<64>(nh * 32 + (lane & 15), kf));
      short8v b1 = ldsv(sB, lofs<64>(nh * 32 + 16 + (lane & 15), kf));
      acc00 = MFMA(a0, b0, acc00);
      acc01 = MFMA(a0, b1, acc01);
      acc10 = MFMA(a1, b0, acc10);
      acc11 = MFMA(a1, b1, acc11);
    }
    __syncthreads();
  }
#pragma unroll
  for (int rt = 0; rt < 2; ++rt) {
#pragma unroll
    for (int ct = 0; ct < 2; ++ct) {
      f32x4 a = rt == 0 ? (ct == 0 ? acc00 : acc01) : (ct == 0 ? acc10 : acc11);
      int col = n0 + nh * 32 + ct * 16 + (lane & 15);
      float bv = bias ? bias[col] : 0.f;
#pragma unroll
      for (int r4 = 0; r4 < 4; ++r4) {
        int row = m0 + mh * 32 + rt * 16 + ((lane >> 4) << 2) + r4;
        float v = apply_act(a[r4] + bv, ACT);
        if (OUT == 0)
          ((float*)Cp)[(long)row * ldc + colOff + col] = v;
        else if (OUT == 1)
          ((u16*)Cp)[(long)row * ldc + col] = bfc(v);
        else
          ((u16*)Cp)[(long)(row / MBc) * BSt + (long)col * ldt + (row % MBc)] = bfc(v);
      }
    }
  }
}

template<int ACT, int OUT>
static void mmx(hipStream_t st, const float* A, const u16* Bt, const float* bias,
                void* C, int M, int N, int K, int lda, int ldc, int colOff = 0,
                int MBc = 1, long BSt = 0, int ldt = 0)
{
  dim3 grid(N / 64, M / 64);
  mfma_mm_kernel<ACT, OUT><<<grid, dim3(256), 0, st>>>(
      A, Bt, bias, C, M, N, K, lda, ldc, colOff, MBc, BSt, ldt);
}

// ---------------------------------------------------------------------------
// mmdot: out[g][row] = sum_col ftanh((X@W_g)[row,col]+bvec)*aw + ab
// grid (M/128, 2): y selects 4 groups.  XBF: X is bf16 (copy-stage).
// ---------------------------------------------------------------------------
template<int XBF>
__global__ __launch_bounds__(256) void mmdot_kernel(
    const void* __restrict__ Xp, const u16* __restrict__ Wcat,
    const float* __restrict__ pk, float* __restrict__ out, long M)
{
  __shared__ u16 sX[128 * 128];    // 32 KB
  __shared__ u16 sW[64 * 128];     // 16 KB
  __shared__ float bv_s[64], aw_s[64];
  long m0 = (long)blockIdx.x * 128;
  int g0 = blockIdx.y * 4;
  int tid = threadIdx.x, lane = tid & 63, wv = tid >> 6;
  if (XBF) {
    const u16* X = (const u16*)Xp;
    for (int q = tid; q < 128 * 16; q += 256) {
      int r = q >> 4, c8 = (q & 15) << 3;
      *(u32x4*)((char*)sX + lofs<128>(r, c8)) =
          *(const u32x4*)(X + (m0 + r) * 128 + c8);
    }
  } else {
    const float* X = (const float*)Xp;
    for (int q = tid; q < 128 * 32; q += 256) {
      int r = q >> 5, c4 = (q & 31) << 2;
      float4 v = *(const float4*)(X + (m0 + r) * 128 + c4);
      u16x4 h = { bfc(v.x), bfc(v.y), bfc(v.z), bfc(v.w) };
      *(u16x4*)((char*)sX + lofs<128>(r, c4)) = h;
    }
  }
  for (int gi = 0; gi < 4; ++gi) {
    int g = g0 + gi;
    float p[2][4] = {{0.f,0.f,0.f,0.f},{0.f,0.f,0.f,0.f}};
    for (int hh = 0; hh < 2; ++hh) {
      __syncthreads();                 // sX ready / protect sW+bv reuse
      for (int q = tid; q < 64 * 16; q += 256) {
        int r = q >> 4, c8 = (q & 15) << 3;
        *(u32x4*)((char*)sW + lofs<128>(r, c8)) =
            *(const u32x4*)(Wcat + (long)g * 16384 + (long)(hh * 64 + r) * 128 + c8);
      }
      if (tid < 64) {
        bv_s[tid] = pk[g * 128 + hh * 64 + tid];
        aw_s[tid] = pk[1024 + g * 128 + hh * 64 + tid];
      }
      __syncthreads();
      for (int lt = 0; lt < 4; ++lt) {
        int col = lt * 16 + (lane & 15);
        float bv = bv_s[col], awv = aw_s[col];
#pragma unroll
        for (int rt = 0; rt < 2; ++rt) {
          f32x4 c = {0.f,0.f,0.f,0.f};
#pragma unroll
          for (int kk = 0; kk < 128; kk += 32) {
            int kf = kk + ((lane >> 4) << 3);
            short8v a = ldsv(sX, lofs<128>(wv * 32 + rt * 16 + (lane & 15), kf));
            short8v bb = ldsv(sW, lofs<128>(lt * 16 + (lane & 15), kf));
            c = MFMA(a, bb, c);
          }
#pragma unroll
          for (int r4 = 0; r4 < 4; ++r4)
            p[rt][r4] += ftanh(c[r4] + bv) * awv;
        }
      }
    }
    float ab = pk[2048 + g];
#pragma unroll
    for (int rt = 0; rt < 2; ++rt)
#pragma unroll
      for (int r4 = 0; r4 < 4; ++r4) {
        float s = p[rt][r4];
        s += __shfl_xor(s, 1, 64); s += __shfl_xor(s, 2, 64);
        s += __shfl_xor(s, 4, 64); s += __shfl_xor(s, 8, 64);
        if ((lane & 15) == 0) {
          long row = m0 + wv * 32 + rt * 16 + ((lane >> 4) << 2) + r4;
          out[(long)g * M + row] = s + ab;
        }
      }
  }
}

// ---------------------------------------------------------------------------
// bidat_fused v3 (r8-validated): A-frags in registers, bf16 PV, fast tanh.
// ---------------------------------------------------------------------------
__global__ __launch_bounds__(256) void bidat_fused(
    const u16* __restrict__ AVU4,    // [Bn*Nn][512] bf16 (4 iters concat)
    const u16* __restrict__ PVbf,    // [Bn][Ln][128] bf16
    float* __restrict__ OUTP,        // [8][Bn*Ln]: g<4 SCP, g>=4 q
    float* __restrict__ OUTA,        // [8][Bn*Nn]: g<4 SCA, g>=4 r
    const float* __restrict__ am, const float* __restrict__ pm)
{
  __shared__ u16 sK[128 * 128];      // 32 KB
  __shared__ float qm_s[128], pm_s[128], amr_s[128], am_sh[128];
  __shared__ float scp_red[4][128];
  const long NBt = (long)Bn * Nn, LBt = (long)Bn * Ln;
  int b = blockIdx.y;
  int n0 = blockIdx.x * 128;
  int zz = blockIdx.z;
  int it = zz & 3, lz = zz >> 2;
  const float* qv = OUTP + (long)(4 + it) * LBt;
  const float* rv = OUTA + (long)(4 + it) * NBt;
  float* SCA = OUTA + (long)it * NBt;
  float* SCP = OUTP + (long)it * LBt;
  int tid = threadIdx.x, lane = tid & 63, wv = tid >> 6;

  short8v af[2][4];
  {
    long rbase = (long)b * Nn + n0 + wv * 32 + (lane & 15);
    int cbase = it * 128 + ((lane >> 4) << 3);
#pragma unroll
    for (int rt = 0; rt < 2; ++rt)
#pragma unroll
      for (int k4 = 0; k4 < 4; ++k4)
        af[rt][k4] = *(const short8v*)(AVU4 + (rbase + rt * 16) * 512 + cbase + k4 * 32);
  }
  if (tid < 128) {
    float amv = am[(long)b * Nn + n0 + tid];
    am_sh[tid] = amv;
    amr_s[tid] = amv * rv[(long)b * Nn + n0 + tid];
  }
  float sca_r[2][4] = {{0.f,0.f,0.f,0.f},{0.f,0.f,0.f,0.f}};
  const u16* pvb = PVbf + (long)b * Ln * 128;
  int lbeg = lz * (Ln / FLSP);

  for (int l0 = lbeg; l0 < lbeg + Ln / FLSP; l0 += 128) {
    __syncthreads();
    for (int q = tid; q < 128 * 16; q += 256) {
      int r = q >> 4, c8 = (q & 15) << 3;
      *(u32x4*)((char*)sK + lofs<128>(r, c8)) =
          *(const u32x4*)(pvb + (long)(l0 + r) * 128 + c8);
    }
    if (tid < 128) {
      float pmv = pm[(long)b * Ln + l0 + tid];
      pm_s[tid] = pmv;
      qm_s[tid] = pmv * qv[(long)b * Ln + l0 + tid];
    }
    __syncthreads();
    for (int lt = 0; lt < 8; ++lt) {
      float sp = 0.f;
      float qmv = qm_s[lt * 16 + (lane & 15)];
#pragma unroll
      for (int rt = 0; rt < 2; ++rt) {
        f32x4 c = {0.f,0.f,0.f,0.f};
#pragma unroll
        for (int k4 = 0; k4 < 4; ++k4) {
          short8v bb = ldsv(sK, lofs<128>(lt * 16 + (lane & 15),
                                          k4 * 32 + ((lane >> 4) << 3)));
          c = MFMA(af[rt][k4], bb, c);
        }
#pragma unroll
        for (int r4 = 0; r4 < 4; ++r4) {
          int nr = wv * 32 + rt * 16 + ((lane >> 4) << 2) + r4;
          float t = ftanh(c[r4]);
          sca_r[rt][r4] += t * qmv;
          sp += t * amr_s[nr];
        }
      }
      sp += __shfl_xor(sp, 16, 64);
      sp += __shfl_xor(sp, 32, 64);
      if (lane < 16) scp_red[wv][lt * 16 + lane] = sp;
    }
    __syncthreads();
    if (tid < 128) {
      float v = scp_red[0][tid] + scp_red[1][tid] + scp_red[2][tid] + scp_red[3][tid];
      atomicAdd(&SCP[(long)b * Ln + l0 + tid], v * pm_s[tid]);
    }
  }
#pragma unroll
  for (int rt = 0; rt < 2; ++rt)
#pragma unroll
    for (int r4 = 0; r4 < 4; ++r4) {
      float s = sca_r[rt][r4];
      s += __shfl_xor(s, 1, 64); s += __shfl_xor(s, 2, 64);
      s += __shfl_xor(s, 4, 64); s += __shfl_xor(s, 8, 64);
      if ((lane & 15) == 0) {
        int nr = wv * 32 + rt * 16 + ((lane >> 4) << 2) + r4;
        atomicAdd(&SCA[(long)b * Nn + n0 + nr], s * am_sh[nr]);
      }
    }
}

// ---------------------------------------------------------------------------
// Legacy fp32 tiled matmul (head layers, K=386)
// ---------------------------------------------------------------------------
__global__ __launch_bounds__(256) void mm_kernel(
    const float* __restrict__ A, const float* __restrict__ Bm,
    const float* __restrict__ bias, float* __restrict__ C,
    int M, int N, int K, int lda, int ldb, int ldc, int colOff, int act)
{
  __shared__ float As[32][33];
  __shared__ float Bs[32][33];
  int tx = threadIdx.x, ty = threadIdx.y;
  int tid = ty * 16 + tx;
  int m0 = blockIdx.y * 32;
  int n0 = blockIdx.x * 32;
  float acc00 = 0.f, acc01 = 0.f, acc10 = 0.f, acc11 = 0.f;
  for (int k0 = 0; k0 < K; k0 += 32) {
#pragma unroll
    for (int t = 0; t < 4; ++t) {
      int li = tid + t * 256;
      int r = li >> 5, c = li & 31;
      int mm = m0 + r, kk = k0 + c;
      As[r][c] = (mm < M && kk < K) ? A[(long)mm * lda + kk] : 0.f;
      int kk2 = k0 + r, nn = n0 + c;
      Bs[r][c] = (kk2 < K && nn < N) ? Bm[(long)kk2 * ldb + nn] : 0.f;
    }
    __syncthreads();
#pragma unroll
    for (int kk = 0; kk < 32; ++kk) {
      float a0 = As[ty][kk], a1 = As[ty + 16][kk];
      float b0 = Bs[kk][tx], b1 = Bs[kk][tx + 16];
      acc00 += a0 * b0; acc01 += a0 * b1;
      acc10 += a1 * b0; acc11 += a1 * b1;
    }
    __syncthreads();
  }
  float accs[2][2] = {{acc00, acc01}, {acc10, acc11}};
#pragma unroll
  for (int i = 0; i < 2; ++i) {
    int m = m0 + ty + i * 16;
    if (m >= M) continue;
#pragma unroll
    for (int j = 0; j < 2; ++j) {
      int n = n0 + tx + j * 16;
      if (n >= N) continue;
      float v = accs[i][j];
      if (bias) v += bias[n];
      C[(long)m * ldc + colOff + n] = apply_act(v, act);
    }
  }
}

static void mm(hipStream_t st, const float* A, const float* Bm, const float* bias,
               float* C, int M, int N, int K, int lda, int ldb, int ldc,
               int colOff, int act)
{
  dim3 grid((N + 31) / 32, (M + 31) / 32), block(16, 16);
  mm_kernel<<<grid, block, 0, st>>>(A, Bm, bias, C, M, N, K, lda, ldb, ldc, colOff, act);
}

// ---------------------------------------------------------------------------
// GAT v3: bitmask adj + register softmax stats + MFMA att@Wh.
// WhT: [b][n][k=256] bf16 (pre-transposed).  grid (Nn/32, Bn, heads).
// ---------------------------------------------------------------------------
template<int F>
__global__ __launch_bounds__(256) void gat3_kernel(
    const u16* __restrict__ WhT, long bStride,
    const float* __restrict__ f1, const float* __restrict__ f2,
    const u64* __restrict__ adjb,
    float* __restrict__ out, int ldo)
{
  __shared__ u16 sP[32 * 256];       // 16 KB, lofs<256>
  __shared__ u16 sW[F * 32];         // 4/8 KB, XOR (n&7)<<4
  __shared__ float f2s[256];
  __shared__ float f1s[32], mrow[32], srow[32];
  __shared__ u64 adjm[32][4];
  int b = blockIdx.y, i0 = blockIdx.x * 32, h = blockIdx.z;
  int tid = threadIdx.x, lane = tid & 63, wv = tid >> 6;
  const long rowb = (long)b * Nn;
  const float* f1h = f1 + (long)h * Bn * Nn;
  const float* f2h = f2 + (long)h * Bn * Nn;

  if (tid < 32) f1s[tid] = f1h[rowb + i0 + tid];
  f2s[tid] = f2h[rowb + tid];
  if (tid < 128) adjm[tid >> 2][tid & 3] = adjb[(rowb + i0 + (tid >> 2)) * 4 + (tid & 3)];
  __syncthreads();

  // phase A: per-row max + sum (8 lanes/row, e recomputed)
  {
    int r = tid >> 3, s = tid & 7;
    float f1v = f1s[r];
    float mx = -3.4e38f;
    for (int j = s; j < 256; j += 8) {
      bool bit = (adjm[r][j >> 6] >> (j & 63)) & 1;
      float e = f1v + f2s[j]; e = e > 0.f ? e : 0.2f * e;
      mx = fmaxf(mx, bit ? e : -9e15f);
    }
    mx = fmaxf(mx, __shfl_xor(mx, 1, 64));
    mx = fmaxf(mx, __shfl_xor(mx, 2, 64));
    mx = fmaxf(mx, __shfl_xor(mx, 4, 64));
    float sum = 0.f;
    for (int j = s; j < 256; j += 8) {
      bool bit = (adjm[r][j >> 6] >> (j & 63)) & 1;
      float e = f1v + f2s[j]; e = e > 0.f ? e : 0.2f * e;
      sum += __expf((bit ? e : -9e15f) - mx);
    }
    sum += __shfl_xor(sum, 1, 64);
    sum += __shfl_xor(sum, 2, 64);
    sum += __shfl_xor(sum, 4, 64);
    if (s == 0) { mrow[r] = mx; srow[r] = 1.f / sum; }
  }
  __syncthreads();
  // phase B: P (unnormalized, bf16) into sP
  {
    int j = tid;
    float f2v = f2s[j];
    int w64 = j >> 6, sh = j & 63;
    for (int r = 0; r < 32; ++r) {
      bool bit = (adjm[r][w64] >> sh) & 1;
      float e = f1s[r] + f2v; e = e > 0.f ? e : 0.2f * e;
      float p = __expf((bit ? e : -9e15f) - mrow[r]);
      *(u16*)((char*)sP + lofs<256>(r, j)) = bfc(p);
    }
  }
  // phase C: MFMA (32 x F) = sP(32x256) @ WhT^T
  constexpr int NT = F / 32;
  f32x4 acc[NT];
#pragma unroll
  for (int t = 0; t < NT; ++t) acc[t] = f32x4{0.f,0.f,0.f,0.f};
  const u16* Wb = WhT + (long)b * bStride + (long)h * F * 256;
  int mh = wv & 1;
  for (int k0 = 0; k0 < 256; k0 += 32) {
    __syncthreads();
    for (int q = tid; q < F * 4; q += 256) {
      int n = q >> 2, c8 = (q & 3) << 3;
      *(u32x4*)((char*)sW + ((n * 64 + c8 * 2) ^ ((n & 7) << 4))) =
          *(const u32x4*)(Wb + (long)n * 256 + k0 + c8);
    }
    __syncthreads();
    int kf = (lane >> 4) << 3;
    short8v a = ldsv(sP, lofs<256>(mh * 16 + (lane & 15), k0 + kf));
#pragma unroll
    for (int t = 0; t < NT; ++t) {
      int n = ((wv >> 1) * NT + t) * 16 + (lane & 15);
      short8v bb = *(const short8v*)((char*)sW + ((n * 64 + kf * 2) ^ ((n & 7) << 4)));
      acc[t] = MFMA(a, bb, acc[t]);
    }
  }
#pragma unroll
  for (int t = 0; t < NT; ++t) {
    int col = ((wv >> 1) * NT + t) * 16 + (lane & 15);
#pragma unroll
    for (int r4 = 0; r4 < 4; ++r4) {
      int rl = mh * 16 + ((lane >> 4) << 2) + r4;
      float v = acc[t][r4] * srow[rl];
      v = v > 0.f ? v : expm1f(v);   // elu
      out[(rowb + i0 + rl) * (long)ldo + h * F + col] = v;
    }
  }
}

// ---------------------------------------------------------------------------
// 11x11 conv (validated r3).  conv11e fuses the amino embedding (layer 1).
// ---------------------------------------------------------------------------
__global__ __launch_bounds__(128) void conv11_kernel(
    const float* __restrict__ in, const float* __restrict__ kw,
    const float* __restrict__ bias_p, float* __restrict__ out)
{
  __shared__ float s[26][140];
  __shared__ float kk[121];
  int b = blockIdx.y;
  int l0 = blockIdx.x * 16;
  int tid = threadIdx.x;
  if (tid < 121) kk[tid] = kw[tid];
  const float* inb = in + (long)b * Ln * PROT;
  for (int r = 0; r < 26; ++r) {
    int l = l0 - 5 + r;
    for (int c = tid; c < 138; c += 128) {
      int p = c - 5;
      float v = 0.f;
      if (l >= 0 && l < Ln && p >= 0 && p < PROT) v = inb[(long)l * PROT + p];
      s[r][c] = v;
    }
  }
  __syncthreads();
  float bias = bias_p[0];
  float acc[16];
#pragma unroll
  for (int i = 0; i < 16; ++i) acc[i] = bias;
  int p = tid;
#pragma unroll
  for (int v = 0; v < 11; ++v) {
    float c[26];
#pragma unroll
    for (int u = 0; u < 26; ++u) c[u] = s[u][p + v];
#pragma unroll
    for (int u = 0; u < 11; ++u) {
      float w = kk[u * 11 + v];
#pragma unroll
      for (int i = 0; i < 16; ++i) acc[i] += c[i + u] * w;
    }
  }
  float* outb = out + (long)b * Ln * PROT;
#pragma unroll
  for (int i = 0; i < 16; ++i) {
    float vv = acc[i];
    outb[(long)(l0 + i) * PROT + p] = vv > 0.f ? vv : 0.2f * vv;
  }
}

__global__ __launch_bounds__(128) void conv11e_kernel(
    const int* __restrict__ amino, const float* __restrict__ E,
    const float* __restrict__ kw, const float* __restrict__ bias_p,
    float* __restrict__ out)
{
  __shared__ float s[26][140];
  __shared__ float kk[121];
  int b = blockIdx.y;
  int l0 = blockIdx.x * 16;
  int tid = threadIdx.x;
  if (tid < 121) kk[tid] = kw[tid];
  const int* amb = amino + (long)b * Ln;
  for (int r = 0; r < 26; ++r) {
    int l = l0 - 5 + r;
    int idx = (l >= 0 && l < Ln) ? amb[l] : -1;
    const float* Er = E + (long)(idx < 0 ? 0 : idx) * PROT;
    for (int c = tid; c < 138; c += 128) {
      int p = c - 5;
      float v = 0.f;
      if (idx >= 0 && p >= 0 && p < PROT) v = Er[p];
      s[r][c] = v;
    }
  }
  __syncthreads();
  float bias = bias_p[0];
  float acc[16];
#pragma unroll
  for (int i = 0; i < 16; ++i) acc[i] = bias;
  int p = tid;
#pragma unroll
  for (int v = 0; v < 11; ++v) {
    float c[26];
#pragma unroll
    for (int u = 0; u < 26; ++u) c[u] = s[u][p + v];
#pragma unroll
    for (int u = 0; u < 11; ++u) {
      float w = kk[u * 11 + v];
#pragma unroll
      for (int i = 0; i < 16; ++i) acc[i] += c[i + u] * w;
    }
  }
  float* outb = out + (long)b * Ln * PROT;
#pragma unroll
  for (int i = 0; i < 16; ++i) {
    float vv = acc[i];
    outb[(long)(l0 + i) * PROT + p] = vv > 0.f ? vv : 0.2f * vv;
  }
}

// ---------------------------------------------------------------------------
// masked softmax (grid.y = iteration)
// ---------------------------------------------------------------------------
__global__ __launch_bounds__(256) void mask_softmax_kernel(
    const float* __restrict__ score, const float* __restrict__ mask,
    float* __restrict__ att, int n)
{
  int b = blockIdx.x;
  long st = (long)blockIdx.y * gridDim.x * n;
  int tid = threadIdx.x;
  __shared__ float red[256];
  const float* s = score + st + (long)b * n;
  const float* mk = mask + (long)b * n;
  float mx = -3.4e38f;
  for (int i = tid; i < n; i += 256) mx = fmaxf(mx, s[i]);
  red[tid] = mx; __syncthreads();
  for (int stp = 128; stp > 0; stp >>= 1) { if (tid < stp) red[tid] = fmaxf(red[tid], red[tid + stp]); __syncthreads(); }
  mx = red[0]; __syncthreads();
  float sum = 0.f;
  for (int i = tid; i < n; i += 256) sum += __expf(s[i] - mx) * mk[i];
  red[tid] = sum; __syncthreads();
  for (int stp = 128; stp > 0; stp >>= 1) { if (tid < stp) red[tid] += red[tid + stp]; __syncthreads(); }
  float denom = red[0] + 1e-6f;
  for (int i = tid; i < n; i += 256)
    att[st + (long)b * n + i] = __expf(s[i] - mx) * mk[i] / denom;
}

// ---------------------------------------------------------------------------
// weighted sum (grid.z = iteration; XBF: x is bf16)
// ---------------------------------------------------------------------------
template<int XBF>
__global__ __launch_bounds__(128) void wsum_kernel(
    const void* __restrict__ xp, const float* __restrict__ att,
    float* __restrict__ out, int n, int nsplit)
{
  int b = blockIdx.x;
  int sp = blockIdx.y;
  int it = blockIdx.z;
  int d = threadIdx.x;
  int chunk = n / nsplit;
  int t0 = sp * chunk, t1 = t0 + chunk;
  const float* ab = att + (long)it * gridDim.x * n + (long)b * n;
  float acc = 0.f;
  if (XBF) {
    const u16* xb = (const u16*)xp + (long)b * n * LT + d;
#pragma unroll 8
    for (int t = t0; t < t1; ++t) acc += bf2f(xb[(long)t * LT]) * ab[t];
  } else {
    const float* xb = (const float*)xp + (long)b * n * LT + d;
#pragma unroll 8
    for (int t = t0; t < t1; ++t) acc += xb[(long)t * LT] * ab[t];
  }
  atomicAdd(&out[(long)b * 512 + it * LT + d], acc);
}

__global__ __launch_bounds__(128) void assemble_v_kernel(
    const float* __restrict__ sf, const float* __restrict__ invT,
    const float* __restrict__ T, float* __restrict__ v)
{
  int b = blockIdx.x;
  int t = threadIdx.x;
  v[(long)b * DOUT + 128 + t] = sf[(long)b * LT + t];
  if (t == 0) { v[(long)b * DOUT + 384] = invT[b]; v[(long)b * DOUT + 385] = T[b]; }
}

// ---------------------------------------------------------------------------
extern "C" void kernel_launch(void* const* d_in, const int* in_sizes, int n_in,
                              void* d_out, int out_size, void* d_ws, size_t ws_size,
                              hipStream_t stream) {
  const long NB = (long)Bn * Nn;    // 16384
  const long LB = (long)Bn * Ln;    // 131072
  const long M1 = 1024 * 1024;

  const int*   atoms      = (const int*)d_in[0];
  const float* atoms_mask = (const float*)d_in[1];
  const int*   adj        = (const int*)d_in[2];
  const int*   amino      = (const int*)d_in[3];
  const float* amino_mask = (const float*)d_in[4];
  const float* fps        = (const float*)d_in[5];
  const float* invT       = (const float*)d_in[6];
  const float* Temp       = (const float*)d_in[7];
  const float* E_atom     = (const float*)d_in[8];
  const float* E_amino    = (const float*)d_in[9];
  const float* gatW       = (const float*)d_in[10];
  const float* gatA       = (const float*)d_in[11];
  const float* goW        = (const float*)d_in[12];
  const float* goA        = (const float*)d_in[13];
  const float* Wc_w       = (const float*)d_in[14];
  const float* Wc_b       = (const float*)d_in[15];
  const float* conv_k     = (const float*)d_in[16];
  const float* conv_b     = (const float*)d_in[17];
  const float* Wp_w       = (const float*)d_in[18];
  const float* Wp_b       = (const float*)d_in[19];
  const float* fp0        = (const float*)d_in[20];
  const float* fp1        = (const float*)d_in[21];
  const float* U          = (const float*)d_in[22];
  const float* t_c2p_w    = (const float*)d_in[23];
  const float* t_c2p_b    = (const float*)d_in[24];
  const float* t_p2c_w    = (const float*)d_in[25];
  const float* t_p2c_b    = (const float*)d_in[26];
  const float* bh_c_w     = (const float*)d_in[27];
  const float* bh_c_b     = (const float*)d_in[28];
  const float* bh_p_w     = (const float*)d_in[29];
  const float* bh_p_b     = (const float*)d_in[30];
  const float* ba_c_w     = (const float*)d_in[31];
  const float* ba_c_b     = (const float*)d_in[32];
  const float* ba_p_w     = (const float*)d_in[33];
  const float* ba_p_b     = (const float*)d_in[34];
  const float* comb_c_w   = (const float*)d_in[35];
  const float* comb_c_b   = (const float*)d_in[36];
  const float* comb_p_w   = (const float*)d_in[37];
  const float* comb_p_b   = (const float*)d_in[38];
  const float* Wout_w     = (const float*)d_in[39];
  const float* Wout_b     = (const float*)d_in[40];
  const float* out_w      = (const float*)d_in[41];
  const float* out_b      = (const float*)d_in[42];
  float* out = (float*)d_out;

  // ---------------- workspace layout (~98 MB) ----------------
  float* ws = (float*)d_ws;
  long off = 0;
  float* AV    = ws + off; off += NB * LT;          // 2M fp32
  u16*   PVbf  = (u16*)(ws + off); off += LB * LT / 2;
  float* SF    = ws + off; off += (long)Bn * LT;
  float* SFT   = ws + off; off += (long)Bn * LT;
  float* CF    = ws + off; off += (long)Bn * 512;
  float* PF    = ws + off; off += (long)Bn * 512;
  float* F1    = ws + off; off += 4 * NB;
  float* F2    = ws + off; off += 4 * NB;
  float* ATTA4 = ws + off; off += 4 * NB;
  float* ATTP4 = ws + off; off += 4 * LB;
  float* V0    = ws + off; off += (long)Bn * DOUT;
  float* V1    = ws + off; off += (long)Bn * DOUT;
  u64*   ADJB  = (u64*)(ws + off); off += NB * 4 * 2;   // [NB][4] u64
  float* WVEC  = ws + off; off += 2048;                 // 1536 used
  // weight cache (persistent)
  u16* WT = (u16*)(ws + off);
  long wo = 0;
  u16* gatW_t  = WT + wo; wo += 4L * 64 * 128;      // [256 n][128 k]
  u16* goW_t   = WT + wo; wo += 128L * 256;
  u16* T23     = WT + wo; wo += 23L * 16384;
  u16* fp0_t   = WT + wo; wo += 128L * 1024;
  u16* combc_t = WT + wo; wo += 128L * 512;
  u16* combp_t = WT + wo; wo += 128L * 512;
  off += (wo + 1) / 2;
  float* pk_a = ws + off; off += 2056;
  float* pk_p = ws + off; off += 2056;
  float* POOL = ws + off;                           // needs 16.78M floats
  u16* Wc_t   = T23;
  u16* Wp_t   = T23 + 16384;
  u16* fp1_t  = T23 + 2L * 16384;
  u16* U_t    = T23 + 3L * 16384;                   // 4 mats contiguous
  u16* wcat_a = T23 + 7L * 16384;                   // [bh_c(4) | t_c2p(4)]
  u16* wcat_p = T23 + 15L * 16384;                  // [bh_p(4) | t_p2c(4)]
  // pool aliases:
  float* AVE   = POOL;                              // [0,2M)
  u16*   WhT4  = (u16*)(POOL + 2 * M1);             // [b][256][256] u16 = [2M,4M)
  float* MH    = POOL + 4 * M1;                     // [4M,8.19M)
  u16*   WhT2  = (u16*)POOL;                        // [b][128][256] u16 = [0,1M)  (AVE dead)
  float* G2    = POOL + 2 * M1;                     // [2M,4M)  (WhT4 dead)
  float* PVA   = POOL;                              // CNN ping [0,8.39M)
  float* PVB   = POOL + 8 * M1;                     // CNN pong
  u16*   AVU4  = (u16*)POOL;                        // [NB][512] u16 = [0,4M)
  float* OUTP  = POOL + 4 * M1;                     // [8][LB]
  float* OUTA  = POOL + 5 * M1;                     // [8][NB]

  // ======================= weight prep =======================
  transp_kernel<<<dim3(32, 4), 256, 0, stream>>>(gatW, gatW_t, 128, 64);
  transp_kernel<<<dim3(128), 256, 0, stream>>>(goW, goW_t, 256, 128);
  transp_kernel<<<dim3(512), 256, 0, stream>>>(fp0, fp0_t, 1024, 128);
  transp_kernel<<<dim3(256), 256, 0, stream>>>(comb_c_w, combc_t, 512, 128);
  transp_kernel<<<dim3(256), 256, 0, stream>>>(comb_p_w, combp_t, 512, 128);
  {
    Ptr8 a1 = {{Wc_w, Wp_w, fp1, U, U + 16384, U + 32768, U + 49152, bh_c_w}};
    Ptr8 a2 = {{bh_c_w + 16384, bh_c_w + 32768, bh_c_w + 49152,
                t_c2p_w, t_c2p_w + 16384, t_c2p_w + 32768, t_c2p_w + 49152,
                bh_p_w}};
    Ptr8 a3 = {{bh_p_w + 16384, bh_p_w + 32768, bh_p_w + 49152,
                t_p2c_w, t_p2c_w + 16384, t_p2c_w + 32768, t_p2c_w + 49152,
                bh_p_w}};
    transp8_kernel<<<dim3(64, 8), 256, 0, stream>>>(a1, T23);
    transp8_kernel<<<dim3(64, 8), 256, 0, stream>>>(a2, T23 + 8L * 16384);
    transp8_kernel<<<dim3(64, 7), 256, 0, stream>>>(a3, T23 + 16L * 16384);
  }
  pack_kernel<<<dim3(9), 256, 0, stream>>>(bh_c_b, t_c2p_b, ba_c_w, ba_c_b,
                                           ba_p_w, bh_p_b, t_p2c_b, ba_p_b,
                                           pk_a, pk_p);
  packadj_kernel<<<dim3((unsigned)(NB * Nn / 256)), 256, 0, stream>>>(adj, ADJB);
  wvec_kernel<<<dim3(6), 256, 0, stream>>>(gatW, gatA, goW, goA, WVEC);

  // ======================= comp GAT (MFMA, bitmask) =======================
  embed_kernel<<<dim3((unsigned)((NB * CMP + 255) / 256)), 256, 0, stream>>>(
      atoms, E_atom, AVE, NB * CMP, CMP);
  // WhT4[b][n=256][k=256] = (AVE @ gatW)^T per batch
  mmx<0, 2>(stream, AVE, gatW_t, nullptr, WhT4, (int)NB, 256, 128, 128, 0, 0,
            256, 256L * 256, 256);
  favv_kernel<<<dim3((unsigned)(NB / 4)), 256, 0, stream>>>(AVE, WVEC, F1, F2, NB);
  gat3_kernel<GF><<<dim3(Nn / 32, Bn, 4), 256, 0, stream>>>(
      WhT4, 256L * 256, F1, F2, ADJB, MH, 256);
  // WhT2[b][n=128][k=256] = (MH @ goW)^T per batch
  mmx<0, 2>(stream, MH, goW_t, nullptr, WhT2, (int)NB, 128, 256, 256, 0, 0,
            256, 128L * 256, 256);
  fmh_kernel<<<dim3((unsigned)(NB / 4)), 256, 0, stream>>>(MH, WVEC + 1024, F1, F2, NB);
  gat3_kernel<CMP><<<dim3(Nn / 32, Bn, 1), 256, 0, stream>>>(
      WhT2, 128L * 256, F1, F2, ADJB, G2, 128);
  mmx<1, 0>(stream, G2, Wc_t, Wc_b, AV, (int)NB, 128, 128, 128, 128);

  // ======================= prot CNN (embed fused into conv1) ===============
  for (int c = 0; c < NCH; ++c) {
    long b0 = (long)c * CB;
    conv11e_kernel<<<dim3(Ln / 16, CB), 128, 0, stream>>>(
        amino + b0 * Ln, E_amino, conv_k + 0 * 121, conv_b + 0, PVA);
    conv11_kernel<<<dim3(Ln / 16, CB), 128, 0, stream>>>(PVA, conv_k + 1 * 121, conv_b + 1, PVB);
    conv11_kernel<<<dim3(Ln / 16, CB), 128, 0, stream>>>(PVB, conv_k + 2 * 121, conv_b + 2, PVA);
    mmx<1, 1>(stream, PVA, Wp_t, Wp_b, PVbf + b0 * Ln * 128,
              (int)((long)CB * Ln), 128, 128, 128, 128);
  }

  // ======================= fingerprint =======================
  mmx<2, 0>(stream, fps, fp0_t, nullptr, SFT, Bn, 128, 1024, 1024, 128);
  mmx<2, 0>(stream, SFT, fp1_t, nullptr, SF, Bn, 128, 128, 128, 128);

  // ======================= bidirectional attention =======================
  mmdot_kernel<1><<<dim3((unsigned)(LB / 128), 2), 256, 0, stream>>>(
      PVbf, wcat_p, pk_p, OUTP, LB);
  mmdot_kernel<0><<<dim3((unsigned)(NB / 128), 2), 256, 0, stream>>>(
      AV, wcat_a, pk_a, OUTA, NB);
  mmx<0, 1>(stream, AV, U_t, nullptr, AVU4, (int)NB, 512, 128, 128, 512);
  zero_kernel<<<dim3((unsigned)((2L * Bn * 512 + 255) / 256)), 256, 0, stream>>>(
      CF, 2L * Bn * 512);
  bidat_fused<<<dim3(Nn / 128, Bn, FLSP * 4), 256, 0, stream>>>(
      AVU4, PVbf, OUTP, OUTA, atoms_mask, amino_mask);
  mask_softmax_kernel<<<dim3(Bn, 4), 256, 0, stream>>>(OUTA, atoms_mask, ATTA4, Nn);
  mask_softmax_kernel<<<dim3(Bn, 4), 256, 0, stream>>>(OUTP, amino_mask, ATTP4, Ln);
  wsum_kernel<0><<<dim3(Bn, 8, 4), 128, 0, stream>>>(AV, ATTA4, CF, Nn, 8);
  wsum_kernel<1><<<dim3(Bn, 8, 4), 128, 0, stream>>>(PVbf, ATTP4, PF, Ln, 8);

  // ======================= head =======================
  mmx<0, 0>(stream, CF, combc_t, comb_c_b, V0, Bn, 128, 512, 512, DOUT, 0);
  mmx<0, 0>(stream, PF, combp_t, comb_p_b, V0, Bn, 128, 512, 512, DOUT, 256);
  assemble_v_kernel<<<Bn, 128, 0, stream>>>(SF, invT, Temp, V0);
  mm(stream, V0, Wout_w,                     Wout_b,            V1, Bn, DOUT, DOUT, DOUT, DOUT, DOUT, 0, 1);
  mm(stream, V1, Wout_w + (long)DOUT * DOUT, Wout_b + DOUT,     V0, Bn, DOUT, DOUT, DOUT, DOUT, DOUT, 0, 1);
  mm(stream, V0, Wout_w + 2L * DOUT * DOUT,  Wout_b + 2 * DOUT, V1, Bn, DOUT, DOUT, DOUT, DOUT, DOUT, 0, 1);
  mm(stream, V1, out_w, out_b, out, Bn, 1, DOUT, DOUT, 1, 1, 0, 0);
}